// Round 2
// baseline (7417.226 us; speedup 1.0000x reference)
//
#include <hip/hip_runtime.h>
#include <math.h>

#define N_NODES 100000
#define N_EDGES 1600000
#define DIM     128
#define NG      64
#define BN_EPS  1e-5f

// ---------------------------------------------------------------- degrees
__global__ void k_deg(const int* __restrict__ src, const int* __restrict__ dst,
                      float* __restrict__ degO, float* __restrict__ degI) {
  int e = blockIdx.x * blockDim.x + threadIdx.x;
  if (e < N_EDGES) {
    atomicAdd(&degO[src[e]], 1.0f);
    atomicAdd(&degI[dst[e]], 1.0f);
  }
}

// ---------------------------------------------------------------- graph CSR starts
__global__ void k_starts_init(int* __restrict__ starts) {
  int g = threadIdx.x;
  if (g <= NG) starts[g] = N_NODES;
}

__global__ void k_starts_fill(const int* __restrict__ gid, int* __restrict__ starts) {
  int i = blockIdx.x * blockDim.x + threadIdx.x;
  if (i >= N_NODES) return;
  int gi = gid[i];
  if (i == 0) {
    for (int g = 0; g <= gi; ++g) starts[g] = 0;
  } else {
    int gp = gid[i - 1];
    if (gp != gi) for (int g = gp + 1; g <= gi; ++g) starts[g] = i;
  }
}

// ---------------------------------------------------------------- init_avg accumulation
__global__ void k_seg_accum(const float* __restrict__ h, const int* __restrict__ starts,
                            float* __restrict__ outp) {
  int g = blockIdx.x >> 3, part = blockIdx.x & 7;
  int s = starts[g], e = starts[g + 1];
  int d = threadIdx.x;
  float acc = 0.f;
  for (int i = s + part; i < e; i += 8) acc += h[(size_t)i * DIM + d];
  atomicAdd(&outp[g * DIM + d], acc);
}

__global__ void k_avg_div(const int* __restrict__ starts, float* __restrict__ outp) {
  int g = blockIdx.x, d = threadIdx.x;
  float cnt = fmaxf((float)(starts[g + 1] - starts[g]), 1.0f);
  outp[g * DIM + d] /= cnt;
}

// ---------------------------------------------------------------- BN column stats
__global__ void k_bnstats(const float* __restrict__ x, float* __restrict__ sums) {
  int d = threadIdx.x;                       // 0..127
  int r = blockIdx.x * 512 + threadIdx.y;    // ty in {0,1}
  int rend = min(blockIdx.x * 512 + 512, N_NODES);
  float s = 0.f, s2 = 0.f;
  for (; r < rend; r += 2) {
    float v = x[(size_t)r * DIM + d];
    s += v; s2 += v * v;
  }
  atomicAdd(&sums[d], s);
  atomicAdd(&sums[DIM + d], s2);
}

__global__ void k_bnfin(const float* __restrict__ sums, const float* __restrict__ gamma,
                        const float* __restrict__ beta, float* __restrict__ scale,
                        float* __restrict__ shift) {
  int d = threadIdx.x;
  float m = sums[d] * (1.0f / N_NODES);
  float v = sums[DIM + d] * (1.0f / N_NODES) - m * m;
  float rs = rsqrtf(fmaxf(v, 0.f) + BN_EPS) * gamma[d];
  scale[d] = rs;
  shift[d] = beta[d] - m * rs;
}

// ---------------------------------------------------------------- SpMM (scatter, fused BN + D_src^-1/2)
__global__ void k_spmm(const float* __restrict__ x, const int* __restrict__ src,
                       const int* __restrict__ dst, const float* __restrict__ degO,
                       const float* __restrict__ scale, const float* __restrict__ shift,
                       float* __restrict__ agg) {
  int e = blockIdx.x * 4 + threadIdx.y;
  if (e >= N_EDGES) return;
  int l = threadIdx.x;            // 0..63
  int s = src[e], t = dst[e];
  float iso = rsqrtf(fmaxf(degO[s], 1.0f));
  float2 xv = *(const float2*)&x[(size_t)s * DIM + l * 2];
  float2 sc = *(const float2*)&scale[l * 2];
  float2 sh = *(const float2*)&shift[l * 2];
  atomicAdd(&agg[(size_t)t * DIM + l * 2 + 0], (xv.x * sc.x + sh.x) * iso);
  atomicAdd(&agg[(size_t)t * DIM + l * 2 + 1], (xv.y * sc.y + sh.y) * iso);
}

// ---------------------------------------------------------------- conv: (agg*isi)@W + b, relu, +res
__launch_bounds__(256)
__global__ void k_conv(const float* __restrict__ agg, const float* __restrict__ degI,
                       const float* __restrict__ W, const float* __restrict__ bias,
                       const float* __restrict__ hres, float* __restrict__ outp) {
  __shared__ float As[64][DIM];   // 32 KB
  __shared__ float Ws[32][DIM];   // 16 KB
  int t = threadIdx.x;
  int row0 = blockIdx.x * 64;

  for (int i = t * 4; i < 64 * DIM; i += 1024) {
    int r = i >> 7, c = i & 127;
    int row = row0 + r;
    float4 v = {0.f, 0.f, 0.f, 0.f};
    if (row < N_NODES) {
      v = *(const float4*)&agg[(size_t)row * DIM + c];
      float isi = rsqrtf(fmaxf(degI[row], 1.0f));
      v.x *= isi; v.y *= isi; v.z *= isi; v.w *= isi;
    }
    *(float4*)&As[r][c] = v;
  }

  int tx = t & 31, ty = t >> 5;
  int c0 = tx * 4, r0 = ty * 8;
  float acc[8][4] = {};

  for (int k0 = 0; k0 < DIM; k0 += 32) {
    __syncthreads();   // also covers A staging on first iteration / Ws reuse after
    for (int i = t * 4; i < 32 * DIM; i += 1024) {
      *(float4*)&Ws[i >> 7][i & 127] = *(const float4*)&W[(size_t)(k0 + (i >> 7)) * DIM + (i & 127)];
    }
    __syncthreads();
    for (int k = 0; k < 32; k += 4) {
      float4 w0 = *(float4*)&Ws[k + 0][c0];
      float4 w1 = *(float4*)&Ws[k + 1][c0];
      float4 w2 = *(float4*)&Ws[k + 2][c0];
      float4 w3 = *(float4*)&Ws[k + 3][c0];
#pragma unroll
      for (int rr = 0; rr < 8; ++rr) {
        float4 a = *(float4*)&As[r0 + rr][k0 + k];
        acc[rr][0] += a.x * w0.x + a.y * w1.x + a.z * w2.x + a.w * w3.x;
        acc[rr][1] += a.x * w0.y + a.y * w1.y + a.z * w2.y + a.w * w3.y;
        acc[rr][2] += a.x * w0.z + a.y * w1.z + a.z * w2.z + a.w * w3.z;
        acc[rr][3] += a.x * w0.w + a.y * w1.w + a.z * w2.w + a.w * w3.w;
      }
    }
  }

  float4 bv = *(const float4*)&bias[c0];
#pragma unroll
  for (int rr = 0; rr < 8; ++rr) {
    int row = row0 + r0 + rr;
    if (row < N_NODES) {
      float4 hv = *(const float4*)&hres[(size_t)row * DIM + c0];
      float4 o;
      o.x = hv.x + fmaxf(acc[rr][0] + bv.x, 0.f);
      o.y = hv.y + fmaxf(acc[rr][1] + bv.y, 0.f);
      o.z = hv.z + fmaxf(acc[rr][2] + bv.z, 0.f);
      o.w = hv.w + fmaxf(acc[rr][3] + bv.w, 0.f);
      *(float4*)&outp[(size_t)row * DIM + c0] = o;
    }
  }
}

// ---------------------------------------------------------------- gate = h2 @ gate_W + gate_b
__global__ void k_gate(const float* __restrict__ h2, const float* __restrict__ gW,
                       const float* __restrict__ gb, float* __restrict__ gate) {
  int i = blockIdx.x * 4 + threadIdx.y;
  if (i >= N_NODES) return;
  int l = threadIdx.x;  // 0..63
  float2 a = *(const float2*)&h2[(size_t)i * DIM + l * 2];
  float2 w = *(const float2*)&gW[l * 2];
  float v = a.x * w.x + a.y * w.y;
  for (int off = 32; off; off >>= 1) v += __shfl_down(v, off);
  if (l == 0) gate[i] = v + gb[0];
}

// ---------------------------------------------------------------- per-graph softmax stats
__global__ void k_gstats(const float* __restrict__ gate, const int* __restrict__ starts,
                         float* __restrict__ gmax, float* __restrict__ gden) {
  int g = blockIdx.x;
  int s = starts[g], e = starts[g + 1];
  int t = threadIdx.x;  // 256
  __shared__ float red[256];
  float m = -INFINITY;
  for (int i = s + t; i < e; i += 256) m = fmaxf(m, gate[i]);
  red[t] = m; __syncthreads();
  for (int w = 128; w; w >>= 1) { if (t < w) red[t] = fmaxf(red[t], red[t + w]); __syncthreads(); }
  float mg = red[0]; __syncthreads();
  float ssum = 0.f;
  for (int i = s + t; i < e; i += 256) ssum += expf(gate[i] - mg);
  red[t] = ssum; __syncthreads();
  for (int w = 128; w; w >>= 1) { if (t < w) red[t] += red[t + w]; __syncthreads(); }
  if (t == 0) { gmax[g] = mg; gden[g] = red[0]; }
}

// ---------------------------------------------------------------- weighted pooling
__global__ void k_pool(const float* __restrict__ h2, const float* __restrict__ gate,
                       const int* __restrict__ starts, const float* __restrict__ gmax,
                       const float* __restrict__ gden, float* __restrict__ outp) {
  int g = blockIdx.x >> 3, part = blockIdx.x & 7;
  int s = starts[g], e = starts[g + 1];
  int d = threadIdx.x;
  float mg = gmax[g];
  float dn = gden[g];
  float invden = dn > 0.f ? 1.0f / dn : 0.f;
  float acc = 0.f;
  for (int i = s + part; i < e; i += 8) {
    float w = expf(gate[i] - mg) * invden;
    acc += w * h2[(size_t)i * DIM + d];
  }
  atomicAdd(&outp[g * DIM + d], acc);
}

// ---------------------------------------------------------------- launch
extern "C" void kernel_launch(void* const* d_in, const int* in_sizes, int n_in,
                              void* d_out, int out_size, void* d_ws, size_t ws_size,
                              hipStream_t stream) {
  const float* h    = (const float*)d_in[0];
  const int*   src  = (const int*)d_in[1];
  const int*   dst  = (const int*)d_in[2];
  const int*   gid  = (const int*)d_in[3];
  const float* W1   = (const float*)d_in[5];
  const float* b1   = (const float*)d_in[6];
  const float* W2   = (const float*)d_in[7];
  const float* b2   = (const float*)d_in[8];
  const float* gW   = (const float*)d_in[9];
  const float* gb   = (const float*)d_in[10];
  const float* gamma= (const float*)d_in[11];
  const float* beta = (const float*)d_in[12];
  float* out = (float*)d_out;

  char* ws = (char*)d_ws;
  float* agg  = (float*)ws; ws += (size_t)N_NODES * DIM * 4;
  float* h12  = (float*)ws; ws += (size_t)N_NODES * DIM * 4;
  float* degO = (float*)ws; ws += (size_t)N_NODES * 4;
  float* degI = (float*)ws; ws += (size_t)N_NODES * 4;
  float* gate = (float*)ws; ws += (size_t)N_NODES * 4;
  float* sums = (float*)ws; ws += 2 * DIM * 4;
  float* scale= (float*)ws; ws += DIM * 4;
  float* shift= (float*)ws; ws += DIM * 4;
  float* gmax = (float*)ws; ws += NG * 4;
  float* gden = (float*)ws; ws += NG * 4;
  int* starts = (int*)ws;   ws += (NG + 1) * 4;

  hipMemsetAsync(agg,  0, (size_t)N_NODES * DIM * 4, stream);
  hipMemsetAsync(degO, 0, (size_t)N_NODES * 4, stream);
  hipMemsetAsync(degI, 0, (size_t)N_NODES * 4, stream);
  hipMemsetAsync(sums, 0, 2 * DIM * 4, stream);
  hipMemsetAsync(d_out, 0, (size_t)out_size * 4, stream);

  k_starts_init<<<1, NG + 1, 0, stream>>>(starts);
  k_starts_fill<<<(N_NODES + 255) / 256, 256, 0, stream>>>(gid, starts);
  k_deg<<<(N_EDGES + 255) / 256, 256, 0, stream>>>(src, dst, degO, degI);

  // init_avg_h -> out[NG*DIM ..]
  k_seg_accum<<<NG * 8, DIM, 0, stream>>>(h, starts, out + NG * DIM);
  k_avg_div<<<NG, DIM, 0, stream>>>(starts, out + NG * DIM);

  // layer 1
  k_bnstats<<<(N_NODES + 511) / 512, dim3(128, 2), 0, stream>>>(h, sums);
  k_bnfin<<<1, DIM, 0, stream>>>(sums, gamma, beta, scale, shift);
  k_spmm<<<(N_EDGES + 3) / 4, dim3(64, 4), 0, stream>>>(h, src, dst, degO, scale, shift, agg);
  k_conv<<<(N_NODES + 63) / 64, 256, 0, stream>>>(agg, degI, W1, b1, h, h12);

  // layer 2
  hipMemsetAsync(agg,  0, (size_t)N_NODES * DIM * 4, stream);
  hipMemsetAsync(sums, 0, 2 * DIM * 4, stream);
  k_bnstats<<<(N_NODES + 511) / 512, dim3(128, 2), 0, stream>>>(h12, sums);
  k_bnfin<<<1, DIM, 0, stream>>>(sums, gamma, beta, scale, shift);
  k_spmm<<<(N_EDGES + 3) / 4, dim3(64, 4), 0, stream>>>(h12, src, dst, degO, scale, shift, agg);
  k_conv<<<(N_NODES + 63) / 64, 256, 0, stream>>>(agg, degI, W2, b2, h12, h12);

  // pooling
  k_gate<<<(N_NODES + 3) / 4, dim3(64, 4), 0, stream>>>(h12, gW, gb, gate);
  k_gstats<<<NG, 256, 0, stream>>>(gate, starts, gmax, gden);
  k_pool<<<NG * 8, DIM, 0, stream>>>(h12, gate, starts, gmax, gden, out);
}

// Round 3
// 1075.610 us; speedup vs baseline: 6.8958x; 6.8958x over previous
//
#include <hip/hip_runtime.h>
#include <math.h>

#define N_NODES 100000
#define N_EDGES 1600000
#define DIM     128
#define NG      64
#define BN_EPS  1e-5f

// ---------------------------------------------------------------- degrees / in-counts
__global__ void k_deg(const int* __restrict__ src, const int* __restrict__ dst,
                      float* __restrict__ degO, int* __restrict__ cnt) {
  int e = blockIdx.x * blockDim.x + threadIdx.x;
  if (e < N_EDGES) {
    atomicAdd(&degO[src[e]], 1.0f);
    atomicAdd(&cnt[dst[e]], 1);
  }
}

// ---------------------------------------------------------------- exclusive scan of cnt -> rowstart (1 block)
__global__ void k_scan(const int* __restrict__ cnt, int* __restrict__ rowstart) {
  __shared__ int part[1024];
  int t = threadIdx.x;
  const int CH = (N_NODES + 1023) / 1024;  // 98
  int lo = t * CH, hi = min(lo + CH, N_NODES);
  int s = 0;
  for (int i = lo; i < hi; ++i) s += cnt[i];
  part[t] = s;
  __syncthreads();
  for (int off = 1; off < 1024; off <<= 1) {
    int v = (t >= off) ? part[t - off] : 0;
    __syncthreads();
    part[t] += v;
    __syncthreads();
  }
  int run = (t == 0) ? 0 : part[t - 1];
  for (int i = lo; i < hi; ++i) { rowstart[i] = run; run += cnt[i]; }
  if (t == 1023) rowstart[N_NODES] = run;  // == N_EDGES
}

// ---------------------------------------------------------------- scatter edges into CSR by dst
__global__ void k_scatter(const int* __restrict__ src, const int* __restrict__ dst,
                          const int* __restrict__ rowstart, int* __restrict__ cursor,
                          int* __restrict__ csr) {
  int e = blockIdx.x * blockDim.x + threadIdx.x;
  if (e < N_EDGES) {
    int d = dst[e];
    int pos = rowstart[d] + atomicAdd(&cursor[d], 1);
    csr[pos] = src[e];
  }
}

// ---------------------------------------------------------------- graph CSR starts
__global__ void k_starts_init(int* __restrict__ starts) {
  int g = threadIdx.x;
  if (g <= NG) starts[g] = N_NODES;
}

__global__ void k_starts_fill(const int* __restrict__ gid, int* __restrict__ starts) {
  int i = blockIdx.x * blockDim.x + threadIdx.x;
  if (i >= N_NODES) return;
  int gi = gid[i];
  if (i == 0) {
    for (int g = 0; g <= gi; ++g) starts[g] = 0;
  } else {
    int gp = gid[i - 1];
    if (gp != gi) for (int g = gp + 1; g <= gi; ++g) starts[g] = i;
  }
}

// ---------------------------------------------------------------- init_avg accumulation
__global__ void k_seg_accum(const float* __restrict__ h, const int* __restrict__ starts,
                            float* __restrict__ outp) {
  int g = blockIdx.x >> 3, part = blockIdx.x & 7;
  int s = starts[g], e = starts[g + 1];
  int d = threadIdx.x;
  float acc = 0.f;
  for (int i = s + part; i < e; i += 8) acc += h[(size_t)i * DIM + d];
  atomicAdd(&outp[g * DIM + d], acc);
}

__global__ void k_avg_div(const int* __restrict__ starts, float* __restrict__ outp) {
  int g = blockIdx.x, d = threadIdx.x;
  float cnt = fmaxf((float)(starts[g + 1] - starts[g]), 1.0f);
  outp[g * DIM + d] /= cnt;
}

// ---------------------------------------------------------------- BN column stats
__global__ void k_bnstats(const float* __restrict__ x, float* __restrict__ sums) {
  int d = threadIdx.x;
  int r = blockIdx.x * 512 + threadIdx.y;
  int rend = min(blockIdx.x * 512 + 512, N_NODES);
  float s = 0.f, s2 = 0.f;
  for (; r < rend; r += 2) {
    float v = x[(size_t)r * DIM + d];
    s += v; s2 += v * v;
  }
  atomicAdd(&sums[d], s);
  atomicAdd(&sums[DIM + d], s2);
}

__global__ void k_bnfin(const float* __restrict__ sums, const float* __restrict__ gamma,
                        const float* __restrict__ beta, float* __restrict__ scale,
                        float* __restrict__ shift) {
  int d = threadIdx.x;
  float m = sums[d] * (1.0f / N_NODES);
  float v = sums[DIM + d] * (1.0f / N_NODES) - m * m;
  float rs = rsqrtf(fmaxf(v, 0.f) + BN_EPS) * gamma[d];
  scale[d] = rs;
  shift[d] = beta[d] - m * rs;
}

// ---------------------------------------------------------------- pull-mode SpMM, fused BN + D_src^-1/2 + D_dst^-1/2
// one wave (64 lanes, float2/lane) per dst row; no atomics
__launch_bounds__(256, 8)
__global__ void k_spmm_pull(const float* __restrict__ x, const int* __restrict__ csr,
                            const int* __restrict__ rowstart, const float* __restrict__ degO,
                            const float* __restrict__ scale, const float* __restrict__ shift,
                            float* __restrict__ agg) {
  int row = blockIdx.x * 4 + threadIdx.y;
  int l = threadIdx.x;  // 0..63
  int s = rowstart[row], e = rowstart[row + 1];
  float2 sc = *(const float2*)&scale[l * 2];
  float2 sh = *(const float2*)&shift[l * 2];
  float ax = 0.f, ay = 0.f;
  int i = s;
  for (; i + 3 < e; i += 4) {
    int s0 = csr[i], s1 = csr[i + 1], s2 = csr[i + 2], s3 = csr[i + 3];
    float i0 = rsqrtf(fmaxf(degO[s0], 1.0f));
    float i1 = rsqrtf(fmaxf(degO[s1], 1.0f));
    float i2 = rsqrtf(fmaxf(degO[s2], 1.0f));
    float i3 = rsqrtf(fmaxf(degO[s3], 1.0f));
    float2 v0 = *(const float2*)&x[(size_t)s0 * DIM + l * 2];
    float2 v1 = *(const float2*)&x[(size_t)s1 * DIM + l * 2];
    float2 v2 = *(const float2*)&x[(size_t)s2 * DIM + l * 2];
    float2 v3 = *(const float2*)&x[(size_t)s3 * DIM + l * 2];
    ax += (v0.x * sc.x + sh.x) * i0 + (v1.x * sc.x + sh.x) * i1
        + (v2.x * sc.x + sh.x) * i2 + (v3.x * sc.x + sh.x) * i3;
    ay += (v0.y * sc.y + sh.y) * i0 + (v1.y * sc.y + sh.y) * i1
        + (v2.y * sc.y + sh.y) * i2 + (v3.y * sc.y + sh.y) * i3;
  }
  for (; i < e; ++i) {
    int s0 = csr[i];
    float i0 = rsqrtf(fmaxf(degO[s0], 1.0f));
    float2 v0 = *(const float2*)&x[(size_t)s0 * DIM + l * 2];
    ax += (v0.x * sc.x + sh.x) * i0;
    ay += (v0.y * sc.y + sh.y) * i0;
  }
  float isi = rsqrtf(fmaxf((float)(e - s), 1.0f));  // in-degree = rowstart diff
  float2 o = {ax * isi, ay * isi};
  *(float2*)&agg[(size_t)row * DIM + l * 2] = o;
}

// ---------------------------------------------------------------- conv: agg@W + b, relu, +res
// 32x128 tile, 256 threads, 4x4 per thread in NAMED float4 accumulators (no scratch)
__launch_bounds__(256, 4)
__global__ void k_conv(const float* __restrict__ agg, const float* __restrict__ W,
                       const float* __restrict__ bias, const float* __restrict__ hres,
                       float* __restrict__ outp) {
  __shared__ float As[32][DIM];   // 16 KB
  __shared__ float Ws[32][DIM];   // 16 KB
  int t = threadIdx.x;
  int row0 = blockIdx.x * 32;     // 3125 * 32 == 100000 exactly

  for (int i = t * 4; i < 32 * DIM; i += 1024) {
    *(float4*)&As[i >> 7][i & 127] = *(const float4*)&agg[(size_t)(row0 + (i >> 7)) * DIM + (i & 127)];
  }

  int tx = t & 31, ty = t >> 5;
  int c0 = tx * 4, r0 = ty * 4;
  float4 acc0 = {0.f,0.f,0.f,0.f}, acc1 = {0.f,0.f,0.f,0.f};
  float4 acc2 = {0.f,0.f,0.f,0.f}, acc3 = {0.f,0.f,0.f,0.f};

  for (int k0 = 0; k0 < DIM; k0 += 32) {
    __syncthreads();
    for (int i = t * 4; i < 32 * DIM; i += 1024) {
      *(float4*)&Ws[i >> 7][i & 127] = *(const float4*)&W[(size_t)(k0 + (i >> 7)) * DIM + (i & 127)];
    }
    __syncthreads();
#pragma unroll 4
    for (int k = 0; k < 32; k += 4) {
      float4 w0 = *(float4*)&Ws[k + 0][c0];
      float4 w1 = *(float4*)&Ws[k + 1][c0];
      float4 w2 = *(float4*)&Ws[k + 2][c0];
      float4 w3 = *(float4*)&Ws[k + 3][c0];
      float4 a0 = *(float4*)&As[r0 + 0][k0 + k];
      float4 a1 = *(float4*)&As[r0 + 1][k0 + k];
      float4 a2 = *(float4*)&As[r0 + 2][k0 + k];
      float4 a3 = *(float4*)&As[r0 + 3][k0 + k];
      acc0.x += a0.x*w0.x + a0.y*w1.x + a0.z*w2.x + a0.w*w3.x;
      acc0.y += a0.x*w0.y + a0.y*w1.y + a0.z*w2.y + a0.w*w3.y;
      acc0.z += a0.x*w0.z + a0.y*w1.z + a0.z*w2.z + a0.w*w3.z;
      acc0.w += a0.x*w0.w + a0.y*w1.w + a0.z*w2.w + a0.w*w3.w;
      acc1.x += a1.x*w0.x + a1.y*w1.x + a1.z*w2.x + a1.w*w3.x;
      acc1.y += a1.x*w0.y + a1.y*w1.y + a1.z*w2.y + a1.w*w3.y;
      acc1.z += a1.x*w0.z + a1.y*w1.z + a1.z*w2.z + a1.w*w3.z;
      acc1.w += a1.x*w0.w + a1.y*w1.w + a1.z*w2.w + a1.w*w3.w;
      acc2.x += a2.x*w0.x + a2.y*w1.x + a2.z*w2.x + a2.w*w3.x;
      acc2.y += a2.x*w0.y + a2.y*w1.y + a2.z*w2.y + a2.w*w3.y;
      acc2.z += a2.x*w0.z + a2.y*w1.z + a2.z*w2.z + a2.w*w3.z;
      acc2.w += a2.x*w0.w + a2.y*w1.w + a2.z*w2.w + a2.w*w3.w;
      acc3.x += a3.x*w0.x + a3.y*w1.x + a3.z*w2.x + a3.w*w3.x;
      acc3.y += a3.x*w0.y + a3.y*w1.y + a3.z*w2.y + a3.w*w3.y;
      acc3.z += a3.x*w0.z + a3.y*w1.z + a3.z*w2.z + a3.w*w3.z;
      acc3.w += a3.x*w0.w + a3.y*w1.w + a3.z*w2.w + a3.w*w3.w;
    }
  }

  float4 bv = *(const float4*)&bias[c0];
  {
    int row = row0 + r0 + 0;
    float4 hv = *(const float4*)&hres[(size_t)row * DIM + c0];
    float4 o = {hv.x + fmaxf(acc0.x + bv.x, 0.f), hv.y + fmaxf(acc0.y + bv.y, 0.f),
                hv.z + fmaxf(acc0.z + bv.z, 0.f), hv.w + fmaxf(acc0.w + bv.w, 0.f)};
    *(float4*)&outp[(size_t)row * DIM + c0] = o;
  }
  {
    int row = row0 + r0 + 1;
    float4 hv = *(const float4*)&hres[(size_t)row * DIM + c0];
    float4 o = {hv.x + fmaxf(acc1.x + bv.x, 0.f), hv.y + fmaxf(acc1.y + bv.y, 0.f),
                hv.z + fmaxf(acc1.z + bv.z, 0.f), hv.w + fmaxf(acc1.w + bv.w, 0.f)};
    *(float4*)&outp[(size_t)row * DIM + c0] = o;
  }
  {
    int row = row0 + r0 + 2;
    float4 hv = *(const float4*)&hres[(size_t)row * DIM + c0];
    float4 o = {hv.x + fmaxf(acc2.x + bv.x, 0.f), hv.y + fmaxf(acc2.y + bv.y, 0.f),
                hv.z + fmaxf(acc2.z + bv.z, 0.f), hv.w + fmaxf(acc2.w + bv.w, 0.f)};
    *(float4*)&outp[(size_t)row * DIM + c0] = o;
  }
  {
    int row = row0 + r0 + 3;
    float4 hv = *(const float4*)&hres[(size_t)row * DIM + c0];
    float4 o = {hv.x + fmaxf(acc3.x + bv.x, 0.f), hv.y + fmaxf(acc3.y + bv.y, 0.f),
                hv.z + fmaxf(acc3.z + bv.z, 0.f), hv.w + fmaxf(acc3.w + bv.w, 0.f)};
    *(float4*)&outp[(size_t)row * DIM + c0] = o;
  }
}

// ---------------------------------------------------------------- gate = h2 @ gate_W + gate_b
__global__ void k_gate(const float* __restrict__ h2, const float* __restrict__ gW,
                       const float* __restrict__ gb, float* __restrict__ gate) {
  int i = blockIdx.x * 4 + threadIdx.y;
  int l = threadIdx.x;
  float2 a = *(const float2*)&h2[(size_t)i * DIM + l * 2];
  float2 w = *(const float2*)&gW[l * 2];
  float v = a.x * w.x + a.y * w.y;
  for (int off = 32; off; off >>= 1) v += __shfl_down(v, off);
  if (l == 0) gate[i] = v + gb[0];
}

// ---------------------------------------------------------------- per-graph softmax stats
__global__ void k_gstats(const float* __restrict__ gate, const int* __restrict__ starts,
                         float* __restrict__ gmax, float* __restrict__ gden) {
  int g = blockIdx.x;
  int s = starts[g], e = starts[g + 1];
  int t = threadIdx.x;
  __shared__ float red[256];
  float m = -INFINITY;
  for (int i = s + t; i < e; i += 256) m = fmaxf(m, gate[i]);
  red[t] = m; __syncthreads();
  for (int w = 128; w; w >>= 1) { if (t < w) red[t] = fmaxf(red[t], red[t + w]); __syncthreads(); }
  float mg = red[0]; __syncthreads();
  float ssum = 0.f;
  for (int i = s + t; i < e; i += 256) ssum += expf(gate[i] - mg);
  red[t] = ssum; __syncthreads();
  for (int w = 128; w; w >>= 1) { if (t < w) red[t] += red[t + w]; __syncthreads(); }
  if (t == 0) { gmax[g] = mg; gden[g] = red[0]; }
}

// ---------------------------------------------------------------- weighted pooling
__global__ void k_pool(const float* __restrict__ h2, const float* __restrict__ gate,
                       const int* __restrict__ starts, const float* __restrict__ gmax,
                       const float* __restrict__ gden, float* __restrict__ outp) {
  int g = blockIdx.x >> 3, part = blockIdx.x & 7;
  int s = starts[g], e = starts[g + 1];
  int d = threadIdx.x;
  float mg = gmax[g];
  float dn = gden[g];
  float invden = dn > 0.f ? 1.0f / dn : 0.f;
  float acc = 0.f;
  for (int i = s + part; i < e; i += 8) {
    float w = expf(gate[i] - mg) * invden;
    acc += w * h2[(size_t)i * DIM + d];
  }
  atomicAdd(&outp[g * DIM + d], acc);
}

// ---------------------------------------------------------------- launch
extern "C" void kernel_launch(void* const* d_in, const int* in_sizes, int n_in,
                              void* d_out, int out_size, void* d_ws, size_t ws_size,
                              hipStream_t stream) {
  const float* h    = (const float*)d_in[0];
  const int*   src  = (const int*)d_in[1];
  const int*   dst  = (const int*)d_in[2];
  const int*   gid  = (const int*)d_in[3];
  const float* W1   = (const float*)d_in[5];
  const float* b1   = (const float*)d_in[6];
  const float* W2   = (const float*)d_in[7];
  const float* b2   = (const float*)d_in[8];
  const float* gW   = (const float*)d_in[9];
  const float* gb   = (const float*)d_in[10];
  const float* gamma= (const float*)d_in[11];
  const float* beta = (const float*)d_in[12];
  float* out = (float*)d_out;

  char* ws = (char*)d_ws;
  float* agg     = (float*)ws; ws += (size_t)N_NODES * DIM * 4;
  float* h12     = (float*)ws; ws += (size_t)N_NODES * DIM * 4;
  int*   csr     = (int*)ws;   ws += (size_t)N_EDGES * 4;
  int*   rowstart= (int*)ws;   ws += (N_NODES + 1) * 4;
  int*   cnt     = (int*)ws;   ws += N_NODES * 4;
  int*   cursor  = (int*)ws;   ws += N_NODES * 4;
  float* degO    = (float*)ws; ws += N_NODES * 4;
  float* gate    = (float*)ws; ws += N_NODES * 4;
  float* sums    = (float*)ws; ws += 2 * DIM * 4;
  float* scale   = (float*)ws; ws += DIM * 4;
  float* shift   = (float*)ws; ws += DIM * 4;
  float* gmax    = (float*)ws; ws += NG * 4;
  float* gden    = (float*)ws; ws += NG * 4;
  int*   starts  = (int*)ws;   ws += (NG + 1) * 4;

  hipMemsetAsync(degO,   0, N_NODES * 4, stream);
  hipMemsetAsync(cnt,    0, N_NODES * 4, stream);
  hipMemsetAsync(cursor, 0, N_NODES * 4, stream);
  hipMemsetAsync(sums,   0, 2 * DIM * 4, stream);
  hipMemsetAsync(d_out,  0, (size_t)out_size * 4, stream);

  // graph structure (built once, used by both layers)
  k_deg<<<(N_EDGES + 255) / 256, 256, 0, stream>>>(src, dst, degO, cnt);
  k_scan<<<1, 1024, 0, stream>>>(cnt, rowstart);
  k_scatter<<<(N_EDGES + 255) / 256, 256, 0, stream>>>(src, dst, rowstart, cursor, csr);
  k_starts_init<<<1, NG + 1, 0, stream>>>(starts);
  k_starts_fill<<<(N_NODES + 255) / 256, 256, 0, stream>>>(gid, starts);

  // init_avg_h -> out[NG*DIM ..]
  k_seg_accum<<<NG * 8, DIM, 0, stream>>>(h, starts, out + NG * DIM);
  k_avg_div<<<NG, DIM, 0, stream>>>(starts, out + NG * DIM);

  // layer 1
  k_bnstats<<<(N_NODES + 511) / 512, dim3(128, 2), 0, stream>>>(h, sums);
  k_bnfin<<<1, DIM, 0, stream>>>(sums, gamma, beta, scale, shift);
  k_spmm_pull<<<N_NODES / 4, dim3(64, 4), 0, stream>>>(h, csr, rowstart, degO, scale, shift, agg);
  k_conv<<<N_NODES / 32, 256, 0, stream>>>(agg, W1, b1, h, h12);

  // layer 2
  hipMemsetAsync(sums, 0, 2 * DIM * 4, stream);
  k_bnstats<<<(N_NODES + 511) / 512, dim3(128, 2), 0, stream>>>(h12, sums);
  k_bnfin<<<1, DIM, 0, stream>>>(sums, gamma, beta, scale, shift);
  k_spmm_pull<<<N_NODES / 4, dim3(64, 4), 0, stream>>>(h12, csr, rowstart, degO, scale, shift, agg);
  k_conv<<<N_NODES / 32, 256, 0, stream>>>(agg, W2, b2, h12, h12);

  // pooling
  k_gate<<<N_NODES / 4, dim3(64, 4), 0, stream>>>(h12, gW, gb, gate);
  k_gstats<<<NG, 256, 0, stream>>>(gate, starts, gmax, gden);
  k_pool<<<NG * 8, DIM, 0, stream>>>(h12, gate, starts, gmax, gden, out);
}

// Round 4
// 921.951 us; speedup vs baseline: 8.0451x; 1.1667x over previous
//
#include <hip/hip_runtime.h>
#include <math.h>

#define N_NODES 100000
#define N_EDGES 1600000
#define DIM     128
#define NG      64
#define BN_EPS  1e-5f
#define NB      98   // scan blocks: 98*1024 >= 100000

// ---------------------------------------------------------------- degrees / in-counts
__global__ void k_deg(const int* __restrict__ src, const int* __restrict__ dst,
                      float* __restrict__ degO, int* __restrict__ cnt) {
  int e = blockIdx.x * blockDim.x + threadIdx.x;
  if (e < N_EDGES) {
    atomicAdd(&degO[src[e]], 1.0f);
    atomicAdd(&cnt[dst[e]], 1);
  }
}

// ---------------------------------------------------------------- 3-pass scan of cnt -> rowstart
__global__ void k_scan_part(const int* __restrict__ cnt, int* __restrict__ bsum) {
  int b = blockIdx.x, t = threadIdx.x;
  int base = b * 1024 + t * 4;
  int s = 0;
#pragma unroll
  for (int j = 0; j < 4; ++j) { int i = base + j; if (i < N_NODES) s += cnt[i]; }
  __shared__ int red[256];
  red[t] = s; __syncthreads();
  for (int w = 128; w; w >>= 1) { if (t < w) red[t] += red[t + w]; __syncthreads(); }
  if (t == 0) bsum[b] = red[0];
}

__global__ void k_scan_mid(const int* __restrict__ bsum, int* __restrict__ boff,
                           int* __restrict__ rowstart) {
  int t = threadIdx.x;  // 128 >= NB
  __shared__ int sh[128];
  int own = (t < NB) ? bsum[t] : 0;
  sh[t] = own;
  __syncthreads();
  for (int off = 1; off < 128; off <<= 1) {
    int v = (t >= off) ? sh[t - off] : 0;
    __syncthreads();
    sh[t] += v;
    __syncthreads();
  }
  if (t < NB) boff[t] = sh[t] - own;          // exclusive
  if (t == NB - 1) rowstart[N_NODES] = sh[t]; // total == N_EDGES
}

__global__ void k_scan_fin(const int* __restrict__ cnt, const int* __restrict__ boff,
                           int* __restrict__ rowstart) {
  int b = blockIdx.x, t = threadIdx.x;
  int base = b * 1024 + t * 4;
  int v0 = 0, v1 = 0, v2 = 0, v3 = 0;
  if (base + 0 < N_NODES) v0 = cnt[base + 0];
  if (base + 1 < N_NODES) v1 = cnt[base + 1];
  if (base + 2 < N_NODES) v2 = cnt[base + 2];
  if (base + 3 < N_NODES) v3 = cnt[base + 3];
  int tsum = v0 + v1 + v2 + v3;
  __shared__ int sh[256];
  sh[t] = tsum;
  __syncthreads();
  for (int off = 1; off < 256; off <<= 1) {
    int v = (t >= off) ? sh[t - off] : 0;
    __syncthreads();
    sh[t] += v;
    __syncthreads();
  }
  int run = boff[b] + sh[t] - tsum;  // exclusive across threads
  if (base + 0 < N_NODES) rowstart[base + 0] = run; run += v0;
  if (base + 1 < N_NODES) rowstart[base + 1] = run; run += v1;
  if (base + 2 < N_NODES) rowstart[base + 2] = run; run += v2;
  if (base + 3 < N_NODES) rowstart[base + 3] = run;
}

// ---------------------------------------------------------------- scatter edges into CSR by dst
__global__ void k_scatter(const int* __restrict__ src, const int* __restrict__ dst,
                          const int* __restrict__ rowstart, int* __restrict__ cursor,
                          int* __restrict__ csr) {
  int e = blockIdx.x * blockDim.x + threadIdx.x;
  if (e < N_EDGES) {
    int d = dst[e];
    int pos = rowstart[d] + atomicAdd(&cursor[d], 1);
    csr[pos] = src[e];
  }
}

// ---------------------------------------------------------------- graph CSR starts
__global__ void k_starts_init(int* __restrict__ starts) {
  int g = threadIdx.x;
  if (g <= NG) starts[g] = N_NODES;
}

__global__ void k_starts_fill(const int* __restrict__ gid, int* __restrict__ starts) {
  int i = blockIdx.x * blockDim.x + threadIdx.x;
  if (i >= N_NODES) return;
  int gi = gid[i];
  if (i == 0) {
    for (int g = 0; g <= gi; ++g) starts[g] = 0;
  } else {
    int gp = gid[i - 1];
    if (gp != gi) for (int g = gp + 1; g <= gi; ++g) starts[g] = i;
  }
}

// ---------------------------------------------------------------- init_avg accumulation
__global__ void k_seg_accum(const float* __restrict__ h, const int* __restrict__ starts,
                            float* __restrict__ outp) {
  int g = blockIdx.x >> 3, part = blockIdx.x & 7;
  int s = starts[g], e = starts[g + 1];
  int d = threadIdx.x;
  float acc = 0.f;
  for (int i = s + part; i < e; i += 8) acc += h[(size_t)i * DIM + d];
  atomicAdd(&outp[g * DIM + d], acc);
}

__global__ void k_avg_div(const int* __restrict__ starts, float* __restrict__ outp) {
  int g = blockIdx.x, d = threadIdx.x;
  float cnt = fmaxf((float)(starts[g + 1] - starts[g]), 1.0f);
  outp[g * DIM + d] /= cnt;
}

// ---------------------------------------------------------------- BN column stats
__global__ void k_bnstats(const float* __restrict__ x, float* __restrict__ sums) {
  int d = threadIdx.x;
  int r = blockIdx.x * 512 + threadIdx.y;
  int rend = min(blockIdx.x * 512 + 512, N_NODES);
  float s = 0.f, s2 = 0.f;
  for (; r < rend; r += 2) {
    float v = x[(size_t)r * DIM + d];
    s += v; s2 += v * v;
  }
  atomicAdd(&sums[d], s);
  atomicAdd(&sums[DIM + d], s2);
}

__global__ void k_bnfin(const float* __restrict__ sums, const float* __restrict__ gamma,
                        const float* __restrict__ beta, float* __restrict__ scale,
                        float* __restrict__ shift) {
  int d = threadIdx.x;
  float m = sums[d] * (1.0f / N_NODES);
  float v = sums[DIM + d] * (1.0f / N_NODES) - m * m;
  float rs = rsqrtf(fmaxf(v, 0.f) + BN_EPS) * gamma[d];
  scale[d] = rs;
  shift[d] = beta[d] - m * rs;
}

// ---------------------------------------------------------------- pull-mode SpMM
// one wave per dst row; two 32-lane halves process neighbors i, i+1 with float4 loads
__launch_bounds__(256, 8)
__global__ void k_spmm_pull(const float* __restrict__ x, const int* __restrict__ csr,
                            const int* __restrict__ rowstart, const float* __restrict__ degO,
                            const float* __restrict__ scale, const float* __restrict__ shift,
                            float* __restrict__ agg) {
  int row = blockIdx.x * 4 + threadIdx.y;
  int l = threadIdx.x;            // 0..63
  int half = l >> 5, l32 = l & 31;
  int s = rowstart[row], e = rowstart[row + 1];
  float4 sc = *(const float4*)&scale[l32 * 4];
  float4 sh = *(const float4*)&shift[l32 * 4];
  float4 acc = {0.f, 0.f, 0.f, 0.f};
  int i = s + half;
  for (; i + 2 < e; i += 4) {          // 2 neighbors per half per iter
    int s0 = csr[i], s1 = csr[i + 2];
    float i0 = rsqrtf(fmaxf(degO[s0], 1.0f));
    float i1 = rsqrtf(fmaxf(degO[s1], 1.0f));
    float4 v0 = *(const float4*)&x[(size_t)s0 * DIM + l32 * 4];
    float4 v1 = *(const float4*)&x[(size_t)s1 * DIM + l32 * 4];
    acc.x += (v0.x * sc.x + sh.x) * i0 + (v1.x * sc.x + sh.x) * i1;
    acc.y += (v0.y * sc.y + sh.y) * i0 + (v1.y * sc.y + sh.y) * i1;
    acc.z += (v0.z * sc.z + sh.z) * i0 + (v1.z * sc.z + sh.z) * i1;
    acc.w += (v0.w * sc.w + sh.w) * i0 + (v1.w * sc.w + sh.w) * i1;
  }
  if (i < e) {
    int s0 = csr[i];
    float i0 = rsqrtf(fmaxf(degO[s0], 1.0f));
    float4 v0 = *(const float4*)&x[(size_t)s0 * DIM + l32 * 4];
    acc.x += (v0.x * sc.x + sh.x) * i0;
    acc.y += (v0.y * sc.y + sh.y) * i0;
    acc.z += (v0.z * sc.z + sh.z) * i0;
    acc.w += (v0.w * sc.w + sh.w) * i0;
  }
  acc.x += __shfl_xor(acc.x, 32);
  acc.y += __shfl_xor(acc.y, 32);
  acc.z += __shfl_xor(acc.z, 32);
  acc.w += __shfl_xor(acc.w, 32);
  if (half == 0) {
    float isi = rsqrtf(fmaxf((float)(e - s), 1.0f));
    float4 o = {acc.x * isi, acc.y * isi, acc.z * isi, acc.w * isi};
    *(float4*)&agg[(size_t)row * DIM + l32 * 4] = o;
  }
}

// ---------------------------------------------------------------- conv: agg@W + b, relu, +res
__launch_bounds__(256, 4)
__global__ void k_conv(const float* __restrict__ agg, const float* __restrict__ W,
                       const float* __restrict__ bias, const float* __restrict__ hres,
                       float* __restrict__ outp) {
  __shared__ float As[32][DIM];
  __shared__ float Ws[32][DIM];
  int t = threadIdx.x;
  int row0 = blockIdx.x * 32;

  for (int i = t * 4; i < 32 * DIM; i += 1024) {
    *(float4*)&As[i >> 7][i & 127] = *(const float4*)&agg[(size_t)(row0 + (i >> 7)) * DIM + (i & 127)];
  }

  int tx = t & 31, ty = t >> 5;
  int c0 = tx * 4, r0 = ty * 4;
  float4 acc0 = {0.f,0.f,0.f,0.f}, acc1 = {0.f,0.f,0.f,0.f};
  float4 acc2 = {0.f,0.f,0.f,0.f}, acc3 = {0.f,0.f,0.f,0.f};

  for (int k0 = 0; k0 < DIM; k0 += 32) {
    __syncthreads();
    for (int i = t * 4; i < 32 * DIM; i += 1024) {
      *(float4*)&Ws[i >> 7][i & 127] = *(const float4*)&W[(size_t)(k0 + (i >> 7)) * DIM + (i & 127)];
    }
    __syncthreads();
#pragma unroll 4
    for (int k = 0; k < 32; k += 4) {
      float4 w0 = *(float4*)&Ws[k + 0][c0];
      float4 w1 = *(float4*)&Ws[k + 1][c0];
      float4 w2 = *(float4*)&Ws[k + 2][c0];
      float4 w3 = *(float4*)&Ws[k + 3][c0];
      float4 a0 = *(float4*)&As[r0 + 0][k0 + k];
      float4 a1 = *(float4*)&As[r0 + 1][k0 + k];
      float4 a2 = *(float4*)&As[r0 + 2][k0 + k];
      float4 a3 = *(float4*)&As[r0 + 3][k0 + k];
      acc0.x += a0.x*w0.x + a0.y*w1.x + a0.z*w2.x + a0.w*w3.x;
      acc0.y += a0.x*w0.y + a0.y*w1.y + a0.z*w2.y + a0.w*w3.y;
      acc0.z += a0.x*w0.z + a0.y*w1.z + a0.z*w2.z + a0.w*w3.z;
      acc0.w += a0.x*w0.w + a0.y*w1.w + a0.z*w2.w + a0.w*w3.w;
      acc1.x += a1.x*w0.x + a1.y*w1.x + a1.z*w2.x + a1.w*w3.x;
      acc1.y += a1.x*w0.y + a1.y*w1.y + a1.z*w2.y + a1.w*w3.y;
      acc1.z += a1.x*w0.z + a1.y*w1.z + a1.z*w2.z + a1.w*w3.z;
      acc1.w += a1.x*w0.w + a1.y*w1.w + a1.z*w2.w + a1.w*w3.w;
      acc2.x += a2.x*w0.x + a2.y*w1.x + a2.z*w2.x + a2.w*w3.x;
      acc2.y += a2.x*w0.y + a2.y*w1.y + a2.z*w2.y + a2.w*w3.y;
      acc2.z += a2.x*w0.z + a2.y*w1.z + a2.z*w2.z + a2.w*w3.z;
      acc2.w += a2.x*w0.w + a2.y*w1.w + a2.z*w2.w + a2.w*w3.w;
      acc3.x += a3.x*w0.x + a3.y*w1.x + a3.z*w2.x + a3.w*w3.x;
      acc3.y += a3.x*w0.y + a3.y*w1.y + a3.z*w2.y + a3.w*w3.y;
      acc3.z += a3.x*w0.z + a3.y*w1.z + a3.z*w2.z + a3.w*w3.z;
      acc3.w += a3.x*w0.w + a3.y*w1.w + a3.z*w2.w + a3.w*w3.w;
    }
  }

  float4 bv = *(const float4*)&bias[c0];
  {
    int row = row0 + r0 + 0;
    float4 hv = *(const float4*)&hres[(size_t)row * DIM + c0];
    float4 o = {hv.x + fmaxf(acc0.x + bv.x, 0.f), hv.y + fmaxf(acc0.y + bv.y, 0.f),
                hv.z + fmaxf(acc0.z + bv.z, 0.f), hv.w + fmaxf(acc0.w + bv.w, 0.f)};
    *(float4*)&outp[(size_t)row * DIM + c0] = o;
  }
  {
    int row = row0 + r0 + 1;
    float4 hv = *(const float4*)&hres[(size_t)row * DIM + c0];
    float4 o = {hv.x + fmaxf(acc1.x + bv.x, 0.f), hv.y + fmaxf(acc1.y + bv.y, 0.f),
                hv.z + fmaxf(acc1.z + bv.z, 0.f), hv.w + fmaxf(acc1.w + bv.w, 0.f)};
    *(float4*)&outp[(size_t)row * DIM + c0] = o;
  }
  {
    int row = row0 + r0 + 2;
    float4 hv = *(const float4*)&hres[(size_t)row * DIM + c0];
    float4 o = {hv.x + fmaxf(acc2.x + bv.x, 0.f), hv.y + fmaxf(acc2.y + bv.y, 0.f),
                hv.z + fmaxf(acc2.z + bv.z, 0.f), hv.w + fmaxf(acc2.w + bv.w, 0.f)};
    *(float4*)&outp[(size_t)row * DIM + c0] = o;
  }
  {
    int row = row0 + r0 + 3;
    float4 hv = *(const float4*)&hres[(size_t)row * DIM + c0];
    float4 o = {hv.x + fmaxf(acc3.x + bv.x, 0.f), hv.y + fmaxf(acc3.y + bv.y, 0.f),
                hv.z + fmaxf(acc3.z + bv.z, 0.f), hv.w + fmaxf(acc3.w + bv.w, 0.f)};
    *(float4*)&outp[(size_t)row * DIM + c0] = o;
  }
}

// ---------------------------------------------------------------- gate = h2 @ gate_W + gate_b
__global__ void k_gate(const float* __restrict__ h2, const float* __restrict__ gW,
                       const float* __restrict__ gb, float* __restrict__ gate) {
  int i = blockIdx.x * 4 + threadIdx.y;
  int l = threadIdx.x;
  float2 a = *(const float2*)&h2[(size_t)i * DIM + l * 2];
  float2 w = *(const float2*)&gW[l * 2];
  float v = a.x * w.x + a.y * w.y;
  for (int off = 32; off; off >>= 1) v += __shfl_down(v, off);
  if (l == 0) gate[i] = v + gb[0];
}

// ---------------------------------------------------------------- per-graph softmax stats
__global__ void k_gstats(const float* __restrict__ gate, const int* __restrict__ starts,
                         float* __restrict__ gmax, float* __restrict__ gden) {
  int g = blockIdx.x;
  int s = starts[g], e = starts[g + 1];
  int t = threadIdx.x;
  __shared__ float red[256];
  float m = -INFINITY;
  for (int i = s + t; i < e; i += 256) m = fmaxf(m, gate[i]);
  red[t] = m; __syncthreads();
  for (int w = 128; w; w >>= 1) { if (t < w) red[t] = fmaxf(red[t], red[t + w]); __syncthreads(); }
  float mg = red[0]; __syncthreads();
  float ssum = 0.f;
  for (int i = s + t; i < e; i += 256) ssum += expf(gate[i] - mg);
  red[t] = ssum; __syncthreads();
  for (int w = 128; w; w >>= 1) { if (t < w) red[t] += red[t + w]; __syncthreads(); }
  if (t == 0) { gmax[g] = mg; gden[g] = red[0]; }
}

// ---------------------------------------------------------------- weighted pooling
__global__ void k_pool(const float* __restrict__ h2, const float* __restrict__ gate,
                       const int* __restrict__ starts, const float* __restrict__ gmax,
                       const float* __restrict__ gden, float* __restrict__ outp) {
  int g = blockIdx.x >> 3, part = blockIdx.x & 7;
  int s = starts[g], e = starts[g + 1];
  int d = threadIdx.x;
  float mg = gmax[g];
  float dn = gden[g];
  float invden = dn > 0.f ? 1.0f / dn : 0.f;
  float acc = 0.f;
  for (int i = s + part; i < e; i += 8) {
    float w = expf(gate[i] - mg) * invden;
    acc += w * h2[(size_t)i * DIM + d];
  }
  atomicAdd(&outp[g * DIM + d], acc);
}

// ---------------------------------------------------------------- launch
extern "C" void kernel_launch(void* const* d_in, const int* in_sizes, int n_in,
                              void* d_out, int out_size, void* d_ws, size_t ws_size,
                              hipStream_t stream) {
  const float* h    = (const float*)d_in[0];
  const int*   src  = (const int*)d_in[1];
  const int*   dst  = (const int*)d_in[2];
  const int*   gid  = (const int*)d_in[3];
  const float* W1   = (const float*)d_in[5];
  const float* b1   = (const float*)d_in[6];
  const float* W2   = (const float*)d_in[7];
  const float* b2   = (const float*)d_in[8];
  const float* gW   = (const float*)d_in[9];
  const float* gb   = (const float*)d_in[10];
  const float* gamma= (const float*)d_in[11];
  const float* beta = (const float*)d_in[12];
  float* out = (float*)d_out;

  char* ws = (char*)d_ws;
  float* agg     = (float*)ws; ws += (size_t)N_NODES * DIM * 4;
  float* h12     = (float*)ws; ws += (size_t)N_NODES * DIM * 4;
  int*   csr     = (int*)ws;   ws += (size_t)N_EDGES * 4;
  int*   rowstart= (int*)ws;   ws += (N_NODES + 1) * 4;
  int*   cnt     = (int*)ws;   ws += N_NODES * 4;
  int*   cursor  = (int*)ws;   ws += N_NODES * 4;
  float* degO    = (float*)ws; ws += N_NODES * 4;
  float* gate    = (float*)ws; ws += N_NODES * 4;
  float* sums    = (float*)ws; ws += 2 * DIM * 4;
  float* scale   = (float*)ws; ws += DIM * 4;
  float* shift   = (float*)ws; ws += DIM * 4;
  float* gmax    = (float*)ws; ws += NG * 4;
  float* gden    = (float*)ws; ws += NG * 4;
  int*   starts  = (int*)ws;   ws += (NG + 1) * 4;
  int*   bsum    = (int*)ws;   ws += NB * 4;
  int*   boff    = (int*)ws;   ws += NB * 4;

  hipMemsetAsync(degO,   0, N_NODES * 4, stream);
  hipMemsetAsync(cnt,    0, N_NODES * 4, stream);
  hipMemsetAsync(cursor, 0, N_NODES * 4, stream);
  hipMemsetAsync(sums,   0, 2 * DIM * 4, stream);
  hipMemsetAsync(d_out,  0, (size_t)out_size * 4, stream);

  // graph structure (built once, used by both layers)
  k_deg<<<(N_EDGES + 255) / 256, 256, 0, stream>>>(src, dst, degO, cnt);
  k_scan_part<<<NB, 256, 0, stream>>>(cnt, bsum);
  k_scan_mid<<<1, 128, 0, stream>>>(bsum, boff, rowstart);
  k_scan_fin<<<NB, 256, 0, stream>>>(cnt, boff, rowstart);
  k_scatter<<<(N_EDGES + 255) / 256, 256, 0, stream>>>(src, dst, rowstart, cursor, csr);
  k_starts_init<<<1, NG + 1, 0, stream>>>(starts);
  k_starts_fill<<<(N_NODES + 255) / 256, 256, 0, stream>>>(gid, starts);

  // init_avg_h -> out[NG*DIM ..]
  k_seg_accum<<<NG * 8, DIM, 0, stream>>>(h, starts, out + NG * DIM);
  k_avg_div<<<NG, DIM, 0, stream>>>(starts, out + NG * DIM);

  // layer 1
  k_bnstats<<<(N_NODES + 511) / 512, dim3(128, 2), 0, stream>>>(h, sums);
  k_bnfin<<<1, DIM, 0, stream>>>(sums, gamma, beta, scale, shift);
  k_spmm_pull<<<N_NODES / 4, dim3(64, 4), 0, stream>>>(h, csr, rowstart, degO, scale, shift, agg);
  k_conv<<<N_NODES / 32, 256, 0, stream>>>(agg, W1, b1, h, h12);

  // layer 2
  hipMemsetAsync(sums, 0, 2 * DIM * 4, stream);
  k_bnstats<<<(N_NODES + 511) / 512, dim3(128, 2), 0, stream>>>(h12, sums);
  k_bnfin<<<1, DIM, 0, stream>>>(sums, gamma, beta, scale, shift);
  k_spmm_pull<<<N_NODES / 4, dim3(64, 4), 0, stream>>>(h12, csr, rowstart, degO, scale, shift, agg);
  k_conv<<<N_NODES / 32, 256, 0, stream>>>(agg, W2, b2, h12, h12);

  // pooling
  k_gate<<<N_NODES / 4, dim3(64, 4), 0, stream>>>(h12, gW, gb, gate);
  k_gstats<<<NG, 256, 0, stream>>>(gate, starts, gmax, gden);
  k_pool<<<NG * 8, DIM, 0, stream>>>(h12, gate, starts, gmax, gden, out);
}

// Round 6
// 763.620 us; speedup vs baseline: 9.7132x; 1.2073x over previous
//
#include <hip/hip_runtime.h>
#include <math.h>

#define N_NODES 100000
#define N_EDGES 1600000
#define DIM     128
#define NG      64
#define BN_EPS  1e-5f
#define NB      98     // scan blocks
#define HRANGE  12500  // nodes per histogram range (50 KB LDS)
#define HNBLK   8      // blocks per range

// ---------------------------------------------------------------- out-degree histogram (LDS ranges, coalesced merge)
__launch_bounds__(256)
__global__ void k_histO(const int* __restrict__ src, int* __restrict__ cntO) {
  __shared__ int histo[HRANGE];   // 50 KB
  int t = threadIdx.x;
  int range = blockIdx.x >> 3, blk = blockIdx.x & 7;
  int lo = range * HRANGE;
  for (int j = t; j < HRANGE; j += 256) histo[j] = 0;
  __syncthreads();
  const int SLICE = N_EDGES / HNBLK;            // 200000
  const int4* sp = (const int4*)(src + blk * SLICE);
  const int n4 = SLICE / 4;                     // 50000
  for (int q = t; q < n4; q += 256) {
    int4 v = sp[q];
    unsigned a = (unsigned)(v.x - lo), b = (unsigned)(v.y - lo);
    unsigned c = (unsigned)(v.z - lo), d = (unsigned)(v.w - lo);
    if (a < (unsigned)HRANGE) atomicAdd(&histo[a], 1);
    if (b < (unsigned)HRANGE) atomicAdd(&histo[b], 1);
    if (c < (unsigned)HRANGE) atomicAdd(&histo[c], 1);
    if (d < (unsigned)HRANGE) atomicAdd(&histo[d], 1);
  }
  __syncthreads();
  for (int j = t; j < HRANGE; j += 256) {
    int v = histo[j];
    if (v) atomicAdd(&cntO[lo + j], v);
  }
}

// ---------------------------------------------------------------- in-degree count + per-edge rank (atomic return)
__global__ void k_rank(const int* __restrict__ dst, int* __restrict__ cnt,
                       int* __restrict__ rank) {
  int e = blockIdx.x * blockDim.x + threadIdx.x;
  if (e < N_EDGES) rank[e] = atomicAdd(&cnt[dst[e]], 1);
}

// ---------------------------------------------------------------- isrO = rsqrt(max(outdeg,1))
__global__ void k_isrO(const int* __restrict__ cntO, float* __restrict__ isrO) {
  int i = blockIdx.x * blockDim.x + threadIdx.x;
  if (i < N_NODES) isrO[i] = rsqrtf(fmaxf((float)cntO[i], 1.0f));
}

// ---------------------------------------------------------------- 3-pass scan of cnt -> rowstart
__global__ void k_scan_part(const int* __restrict__ cnt, int* __restrict__ bsum) {
  int b = blockIdx.x, t = threadIdx.x;
  int base = b * 1024 + t * 4;
  int s = 0;
#pragma unroll
  for (int j = 0; j < 4; ++j) { int i = base + j; if (i < N_NODES) s += cnt[i]; }
  __shared__ int red[256];
  red[t] = s; __syncthreads();
  for (int w = 128; w; w >>= 1) { if (t < w) red[t] += red[t + w]; __syncthreads(); }
  if (t == 0) bsum[b] = red[0];
}

__global__ void k_scan_mid(const int* __restrict__ bsum, int* __restrict__ boff,
                           int* __restrict__ rowstart) {
  int t = threadIdx.x;  // 128 >= NB
  __shared__ int sh[128];
  int own = (t < NB) ? bsum[t] : 0;
  sh[t] = own;
  __syncthreads();
  for (int off = 1; off < 128; off <<= 1) {
    int v = (t >= off) ? sh[t - off] : 0;
    __syncthreads();
    sh[t] += v;
    __syncthreads();
  }
  if (t < NB) boff[t] = sh[t] - own;
  if (t == NB - 1) rowstart[N_NODES] = sh[t];
}

__global__ void k_scan_fin(const int* __restrict__ cnt, const int* __restrict__ boff,
                           int* __restrict__ rowstart) {
  int b = blockIdx.x, t = threadIdx.x;
  int base = b * 1024 + t * 4;
  int v0 = 0, v1 = 0, v2 = 0, v3 = 0;
  if (base + 0 < N_NODES) v0 = cnt[base + 0];
  if (base + 1 < N_NODES) v1 = cnt[base + 1];
  if (base + 2 < N_NODES) v2 = cnt[base + 2];
  if (base + 3 < N_NODES) v3 = cnt[base + 3];
  int tsum = v0 + v1 + v2 + v3;
  __shared__ int sh[256];
  sh[t] = tsum;
  __syncthreads();
  for (int off = 1; off < 256; off <<= 1) {
    int v = (t >= off) ? sh[t - off] : 0;
    __syncthreads();
    sh[t] += v;
    __syncthreads();
  }
  int run = boff[b] + sh[t] - tsum;
  if (base + 0 < N_NODES) rowstart[base + 0] = run; run += v0;
  if (base + 1 < N_NODES) rowstart[base + 1] = run; run += v1;
  if (base + 2 < N_NODES) rowstart[base + 2] = run; run += v2;
  if (base + 3 < N_NODES) rowstart[base + 3] = run;
}

// ---------------------------------------------------------------- scatter (NO atomics: rank precomputed)
__global__ void k_scatter(const int* __restrict__ src, const int* __restrict__ dst,
                          const int* __restrict__ rowstart, const int* __restrict__ rank,
                          int* __restrict__ csr) {
  int e = blockIdx.x * blockDim.x + threadIdx.x;
  if (e < N_EDGES) {
    int d = dst[e];
    csr[rowstart[d] + rank[e]] = src[e];
  }
}

// ---------------------------------------------------------------- graph CSR starts
__global__ void k_starts_init(int* __restrict__ starts) {
  int g = threadIdx.x;
  if (g <= NG) starts[g] = N_NODES;
}

__global__ void k_starts_fill(const int* __restrict__ gid, int* __restrict__ starts) {
  int i = blockIdx.x * blockDim.x + threadIdx.x;
  if (i >= N_NODES) return;
  int gi = gid[i];
  if (i == 0) {
    for (int g = 0; g <= gi; ++g) starts[g] = 0;
  } else {
    int gp = gid[i - 1];
    if (gp != gi) for (int g = gp + 1; g <= gi; ++g) starts[g] = i;
  }
}

// ---------------------------------------------------------------- init_avg accumulation
__global__ void k_seg_accum(const float* __restrict__ h, const int* __restrict__ starts,
                            float* __restrict__ outp) {
  int g = blockIdx.x >> 3, part = blockIdx.x & 7;
  int s = starts[g], e = starts[g + 1];
  int d = threadIdx.x;
  float acc = 0.f;
  for (int i = s + part; i < e; i += 8) acc += h[(size_t)i * DIM + d];
  atomicAdd(&outp[g * DIM + d], acc);
}

__global__ void k_avg_div(const int* __restrict__ starts, float* __restrict__ outp) {
  int g = blockIdx.x, d = threadIdx.x;
  float cnt = fmaxf((float)(starts[g + 1] - starts[g]), 1.0f);
  outp[g * DIM + d] /= cnt;
}

// ---------------------------------------------------------------- BN column stats (float4 + LDS reduce)
__launch_bounds__(256)
__global__ void k_bnstats(const float* __restrict__ x, float* __restrict__ sums) {
  __shared__ float ls[8][DIM];
  __shared__ float ls2[8][DIM];
  int t = threadIdx.x;
  int col4 = (t & 31) * 4, rg = t >> 5;
  float4 s = {0.f,0.f,0.f,0.f}, s2 = {0.f,0.f,0.f,0.f};
  int rend = min(blockIdx.x * 1024 + 1024, N_NODES);
  for (int r = blockIdx.x * 1024 + rg; r < rend; r += 8) {
    float4 v = *(const float4*)&x[(size_t)r * DIM + col4];
    s.x += v.x; s.y += v.y; s.z += v.z; s.w += v.w;
    s2.x += v.x*v.x; s2.y += v.y*v.y; s2.z += v.z*v.z; s2.w += v.w*v.w;
  }
  *(float4*)&ls[rg][col4] = s;
  *(float4*)&ls2[rg][col4] = s2;
  __syncthreads();
  if (t < DIM) {
    float a = 0.f, b = 0.f;
#pragma unroll
    for (int j = 0; j < 8; ++j) { a += ls[j][t]; b += ls2[j][t]; }
    atomicAdd(&sums[t], a);
    atomicAdd(&sums[DIM + t], b);
  }
}

__global__ void k_bnfin(const float* __restrict__ sums, const float* __restrict__ gamma,
                        const float* __restrict__ beta, float* __restrict__ scale,
                        float* __restrict__ shift) {
  int d = threadIdx.x;
  float m = sums[d] * (1.0f / N_NODES);
  float v = sums[DIM + d] * (1.0f / N_NODES) - m * m;
  float rs = rsqrtf(fmaxf(v, 0.f) + BN_EPS) * gamma[d];
  scale[d] = rs;
  shift[d] = beta[d] - m * rs;
}

// ---------------------------------------------------------------- pull-mode SpMM (4 neighbors in flight per half)
__launch_bounds__(256, 8)
__global__ void k_spmm_pull(const float* __restrict__ x, const int* __restrict__ csr,
                            const int* __restrict__ rowstart, const float* __restrict__ isrO,
                            const float* __restrict__ scale, const float* __restrict__ shift,
                            float* __restrict__ agg) {
  int row = blockIdx.x * 4 + threadIdx.y;
  int l = threadIdx.x;            // 0..63
  int half = l >> 5, l32 = l & 31;
  int s = rowstart[row], e = rowstart[row + 1];
  float4 sc = *(const float4*)&scale[l32 * 4];
  float4 sh = *(const float4*)&shift[l32 * 4];
  float4 acc = {0.f, 0.f, 0.f, 0.f};
  int i = s + half;
  for (; i + 6 < e; i += 8) {          // 4 neighbors per half per iter
    int s0 = csr[i], s1 = csr[i + 2], s2 = csr[i + 4], s3 = csr[i + 6];
    float f0 = isrO[s0], f1 = isrO[s1], f2 = isrO[s2], f3 = isrO[s3];
    float4 v0 = *(const float4*)&x[(size_t)s0 * DIM + l32 * 4];
    float4 v1 = *(const float4*)&x[(size_t)s1 * DIM + l32 * 4];
    float4 v2 = *(const float4*)&x[(size_t)s2 * DIM + l32 * 4];
    float4 v3 = *(const float4*)&x[(size_t)s3 * DIM + l32 * 4];
    acc.x += (v0.x*sc.x+sh.x)*f0 + (v1.x*sc.x+sh.x)*f1 + (v2.x*sc.x+sh.x)*f2 + (v3.x*sc.x+sh.x)*f3;
    acc.y += (v0.y*sc.y+sh.y)*f0 + (v1.y*sc.y+sh.y)*f1 + (v2.y*sc.y+sh.y)*f2 + (v3.y*sc.y+sh.y)*f3;
    acc.z += (v0.z*sc.z+sh.z)*f0 + (v1.z*sc.z+sh.z)*f1 + (v2.z*sc.z+sh.z)*f2 + (v3.z*sc.z+sh.z)*f3;
    acc.w += (v0.w*sc.w+sh.w)*f0 + (v1.w*sc.w+sh.w)*f1 + (v2.w*sc.w+sh.w)*f2 + (v3.w*sc.w+sh.w)*f3;
  }
  for (; i < e; i += 2) {
    int s0 = csr[i];
    float f0 = isrO[s0];
    float4 v0 = *(const float4*)&x[(size_t)s0 * DIM + l32 * 4];
    acc.x += (v0.x*sc.x+sh.x)*f0;
    acc.y += (v0.y*sc.y+sh.y)*f0;
    acc.z += (v0.z*sc.z+sh.z)*f0;
    acc.w += (v0.w*sc.w+sh.w)*f0;
  }
  acc.x += __shfl_xor(acc.x, 32);
  acc.y += __shfl_xor(acc.y, 32);
  acc.z += __shfl_xor(acc.z, 32);
  acc.w += __shfl_xor(acc.w, 32);
  if (half == 0) {
    float isi = rsqrtf(fmaxf((float)(e - s), 1.0f));
    float4 o = {acc.x * isi, acc.y * isi, acc.z * isi, acc.w * isi};
    *(float4*)&agg[(size_t)row * DIM + l32 * 4] = o;
  }
}

// ---------------------------------------------------------------- conv: agg@W + b, relu, +res
__launch_bounds__(256, 4)
__global__ void k_conv(const float* __restrict__ agg, const float* __restrict__ W,
                       const float* __restrict__ bias, const float* __restrict__ hres,
                       float* __restrict__ outp) {
  __shared__ float As[32][DIM];
  __shared__ float Ws[32][DIM];
  int t = threadIdx.x;
  int row0 = blockIdx.x * 32;

  for (int i = t * 4; i < 32 * DIM; i += 1024) {
    *(float4*)&As[i >> 7][i & 127] = *(const float4*)&agg[(size_t)(row0 + (i >> 7)) * DIM + (i & 127)];
  }

  int tx = t & 31, ty = t >> 5;
  int c0 = tx * 4, r0 = ty * 4;
  float4 acc0 = {0.f,0.f,0.f,0.f}, acc1 = {0.f,0.f,0.f,0.f};
  float4 acc2 = {0.f,0.f,0.f,0.f}, acc3 = {0.f,0.f,0.f,0.f};

  for (int k0 = 0; k0 < DIM; k0 += 32) {
    __syncthreads();
    for (int i = t * 4; i < 32 * DIM; i += 1024) {
      *(float4*)&Ws[i >> 7][i & 127] = *(const float4*)&W[(size_t)(k0 + (i >> 7)) * DIM + (i & 127)];
    }
    __syncthreads();
#pragma unroll 4
    for (int k = 0; k < 32; k += 4) {
      float4 w0 = *(float4*)&Ws[k + 0][c0];
      float4 w1 = *(float4*)&Ws[k + 1][c0];
      float4 w2 = *(float4*)&Ws[k + 2][c0];
      float4 w3 = *(float4*)&Ws[k + 3][c0];
      float4 a0 = *(float4*)&As[r0 + 0][k0 + k];
      float4 a1 = *(float4*)&As[r0 + 1][k0 + k];
      float4 a2 = *(float4*)&As[r0 + 2][k0 + k];
      float4 a3 = *(float4*)&As[r0 + 3][k0 + k];
      acc0.x += a0.x*w0.x + a0.y*w1.x + a0.z*w2.x + a0.w*w3.x;
      acc0.y += a0.x*w0.y + a0.y*w1.y + a0.z*w2.y + a0.w*w3.y;
      acc0.z += a0.x*w0.z + a0.y*w1.z + a0.z*w2.z + a0.w*w3.z;
      acc0.w += a0.x*w0.w + a0.y*w1.w + a0.z*w2.w + a0.w*w3.w;
      acc1.x += a1.x*w0.x + a1.y*w1.x + a1.z*w2.x + a1.w*w3.x;
      acc1.y += a1.x*w0.y + a1.y*w1.y + a1.z*w2.y + a1.w*w3.y;
      acc1.z += a1.x*w0.z + a1.y*w1.z + a1.z*w2.z + a1.w*w3.z;
      acc1.w += a1.x*w0.w + a1.y*w1.w + a1.z*w2.w + a1.w*w3.w;
      acc2.x += a2.x*w0.x + a2.y*w1.x + a2.z*w2.x + a2.w*w3.x;
      acc2.y += a2.x*w0.y + a2.y*w1.y + a2.z*w2.y + a2.w*w3.y;
      acc2.z += a2.x*w0.z + a2.y*w1.z + a2.z*w2.z + a2.w*w3.z;
      acc2.w += a2.x*w0.w + a2.y*w1.w + a2.z*w2.w + a2.w*w3.w;
      acc3.x += a3.x*w0.x + a3.y*w1.x + a3.z*w2.x + a3.w*w3.x;
      acc3.y += a3.x*w0.y + a3.y*w1.y + a3.z*w2.y + a3.w*w3.y;
      acc3.z += a3.x*w0.z + a3.y*w1.z + a3.z*w2.z + a3.w*w3.z;
      acc3.w += a3.x*w0.w + a3.y*w1.w + a3.z*w2.w + a3.w*w3.w;
    }
  }

  float4 bv = *(const float4*)&bias[c0];
  {
    int row = row0 + r0 + 0;
    float4 hv = *(const float4*)&hres[(size_t)row * DIM + c0];
    float4 o = {hv.x + fmaxf(acc0.x + bv.x, 0.f), hv.y + fmaxf(acc0.y + bv.y, 0.f),
                hv.z + fmaxf(acc0.z + bv.z, 0.f), hv.w + fmaxf(acc0.w + bv.w, 0.f)};
    *(float4*)&outp[(size_t)row * DIM + c0] = o;
  }
  {
    int row = row0 + r0 + 1;
    float4 hv = *(const float4*)&hres[(size_t)row * DIM + c0];
    float4 o = {hv.x + fmaxf(acc1.x + bv.x, 0.f), hv.y + fmaxf(acc1.y + bv.y, 0.f),
                hv.z + fmaxf(acc1.z + bv.z, 0.f), hv.w + fmaxf(acc1.w + bv.w, 0.f)};
    *(float4*)&outp[(size_t)row * DIM + c0] = o;
  }
  {
    int row = row0 + r0 + 2;
    float4 hv = *(const float4*)&hres[(size_t)row * DIM + c0];
    float4 o = {hv.x + fmaxf(acc2.x + bv.x, 0.f), hv.y + fmaxf(acc2.y + bv.y, 0.f),
                hv.z + fmaxf(acc2.z + bv.z, 0.f), hv.w + fmaxf(acc2.w + bv.w, 0.f)};
    *(float4*)&outp[(size_t)row * DIM + c0] = o;
  }
  {
    int row = row0 + r0 + 3;
    float4 hv = *(const float4*)&hres[(size_t)row * DIM + c0];
    float4 o = {hv.x + fmaxf(acc3.x + bv.x, 0.f), hv.y + fmaxf(acc3.y + bv.y, 0.f),
                hv.z + fmaxf(acc3.z + bv.z, 0.f), hv.w + fmaxf(acc3.w + bv.w, 0.f)};
    *(float4*)&outp[(size_t)row * DIM + c0] = o;
  }
}

// ---------------------------------------------------------------- gate = h2 @ gate_W + gate_b
__global__ void k_gate(const float* __restrict__ h2, const float* __restrict__ gW,
                       const float* __restrict__ gb, float* __restrict__ gate) {
  int i = blockIdx.x * 4 + threadIdx.y;
  int l = threadIdx.x;
  float2 a = *(const float2*)&h2[(size_t)i * DIM + l * 2];
  float2 w = *(const float2*)&gW[l * 2];
  float v = a.x * w.x + a.y * w.y;
  for (int off = 32; off; off >>= 1) v += __shfl_down(v, off);
  if (l == 0) gate[i] = v + gb[0];
}

// ---------------------------------------------------------------- per-graph softmax stats
__global__ void k_gstats(const float* __restrict__ gate, const int* __restrict__ starts,
                         float* __restrict__ gmax, float* __restrict__ gden) {
  int g = blockIdx.x;
  int s = starts[g], e = starts[g + 1];
  int t = threadIdx.x;
  __shared__ float red[256];
  float m = -INFINITY;
  for (int i = s + t; i < e; i += 256) m = fmaxf(m, gate[i]);
  red[t] = m; __syncthreads();
  for (int w = 128; w; w >>= 1) { if (t < w) red[t] = fmaxf(red[t], red[t + w]); __syncthreads(); }
  float mg = red[0]; __syncthreads();
  float ssum = 0.f;
  for (int i = s + t; i < e; i += 256) ssum += expf(gate[i] - mg);
  red[t] = ssum; __syncthreads();
  for (int w = 128; w; w >>= 1) { if (t < w) red[t] += red[t + w]; __syncthreads(); }
  if (t == 0) { gmax[g] = mg; gden[g] = red[0]; }
}

// ---------------------------------------------------------------- weighted pooling
__global__ void k_pool(const float* __restrict__ h2, const float* __restrict__ gate,
                       const int* __restrict__ starts, const float* __restrict__ gmax,
                       const float* __restrict__ gden, float* __restrict__ outp) {
  int g = blockIdx.x >> 3, part = blockIdx.x & 7;
  int s = starts[g], e = starts[g + 1];
  int d = threadIdx.x;
  float mg = gmax[g];
  float dn = gden[g];
  float invden = dn > 0.f ? 1.0f / dn : 0.f;
  float acc = 0.f;
  for (int i = s + part; i < e; i += 8) {
    float w = expf(gate[i] - mg) * invden;
    acc += w * h2[(size_t)i * DIM + d];
  }
  atomicAdd(&outp[g * DIM + d], acc);
}

// ---------------------------------------------------------------- launch
extern "C" void kernel_launch(void* const* d_in, const int* in_sizes, int n_in,
                              void* d_out, int out_size, void* d_ws, size_t ws_size,
                              hipStream_t stream) {
  const float* h    = (const float*)d_in[0];
  const int*   src  = (const int*)d_in[1];
  const int*   dst  = (const int*)d_in[2];
  const int*   gid  = (const int*)d_in[3];
  const float* W1   = (const float*)d_in[5];
  const float* b1   = (const float*)d_in[6];
  const float* W2   = (const float*)d_in[7];
  const float* b2   = (const float*)d_in[8];
  const float* gW   = (const float*)d_in[9];
  const float* gb   = (const float*)d_in[10];
  const float* gamma= (const float*)d_in[11];
  const float* beta = (const float*)d_in[12];
  float* out = (float*)d_out;

  char* ws = (char*)d_ws;
  float* agg     = (float*)ws; ws += (size_t)N_NODES * DIM * 4;
  float* h12     = (float*)ws; ws += (size_t)N_NODES * DIM * 4;
  int*   csr     = (int*)ws;   ws += (size_t)N_EDGES * 4;
  int*   rank    = (int*)ws;   ws += (size_t)N_EDGES * 4;
  int*   rowstart= (int*)ws;   ws += (N_NODES + 1) * 4;
  int*   cnt     = (int*)ws;   ws += N_NODES * 4;
  int*   cntO    = (int*)ws;   ws += N_NODES * 4;
  float* isrO    = (float*)ws; ws += N_NODES * 4;
  float* gate    = (float*)ws; ws += N_NODES * 4;
  float* sums    = (float*)ws; ws += 2 * DIM * 4;
  float* scale   = (float*)ws; ws += DIM * 4;
  float* shift   = (float*)ws; ws += DIM * 4;
  float* gmax    = (float*)ws; ws += NG * 4;
  float* gden    = (float*)ws; ws += NG * 4;
  int*   starts  = (int*)ws;   ws += (NG + 1) * 4;
  int*   bsum    = (int*)ws;   ws += NB * 4;
  int*   boff    = (int*)ws;   ws += NB * 4;

  hipMemsetAsync(cntO,  0, N_NODES * 4, stream);
  hipMemsetAsync(cnt,   0, N_NODES * 4, stream);
  hipMemsetAsync(sums,  0, 2 * DIM * 4, stream);
  hipMemsetAsync(d_out, 0, (size_t)out_size * 4, stream);

  // graph structure (built once, used by both layers)
  k_histO<<<8 * HNBLK, 256, 0, stream>>>(src, cntO);
  k_rank<<<(N_EDGES + 255) / 256, 256, 0, stream>>>(dst, cnt, rank);
  k_isrO<<<(N_NODES + 255) / 256, 256, 0, stream>>>(cntO, isrO);
  k_scan_part<<<NB, 256, 0, stream>>>(cnt, bsum);
  k_scan_mid<<<1, 128, 0, stream>>>(bsum, boff, rowstart);
  k_scan_fin<<<NB, 256, 0, stream>>>(cnt, boff, rowstart);
  k_scatter<<<(N_EDGES + 255) / 256, 256, 0, stream>>>(src, dst, rowstart, rank, csr);
  k_starts_init<<<1, NG + 1, 0, stream>>>(starts);
  k_starts_fill<<<(N_NODES + 255) / 256, 256, 0, stream>>>(gid, starts);

  // init_avg_h -> out[NG*DIM ..]
  k_seg_accum<<<NG * 8, DIM, 0, stream>>>(h, starts, out + NG * DIM);
  k_avg_div<<<NG, DIM, 0, stream>>>(starts, out + NG * DIM);

  // layer 1
  k_bnstats<<<NB, 256, 0, stream>>>(h, sums);
  k_bnfin<<<1, DIM, 0, stream>>>(sums, gamma, beta, scale, shift);
  k_spmm_pull<<<N_NODES / 4, dim3(64, 4), 0, stream>>>(h, csr, rowstart, isrO, scale, shift, agg);
  k_conv<<<N_NODES / 32, 256, 0, stream>>>(agg, W1, b1, h, h12);

  // layer 2
  hipMemsetAsync(sums, 0, 2 * DIM * 4, stream);
  k_bnstats<<<NB, 256, 0, stream>>>(h12, sums);
  k_bnfin<<<1, DIM, 0, stream>>>(sums, gamma, beta, scale, shift);
  k_spmm_pull<<<N_NODES / 4, dim3(64, 4), 0, stream>>>(h12, csr, rowstart, isrO, scale, shift, agg);
  k_conv<<<N_NODES / 32, 256, 0, stream>>>(agg, W2, b2, h12, h12);

  // pooling
  k_gate<<<N_NODES / 4, dim3(64, 4), 0, stream>>>(h12, gW, gb, gate);
  k_gstats<<<NG, 256, 0, stream>>>(gate, starts, gmax, gden);
  k_pool<<<NG * 8, DIM, 0, stream>>>(h12, gate, starts, gmax, gden, out);
}

// Round 7
// 691.878 us; speedup vs baseline: 10.7204x; 1.1037x over previous
//
#include <hip/hip_runtime.h>
#include <math.h>

#define N_NODES 100000
#define N_EDGES 1600000
#define DIM     128
#define NG      64
#define BN_EPS  1e-5f
#define NB      98     // scan blocks
#define HRANGE  12500  // nodes per histogram range (50 KB LDS)
#define HNBLK   8      // blocks per range

__device__ __forceinline__ unsigned short f2bf(float f) {
  unsigned b = __float_as_uint(f);
  unsigned r = (b + 0x7FFFu + ((b >> 16) & 1u)) >> 16;   // RNE
  return (unsigned short)r;
}

// ---------------------------------------------------------------- out-degree histogram (LDS ranges, coalesced merge)
__launch_bounds__(256)
__global__ void k_histO(const int* __restrict__ src, int* __restrict__ cntO) {
  __shared__ int histo[HRANGE];   // 50 KB
  int t = threadIdx.x;
  int range = blockIdx.x >> 3, blk = blockIdx.x & 7;
  int lo = range * HRANGE;
  for (int j = t; j < HRANGE; j += 256) histo[j] = 0;
  __syncthreads();
  const int SLICE = N_EDGES / HNBLK;            // 200000
  const int4* sp = (const int4*)(src + blk * SLICE);
  const int n4 = SLICE / 4;                     // 50000
  for (int q = t; q < n4; q += 256) {
    int4 v = sp[q];
    unsigned a = (unsigned)(v.x - lo), b = (unsigned)(v.y - lo);
    unsigned c = (unsigned)(v.z - lo), d = (unsigned)(v.w - lo);
    if (a < (unsigned)HRANGE) atomicAdd(&histo[a], 1);
    if (b < (unsigned)HRANGE) atomicAdd(&histo[b], 1);
    if (c < (unsigned)HRANGE) atomicAdd(&histo[c], 1);
    if (d < (unsigned)HRANGE) atomicAdd(&histo[d], 1);
  }
  __syncthreads();
  for (int j = t; j < HRANGE; j += 256) {
    int v = histo[j];
    if (v) atomicAdd(&cntO[lo + j], v);
  }
}

// ---------------------------------------------------------------- in-degree count + per-edge rank (atomic return)
__global__ void k_rank(const int* __restrict__ dst, int* __restrict__ cnt,
                       int* __restrict__ rank) {
  int e = blockIdx.x * blockDim.x + threadIdx.x;
  if (e < N_EDGES) rank[e] = atomicAdd(&cnt[dst[e]], 1);
}

// ---------------------------------------------------------------- isrO = rsqrt(max(outdeg,1))
__global__ void k_isrO(const int* __restrict__ cntO, float* __restrict__ isrO) {
  int i = blockIdx.x * blockDim.x + threadIdx.x;
  if (i < N_NODES) isrO[i] = rsqrtf(fmaxf((float)cntO[i], 1.0f));
}

// ---------------------------------------------------------------- 3-pass scan of cnt -> rowstart
__global__ void k_scan_part(const int* __restrict__ cnt, int* __restrict__ bsum) {
  int b = blockIdx.x, t = threadIdx.x;
  int base = b * 1024 + t * 4;
  int s = 0;
#pragma unroll
  for (int j = 0; j < 4; ++j) { int i = base + j; if (i < N_NODES) s += cnt[i]; }
  __shared__ int red[256];
  red[t] = s; __syncthreads();
  for (int w = 128; w; w >>= 1) { if (t < w) red[t] += red[t + w]; __syncthreads(); }
  if (t == 0) bsum[b] = red[0];
}

__global__ void k_scan_mid(const int* __restrict__ bsum, int* __restrict__ boff,
                           int* __restrict__ rowstart) {
  int t = threadIdx.x;  // 128 >= NB
  __shared__ int sh[128];
  int own = (t < NB) ? bsum[t] : 0;
  sh[t] = own;
  __syncthreads();
  for (int off = 1; off < 128; off <<= 1) {
    int v = (t >= off) ? sh[t - off] : 0;
    __syncthreads();
    sh[t] += v;
    __syncthreads();
  }
  if (t < NB) boff[t] = sh[t] - own;
  if (t == NB - 1) rowstart[N_NODES] = sh[t];
}

__global__ void k_scan_fin(const int* __restrict__ cnt, const int* __restrict__ boff,
                           int* __restrict__ rowstart) {
  int b = blockIdx.x, t = threadIdx.x;
  int base = b * 1024 + t * 4;
  int v0 = 0, v1 = 0, v2 = 0, v3 = 0;
  if (base + 0 < N_NODES) v0 = cnt[base + 0];
  if (base + 1 < N_NODES) v1 = cnt[base + 1];
  if (base + 2 < N_NODES) v2 = cnt[base + 2];
  if (base + 3 < N_NODES) v3 = cnt[base + 3];
  int tsum = v0 + v1 + v2 + v3;
  __shared__ int sh[256];
  sh[t] = tsum;
  __syncthreads();
  for (int off = 1; off < 256; off <<= 1) {
    int v = (t >= off) ? sh[t - off] : 0;
    __syncthreads();
    sh[t] += v;
    __syncthreads();
  }
  int run = boff[b] + sh[t] - tsum;
  if (base + 0 < N_NODES) rowstart[base + 0] = run; run += v0;
  if (base + 1 < N_NODES) rowstart[base + 1] = run; run += v1;
  if (base + 2 < N_NODES) rowstart[base + 2] = run; run += v2;
  if (base + 3 < N_NODES) rowstart[base + 3] = run;
}

// ---------------------------------------------------------------- scatter (NO atomics: rank precomputed)
__global__ void k_scatter(const int* __restrict__ src, const int* __restrict__ dst,
                          const int* __restrict__ rowstart, const int* __restrict__ rank,
                          int* __restrict__ csr) {
  int e = blockIdx.x * blockDim.x + threadIdx.x;
  if (e < N_EDGES) {
    int d = dst[e];
    csr[rowstart[d] + rank[e]] = src[e];
  }
}

// ---------------------------------------------------------------- graph CSR starts
__global__ void k_starts_init(int* __restrict__ starts) {
  int g = threadIdx.x;
  if (g <= NG) starts[g] = N_NODES;
}

__global__ void k_starts_fill(const int* __restrict__ gid, int* __restrict__ starts) {
  int i = blockIdx.x * blockDim.x + threadIdx.x;
  if (i >= N_NODES) return;
  int gi = gid[i];
  if (i == 0) {
    for (int g = 0; g <= gi; ++g) starts[g] = 0;
  } else {
    int gp = gid[i - 1];
    if (gp != gi) for (int g = gp + 1; g <= gi; ++g) starts[g] = i;
  }
}

// ---------------------------------------------------------------- init_avg accumulation
__global__ void k_seg_accum(const float* __restrict__ h, const int* __restrict__ starts,
                            float* __restrict__ outp) {
  int g = blockIdx.x >> 3, part = blockIdx.x & 7;
  int s = starts[g], e = starts[g + 1];
  int d = threadIdx.x;
  float acc = 0.f;
  for (int i = s + part; i < e; i += 8) acc += h[(size_t)i * DIM + d];
  atomicAdd(&outp[g * DIM + d], acc);
}

__global__ void k_avg_div(const int* __restrict__ starts, float* __restrict__ outp) {
  int g = blockIdx.x, d = threadIdx.x;
  float cnt = fmaxf((float)(starts[g + 1] - starts[g]), 1.0f);
  outp[g * DIM + d] /= cnt;
}

// ---------------------------------------------------------------- BN column stats (float4 + LDS reduce)
__launch_bounds__(256)
__global__ void k_bnstats(const float* __restrict__ x, float* __restrict__ sums) {
  __shared__ float ls[8][DIM];
  __shared__ float ls2[8][DIM];
  int t = threadIdx.x;
  int col4 = (t & 31) * 4, rg = t >> 5;
  float4 s = {0.f,0.f,0.f,0.f}, s2 = {0.f,0.f,0.f,0.f};
  int rend = min(blockIdx.x * 1024 + 1024, N_NODES);
  for (int r = blockIdx.x * 1024 + rg; r < rend; r += 8) {
    float4 v = *(const float4*)&x[(size_t)r * DIM + col4];
    s.x += v.x; s.y += v.y; s.z += v.z; s.w += v.w;
    s2.x += v.x*v.x; s2.y += v.y*v.y; s2.z += v.z*v.z; s2.w += v.w*v.w;
  }
  *(float4*)&ls[rg][col4] = s;
  *(float4*)&ls2[rg][col4] = s2;
  __syncthreads();
  if (t < DIM) {
    float a = 0.f, b = 0.f;
#pragma unroll
    for (int j = 0; j < 8; ++j) { a += ls[j][t]; b += ls2[j][t]; }
    atomicAdd(&sums[t], a);
    atomicAdd(&sums[DIM + t], b);
  }
}

__global__ void k_bnfin(const float* __restrict__ sums, const float* __restrict__ gamma,
                        const float* __restrict__ beta, float* __restrict__ scale,
                        float* __restrict__ shift) {
  int d = threadIdx.x;
  float m = sums[d] * (1.0f / N_NODES);
  float v = sums[DIM + d] * (1.0f / N_NODES) - m * m;
  float rs = rsqrtf(fmaxf(v, 0.f) + BN_EPS) * gamma[d];
  scale[d] = rs;
  shift[d] = beta[d] - m * rs;
}

// ---------------------------------------------------------------- xb = bf16((x*scale + shift) * isrO[row])
__launch_bounds__(256)
__global__ void k_bnx(const float* __restrict__ x, const float* __restrict__ scale,
                      const float* __restrict__ shift, const float* __restrict__ isrO,
                      unsigned short* __restrict__ xb) {
  int idx = blockIdx.x * 256 + threadIdx.x;   // 3.2M threads, 4 elems each
  int row = idx >> 5, c4 = (idx & 31) * 4;
  float4 v  = *(const float4*)&x[(size_t)row * DIM + c4];
  float4 sc = *(const float4*)&scale[c4];
  float4 sh = *(const float4*)&shift[c4];
  float f = isrO[row];
  ushort4 o;
  o.x = f2bf((v.x * sc.x + sh.x) * f);
  o.y = f2bf((v.y * sc.y + sh.y) * f);
  o.z = f2bf((v.z * sc.z + sh.z) * f);
  o.w = f2bf((v.w * sc.w + sh.w) * f);
  *(ushort4*)&xb[(size_t)row * DIM + c4] = o;
}

// ---------------------------------------------------------------- pull-mode SpMM on bf16 table (pure gather-sum)
__launch_bounds__(256, 8)
__global__ void k_spmm_pull(const unsigned short* __restrict__ xb, const int* __restrict__ csr,
                            const int* __restrict__ rowstart, float* __restrict__ agg) {
  int row = blockIdx.x * 4 + threadIdx.y;
  int l = threadIdx.x;            // 0..63
  int half = l >> 5, l32 = l & 31;
  int s = rowstart[row], e = rowstart[row + 1];
  float4 acc = {0.f, 0.f, 0.f, 0.f};
  const size_t coff = (size_t)l32 * 4;
  int i = s + half;
  for (; i + 6 < e; i += 8) {          // 4 neighbors per half per iter
    int s0 = csr[i], s1 = csr[i + 2], s2 = csr[i + 4], s3 = csr[i + 6];
    uint2 w0 = *(const uint2*)&xb[(size_t)s0 * DIM + coff];
    uint2 w1 = *(const uint2*)&xb[(size_t)s1 * DIM + coff];
    uint2 w2 = *(const uint2*)&xb[(size_t)s2 * DIM + coff];
    uint2 w3 = *(const uint2*)&xb[(size_t)s3 * DIM + coff];
    acc.x += __uint_as_float(w0.x << 16) + __uint_as_float(w1.x << 16)
           + __uint_as_float(w2.x << 16) + __uint_as_float(w3.x << 16);
    acc.y += __uint_as_float(w0.x & 0xFFFF0000u) + __uint_as_float(w1.x & 0xFFFF0000u)
           + __uint_as_float(w2.x & 0xFFFF0000u) + __uint_as_float(w3.x & 0xFFFF0000u);
    acc.z += __uint_as_float(w0.y << 16) + __uint_as_float(w1.y << 16)
           + __uint_as_float(w2.y << 16) + __uint_as_float(w3.y << 16);
    acc.w += __uint_as_float(w0.y & 0xFFFF0000u) + __uint_as_float(w1.y & 0xFFFF0000u)
           + __uint_as_float(w2.y & 0xFFFF0000u) + __uint_as_float(w3.y & 0xFFFF0000u);
  }
  for (; i < e; i += 2) {
    int s0 = csr[i];
    uint2 w0 = *(const uint2*)&xb[(size_t)s0 * DIM + coff];
    acc.x += __uint_as_float(w0.x << 16);
    acc.y += __uint_as_float(w0.x & 0xFFFF0000u);
    acc.z += __uint_as_float(w0.y << 16);
    acc.w += __uint_as_float(w0.y & 0xFFFF0000u);
  }
  acc.x += __shfl_xor(acc.x, 32);
  acc.y += __shfl_xor(acc.y, 32);
  acc.z += __shfl_xor(acc.z, 32);
  acc.w += __shfl_xor(acc.w, 32);
  if (half == 0) {
    float isi = rsqrtf(fmaxf((float)(e - s), 1.0f));
    float4 o = {acc.x * isi, acc.y * isi, acc.z * isi, acc.w * isi};
    *(float4*)&agg[(size_t)row * DIM + l32 * 4] = o;
  }
}

// ---------------------------------------------------------------- conv: agg@W + b, relu, +res (+ optional fused gate)
__launch_bounds__(256, 4)
__global__ void k_conv(const float* __restrict__ agg, const float* __restrict__ W,
                       const float* __restrict__ bias, const float* __restrict__ hres,
                       float* __restrict__ outp,
                       const float* __restrict__ gWp, const float* __restrict__ gbp,
                       float* __restrict__ gatep) {
  __shared__ float As[32][DIM];
  __shared__ float Ws[32][DIM];
  __shared__ float gsh[32];
  int t = threadIdx.x;
  int row0 = blockIdx.x * 32;

  for (int i = t * 4; i < 32 * DIM; i += 1024) {
    *(float4*)&As[i >> 7][i & 127] = *(const float4*)&agg[(size_t)(row0 + (i >> 7)) * DIM + (i & 127)];
  }

  int tx = t & 31, ty = t >> 5;
  int c0 = tx * 4, r0 = ty * 4;
  float4 acc0 = {0.f,0.f,0.f,0.f}, acc1 = {0.f,0.f,0.f,0.f};
  float4 acc2 = {0.f,0.f,0.f,0.f}, acc3 = {0.f,0.f,0.f,0.f};

  for (int k0 = 0; k0 < DIM; k0 += 32) {
    __syncthreads();
    for (int i = t * 4; i < 32 * DIM; i += 1024) {
      *(float4*)&Ws[i >> 7][i & 127] = *(const float4*)&W[(size_t)(k0 + (i >> 7)) * DIM + (i & 127)];
    }
    __syncthreads();
#pragma unroll 4
    for (int k = 0; k < 32; k += 4) {
      float4 w0 = *(float4*)&Ws[k + 0][c0];
      float4 w1 = *(float4*)&Ws[k + 1][c0];
      float4 w2 = *(float4*)&Ws[k + 2][c0];
      float4 w3 = *(float4*)&Ws[k + 3][c0];
      float4 a0 = *(float4*)&As[r0 + 0][k0 + k];
      float4 a1 = *(float4*)&As[r0 + 1][k0 + k];
      float4 a2 = *(float4*)&As[r0 + 2][k0 + k];
      float4 a3 = *(float4*)&As[r0 + 3][k0 + k];
      acc0.x += a0.x*w0.x + a0.y*w1.x + a0.z*w2.x + a0.w*w3.x;
      acc0.y += a0.x*w0.y + a0.y*w1.y + a0.z*w2.y + a0.w*w3.y;
      acc0.z += a0.x*w0.z + a0.y*w1.z + a0.z*w2.z + a0.w*w3.z;
      acc0.w += a0.x*w0.w + a0.y*w1.w + a0.z*w2.w + a0.w*w3.w;
      acc1.x += a1.x*w0.x + a1.y*w1.x + a1.z*w2.x + a1.w*w3.x;
      acc1.y += a1.x*w0.y + a1.y*w1.y + a1.z*w2.y + a1.w*w3.y;
      acc1.z += a1.x*w0.z + a1.y*w1.z + a1.z*w2.z + a1.w*w3.z;
      acc1.w += a1.x*w0.w + a1.y*w1.w + a1.z*w2.w + a1.w*w3.w;
      acc2.x += a2.x*w0.x + a2.y*w1.x + a2.z*w2.x + a2.w*w3.x;
      acc2.y += a2.x*w0.y + a2.y*w1.y + a2.z*w2.y + a2.w*w3.y;
      acc2.z += a2.x*w0.z + a2.y*w1.z + a2.z*w2.z + a2.w*w3.z;
      acc2.w += a2.x*w0.w + a2.y*w1.w + a2.z*w2.w + a2.w*w3.w;
      acc3.x += a3.x*w0.x + a3.y*w1.x + a3.z*w2.x + a3.w*w3.x;
      acc3.y += a3.x*w0.y + a3.y*w1.y + a3.z*w2.y + a3.w*w3.y;
      acc3.z += a3.x*w0.z + a3.y*w1.z + a3.z*w2.z + a3.w*w3.z;
      acc3.w += a3.x*w0.w + a3.y*w1.w + a3.z*w2.w + a3.w*w3.w;
    }
  }

  float4 bv = *(const float4*)&bias[c0];
  float4 o0, o1, o2, o3;
  {
    float4 hv = *(const float4*)&hres[(size_t)(row0 + r0 + 0) * DIM + c0];
    o0 = {hv.x + fmaxf(acc0.x + bv.x, 0.f), hv.y + fmaxf(acc0.y + bv.y, 0.f),
          hv.z + fmaxf(acc0.z + bv.z, 0.f), hv.w + fmaxf(acc0.w + bv.w, 0.f)};
    *(float4*)&outp[(size_t)(row0 + r0 + 0) * DIM + c0] = o0;
  }
  {
    float4 hv = *(const float4*)&hres[(size_t)(row0 + r0 + 1) * DIM + c0];
    o1 = {hv.x + fmaxf(acc1.x + bv.x, 0.f), hv.y + fmaxf(acc1.y + bv.y, 0.f),
          hv.z + fmaxf(acc1.z + bv.z, 0.f), hv.w + fmaxf(acc1.w + bv.w, 0.f)};
    *(float4*)&outp[(size_t)(row0 + r0 + 1) * DIM + c0] = o1;
  }
  {
    float4 hv = *(const float4*)&hres[(size_t)(row0 + r0 + 2) * DIM + c0];
    o2 = {hv.x + fmaxf(acc2.x + bv.x, 0.f), hv.y + fmaxf(acc2.y + bv.y, 0.f),
          hv.z + fmaxf(acc2.z + bv.z, 0.f), hv.w + fmaxf(acc2.w + bv.w, 0.f)};
    *(float4*)&outp[(size_t)(row0 + r0 + 2) * DIM + c0] = o2;
  }
  {
    float4 hv = *(const float4*)&hres[(size_t)(row0 + r0 + 3) * DIM + c0];
    o3 = {hv.x + fmaxf(acc3.x + bv.x, 0.f), hv.y + fmaxf(acc3.y + bv.y, 0.f),
          hv.z + fmaxf(acc3.z + bv.z, 0.f), hv.w + fmaxf(acc3.w + bv.w, 0.f)};
    *(float4*)&outp[(size_t)(row0 + r0 + 3) * DIM + c0] = o3;
  }

  if (gatep) {   // fused gate = h2 @ gate_W + gate_b (per 32-row block)
    __syncthreads();
    if (t < 32) gsh[t] = 0.f;
    __syncthreads();
    float4 gw = *(const float4*)&gWp[c0];
    atomicAdd(&gsh[r0 + 0], o0.x*gw.x + o0.y*gw.y + o0.z*gw.z + o0.w*gw.w);
    atomicAdd(&gsh[r0 + 1], o1.x*gw.x + o1.y*gw.y + o1.z*gw.z + o1.w*gw.w);
    atomicAdd(&gsh[r0 + 2], o2.x*gw.x + o2.y*gw.y + o2.z*gw.z + o2.w*gw.w);
    atomicAdd(&gsh[r0 + 3], o3.x*gw.x + o3.y*gw.y + o3.z*gw.z + o3.w*gw.w);
    __syncthreads();
    if (t < 32) gatep[row0 + t] = gsh[t] + gbp[0];
  }
}

// ---------------------------------------------------------------- per-graph softmax stats
__global__ void k_gstats(const float* __restrict__ gate, const int* __restrict__ starts,
                         float* __restrict__ gmax, float* __restrict__ gden) {
  int g = blockIdx.x;
  int s = starts[g], e = starts[g + 1];
  int t = threadIdx.x;
  __shared__ float red[256];
  float m = -INFINITY;
  for (int i = s + t; i < e; i += 256) m = fmaxf(m, gate[i]);
  red[t] = m; __syncthreads();
  for (int w = 128; w; w >>= 1) { if (t < w) red[t] = fmaxf(red[t], red[t + w]); __syncthreads(); }
  float mg = red[0]; __syncthreads();
  float ssum = 0.f;
  for (int i = s + t; i < e; i += 256) ssum += expf(gate[i] - mg);
  red[t] = ssum; __syncthreads();
  for (int w = 128; w; w >>= 1) { if (t < w) red[t] += red[t + w]; __syncthreads(); }
  if (t == 0) { gmax[g] = mg; gden[g] = red[0]; }
}

// ---------------------------------------------------------------- weighted pooling
__global__ void k_pool(const float* __restrict__ h2, const float* __restrict__ gate,
                       const int* __restrict__ starts, const float* __restrict__ gmax,
                       const float* __restrict__ gden, float* __restrict__ outp) {
  int g = blockIdx.x >> 3, part = blockIdx.x & 7;
  int s = starts[g], e = starts[g + 1];
  int d = threadIdx.x;
  float mg = gmax[g];
  float dn = gden[g];
  float invden = dn > 0.f ? 1.0f / dn : 0.f;
  float acc = 0.f;
  for (int i = s + part; i < e; i += 8) {
    float w = expf(gate[i] - mg) * invden;
    acc += w * h2[(size_t)i * DIM + d];
  }
  atomicAdd(&outp[g * DIM + d], acc);
}

// ---------------------------------------------------------------- launch
extern "C" void kernel_launch(void* const* d_in, const int* in_sizes, int n_in,
                              void* d_out, int out_size, void* d_ws, size_t ws_size,
                              hipStream_t stream) {
  const float* h    = (const float*)d_in[0];
  const int*   src  = (const int*)d_in[1];
  const int*   dst  = (const int*)d_in[2];
  const int*   gid  = (const int*)d_in[3];
  const float* W1   = (const float*)d_in[5];
  const float* b1   = (const float*)d_in[6];
  const float* W2   = (const float*)d_in[7];
  const float* b2   = (const float*)d_in[8];
  const float* gW   = (const float*)d_in[9];
  const float* gb   = (const float*)d_in[10];
  const float* gamma= (const float*)d_in[11];
  const float* beta = (const float*)d_in[12];
  float* out = (float*)d_out;

  char* ws = (char*)d_ws;
  float* agg     = (float*)ws; ws += (size_t)N_NODES * DIM * 4;
  float* h12     = (float*)ws; ws += (size_t)N_NODES * DIM * 4;
  unsigned short* xb = (unsigned short*)ws; ws += (size_t)N_NODES * DIM * 2;
  int*   csr     = (int*)ws;   ws += (size_t)N_EDGES * 4;
  int*   rowstart= (int*)ws;   ws += (N_NODES + 1) * 4;
  int*   cnt     = (int*)ws;   ws += N_NODES * 4;
  int*   cntO    = (int*)ws;   ws += N_NODES * 4;
  float* isrO    = (float*)ws; ws += N_NODES * 4;
  float* gate    = (float*)ws; ws += N_NODES * 4;
  float* sums    = (float*)ws; ws += 2 * DIM * 4;
  float* scale   = (float*)ws; ws += DIM * 4;
  float* shift   = (float*)ws; ws += DIM * 4;
  float* gmax    = (float*)ws; ws += NG * 4;
  float* gden    = (float*)ws; ws += NG * 4;
  int*   starts  = (int*)ws;   ws += (NG + 1) * 4;
  int*   bsum    = (int*)ws;   ws += NB * 4;
  int*   boff    = (int*)ws;   ws += NB * 4;
  int*   rank    = (int*)agg;  // alias: rank dead before spmm writes agg

  hipMemsetAsync(cntO,  0, N_NODES * 4, stream);
  hipMemsetAsync(cnt,   0, N_NODES * 4, stream);
  hipMemsetAsync(sums,  0, 2 * DIM * 4, stream);
  hipMemsetAsync(d_out, 0, (size_t)out_size * 4, stream);

  // graph structure (built once, used by both layers)
  k_histO<<<8 * HNBLK, 256, 0, stream>>>(src, cntO);
  k_rank<<<(N_EDGES + 255) / 256, 256, 0, stream>>>(dst, cnt, rank);
  k_isrO<<<(N_NODES + 255) / 256, 256, 0, stream>>>(cntO, isrO);
  k_scan_part<<<NB, 256, 0, stream>>>(cnt, bsum);
  k_scan_mid<<<1, 128, 0, stream>>>(bsum, boff, rowstart);
  k_scan_fin<<<NB, 256, 0, stream>>>(cnt, boff, rowstart);
  k_scatter<<<(N_EDGES + 255) / 256, 256, 0, stream>>>(src, dst, rowstart, rank, csr);
  k_starts_init<<<1, NG + 1, 0, stream>>>(starts);
  k_starts_fill<<<(N_NODES + 255) / 256, 256, 0, stream>>>(gid, starts);

  // init_avg_h -> out[NG*DIM ..]
  k_seg_accum<<<NG * 8, DIM, 0, stream>>>(h, starts, out + NG * DIM);
  k_avg_div<<<NG, DIM, 0, stream>>>(starts, out + NG * DIM);

  // layer 1
  k_bnstats<<<NB, 256, 0, stream>>>(h, sums);
  k_bnfin<<<1, DIM, 0, stream>>>(sums, gamma, beta, scale, shift);
  k_bnx<<<N_NODES * 32 / 256, 256, 0, stream>>>(h, scale, shift, isrO, xb);
  k_spmm_pull<<<N_NODES / 4, dim3(64, 4), 0, stream>>>(xb, csr, rowstart, agg);
  k_conv<<<N_NODES / 32, 256, 0, stream>>>(agg, W1, b1, h, h12, nullptr, nullptr, nullptr);

  // layer 2
  hipMemsetAsync(sums, 0, 2 * DIM * 4, stream);
  k_bnstats<<<NB, 256, 0, stream>>>(h12, sums);
  k_bnfin<<<1, DIM, 0, stream>>>(sums, gamma, beta, scale, shift);
  k_bnx<<<N_NODES * 32 / 256, 256, 0, stream>>>(h12, scale, shift, isrO, xb);
  k_spmm_pull<<<N_NODES / 4, dim3(64, 4), 0, stream>>>(xb, csr, rowstart, agg);
  k_conv<<<N_NODES / 32, 256, 0, stream>>>(agg, W2, b2, h12, h12, gW, gb, gate);

  // pooling
  k_gstats<<<NG, 256, 0, stream>>>(gate, starts, gmax, gden);
  k_pool<<<NG * 8, DIM, 0, stream>>>(h12, gate, starts, gmax, gden, out);
}

// Round 8
// 635.665 us; speedup vs baseline: 11.6684x; 1.0884x over previous
//
#include <hip/hip_runtime.h>
#include <math.h>

#define N_NODES 100000
#define N_EDGES 1600000
#define DIM     128
#define NG      64
#define BN_EPS  1e-5f
#define NB      98     // scan blocks
#define HRANGE  12500  // nodes per histogram range (50 KB LDS)
#define HNBLK   8      // blocks per range

__device__ __forceinline__ unsigned short f2bf(float f) {
  unsigned b = __float_as_uint(f);
  unsigned r = (b + 0x7FFFu + ((b >> 16) & 1u)) >> 16;   // RNE
  return (unsigned short)r;
}

// ---------------------------------------------------------------- out-degree histogram
// 1024 thr/block: 16 waves hide the {int4 load -> LDS atomic} latency chain (was 2.4% occ @ 256 thr)
__launch_bounds__(1024)
__global__ void k_histO(const int* __restrict__ src, int* __restrict__ cntO) {
  __shared__ int histo[HRANGE];   // 50 KB
  int t = threadIdx.x;
  int range = blockIdx.x >> 3, blk = blockIdx.x & 7;
  int lo = range * HRANGE;
  for (int j = t; j < HRANGE; j += 1024) histo[j] = 0;
  __syncthreads();
  const int SLICE = N_EDGES / HNBLK;            // 200000
  const int4* sp = (const int4*)(src + blk * SLICE);
  const int n4 = SLICE / 4;                     // 50000
  for (int q = t; q < n4; q += 1024) {
    int4 v = sp[q];
    unsigned a = (unsigned)(v.x - lo), b = (unsigned)(v.y - lo);
    unsigned c = (unsigned)(v.z - lo), d = (unsigned)(v.w - lo);
    if (a < (unsigned)HRANGE) atomicAdd(&histo[a], 1);
    if (b < (unsigned)HRANGE) atomicAdd(&histo[b], 1);
    if (c < (unsigned)HRANGE) atomicAdd(&histo[c], 1);
    if (d < (unsigned)HRANGE) atomicAdd(&histo[d], 1);
  }
  __syncthreads();
  for (int j = t; j < HRANGE; j += 1024) {
    int v = histo[j];
    if (v) atomicAdd(&cntO[lo + j], v);
  }
}

// ---------------------------------------------------------------- in-degree count + per-edge rank (atomic return)
__global__ void k_rank(const int* __restrict__ dst, int* __restrict__ cnt,
                       int* __restrict__ rank) {
  int e = blockIdx.x * blockDim.x + threadIdx.x;
  if (e < N_EDGES) rank[e] = atomicAdd(&cnt[dst[e]], 1);
}

// ---------------------------------------------------------------- 3-pass scan of cnt -> rowstart
__global__ void k_scan_part(const int* __restrict__ cnt, int* __restrict__ bsum) {
  int b = blockIdx.x, t = threadIdx.x;
  int base = b * 1024 + t * 4;
  int s = 0;
#pragma unroll
  for (int j = 0; j < 4; ++j) { int i = base + j; if (i < N_NODES) s += cnt[i]; }
  __shared__ int red[256];
  red[t] = s; __syncthreads();
  for (int w = 128; w; w >>= 1) { if (t < w) red[t] += red[t + w]; __syncthreads(); }
  if (t == 0) bsum[b] = red[0];
}

__global__ void k_scan_mid(const int* __restrict__ bsum, int* __restrict__ boff,
                           int* __restrict__ rowstart) {
  int t = threadIdx.x;  // 128 >= NB
  __shared__ int sh[128];
  int own = (t < NB) ? bsum[t] : 0;
  sh[t] = own;
  __syncthreads();
  for (int off = 1; off < 128; off <<= 1) {
    int v = (t >= off) ? sh[t - off] : 0;
    __syncthreads();
    sh[t] += v;
    __syncthreads();
  }
  if (t < NB) boff[t] = sh[t] - own;
  if (t == NB - 1) rowstart[N_NODES] = sh[t];
}

__global__ void k_scan_fin(const int* __restrict__ cnt, const int* __restrict__ boff,
                           int* __restrict__ rowstart) {
  int b = blockIdx.x, t = threadIdx.x;
  int base = b * 1024 + t * 4;
  int v0 = 0, v1 = 0, v2 = 0, v3 = 0;
  if (base + 0 < N_NODES) v0 = cnt[base + 0];
  if (base + 1 < N_NODES) v1 = cnt[base + 1];
  if (base + 2 < N_NODES) v2 = cnt[base + 2];
  if (base + 3 < N_NODES) v3 = cnt[base + 3];
  int tsum = v0 + v1 + v2 + v3;
  __shared__ int sh[256];
  sh[t] = tsum;
  __syncthreads();
  for (int off = 1; off < 256; off <<= 1) {
    int v = (t >= off) ? sh[t - off] : 0;
    __syncthreads();
    sh[t] += v;
    __syncthreads();
  }
  int run = boff[b] + sh[t] - tsum;
  if (base + 0 < N_NODES) rowstart[base + 0] = run; run += v0;
  if (base + 1 < N_NODES) rowstart[base + 1] = run; run += v1;
  if (base + 2 < N_NODES) rowstart[base + 2] = run; run += v2;
  if (base + 3 < N_NODES) rowstart[base + 3] = run;
}

// ---------------------------------------------------------------- scatter (NO atomics: rank precomputed)
__global__ void k_scatter(const int* __restrict__ src, const int* __restrict__ dst,
                          const int* __restrict__ rowstart, const int* __restrict__ rank,
                          int* __restrict__ csr) {
  int e = blockIdx.x * blockDim.x + threadIdx.x;
  if (e < N_EDGES) {
    int d = dst[e];
    csr[rowstart[d] + rank[e]] = src[e];
  }
}

// ---------------------------------------------------------------- graph CSR starts
__global__ void k_starts_init(int* __restrict__ starts) {
  int g = threadIdx.x;
  if (g <= NG) starts[g] = N_NODES;
}

__global__ void k_starts_fill(const int* __restrict__ gid, int* __restrict__ starts) {
  int i = blockIdx.x * blockDim.x + threadIdx.x;
  if (i >= N_NODES) return;
  int gi = gid[i];
  if (i == 0) {
    for (int g = 0; g <= gi; ++g) starts[g] = 0;
  } else {
    int gp = gid[i - 1];
    if (gp != gi) for (int g = gp + 1; g <= gi; ++g) starts[g] = i;
  }
}

// ---------------------------------------------------------------- init_avg accumulation
__global__ void k_seg_accum(const float* __restrict__ h, const int* __restrict__ starts,
                            float* __restrict__ outp) {
  int g = blockIdx.x >> 3, part = blockIdx.x & 7;
  int s = starts[g], e = starts[g + 1];
  int d = threadIdx.x;
  float acc = 0.f;
  for (int i = s + part; i < e; i += 8) acc += h[(size_t)i * DIM + d];
  atomicAdd(&outp[g * DIM + d], acc);
}

__global__ void k_avg_div(const int* __restrict__ starts, float* __restrict__ outp) {
  int g = blockIdx.x, d = threadIdx.x;
  float cnt = fmaxf((float)(starts[g + 1] - starts[g]), 1.0f);
  outp[g * DIM + d] /= cnt;
}

// ---------------------------------------------------------------- BN column stats (float4 + LDS reduce)
__launch_bounds__(256)
__global__ void k_bnstats(const float* __restrict__ x, float* __restrict__ sums) {
  __shared__ float ls[8][DIM];
  __shared__ float ls2[8][DIM];
  int t = threadIdx.x;
  int col4 = (t & 31) * 4, rg = t >> 5;
  float4 s = {0.f,0.f,0.f,0.f}, s2 = {0.f,0.f,0.f,0.f};
  int rend = min(blockIdx.x * 1024 + 1024, N_NODES);
  for (int r = blockIdx.x * 1024 + rg; r < rend; r += 8) {
    float4 v = *(const float4*)&x[(size_t)r * DIM + col4];
    s.x += v.x; s.y += v.y; s.z += v.z; s.w += v.w;
    s2.x += v.x*v.x; s2.y += v.y*v.y; s2.z += v.z*v.z; s2.w += v.w*v.w;
  }
  *(float4*)&ls[rg][col4] = s;
  *(float4*)&ls2[rg][col4] = s2;
  __syncthreads();
  if (t < DIM) {
    float a = 0.f, b = 0.f;
#pragma unroll
    for (int j = 0; j < 8; ++j) { a += ls[j][t]; b += ls2[j][t]; }
    atomicAdd(&sums[t], a);
    atomicAdd(&sums[DIM + t], b);
  }
}

__global__ void k_bnfin(const float* __restrict__ sums, const float* __restrict__ gamma,
                        const float* __restrict__ beta, float* __restrict__ scale,
                        float* __restrict__ shift) {
  int d = threadIdx.x;
  float m = sums[d] * (1.0f / N_NODES);
  float v = sums[DIM + d] * (1.0f / N_NODES) - m * m;
  float rs = rsqrtf(fmaxf(v, 0.f) + BN_EPS) * gamma[d];
  scale[d] = rs;
  shift[d] = beta[d] - m * rs;
}

// ---------------------------------------------------------------- xb = bf16((x*scale + shift) * rsqrt(outdeg))
__launch_bounds__(256)
__global__ void k_bnx(const float* __restrict__ x, const float* __restrict__ scale,
                      const float* __restrict__ shift, const int* __restrict__ cntO,
                      unsigned short* __restrict__ xb) {
  int idx = blockIdx.x * 256 + threadIdx.x;   // 3.2M threads, 4 elems each
  int row = idx >> 5, c4 = (idx & 31) * 4;
  float4 v  = *(const float4*)&x[(size_t)row * DIM + c4];
  float4 sc = *(const float4*)&scale[c4];
  float4 sh = *(const float4*)&shift[c4];
  float f = rsqrtf(fmaxf((float)cntO[row], 1.0f));
  ushort4 o;
  o.x = f2bf((v.x * sc.x + sh.x) * f);
  o.y = f2bf((v.y * sc.y + sh.y) * f);
  o.z = f2bf((v.z * sc.z + sh.z) * f);
  o.w = f2bf((v.w * sc.w + sh.w) * f);
  *(ushort4*)&xb[(size_t)row * DIM + c4] = o;
}

// ---------------------------------------------------------------- pull-mode SpMM on bf16 table (pure gather-sum)
__launch_bounds__(256, 8)
__global__ void k_spmm_pull(const unsigned short* __restrict__ xb, const int* __restrict__ csr,
                            const int* __restrict__ rowstart, float* __restrict__ agg) {
  int row = blockIdx.x * 4 + threadIdx.y;
  int l = threadIdx.x;            // 0..63
  int half = l >> 5, l32 = l & 31;
  int s = rowstart[row], e = rowstart[row + 1];
  float4 acc = {0.f, 0.f, 0.f, 0.f};
  const size_t coff = (size_t)l32 * 4;
  int i = s + half;
  for (; i + 6 < e; i += 8) {          // 4 neighbors per half per iter
    int s0 = csr[i], s1 = csr[i + 2], s2 = csr[i + 4], s3 = csr[i + 6];
    uint2 w0 = *(const uint2*)&xb[(size_t)s0 * DIM + coff];
    uint2 w1 = *(const uint2*)&xb[(size_t)s1 * DIM + coff];
    uint2 w2 = *(const uint2*)&xb[(size_t)s2 * DIM + coff];
    uint2 w3 = *(const uint2*)&xb[(size_t)s3 * DIM + coff];
    acc.x += __uint_as_float(w0.x << 16) + __uint_as_float(w1.x << 16)
           + __uint_as_float(w2.x << 16) + __uint_as_float(w3.x << 16);
    acc.y += __uint_as_float(w0.x & 0xFFFF0000u) + __uint_as_float(w1.x & 0xFFFF0000u)
           + __uint_as_float(w2.x & 0xFFFF0000u) + __uint_as_float(w3.x & 0xFFFF0000u);
    acc.z += __uint_as_float(w0.y << 16) + __uint_as_float(w1.y << 16)
           + __uint_as_float(w2.y << 16) + __uint_as_float(w3.y << 16);
    acc.w += __uint_as_float(w0.y & 0xFFFF0000u) + __uint_as_float(w1.y & 0xFFFF0000u)
           + __uint_as_float(w2.y & 0xFFFF0000u) + __uint_as_float(w3.y & 0xFFFF0000u);
  }
  for (; i < e; i += 2) {
    int s0 = csr[i];
    uint2 w0 = *(const uint2*)&xb[(size_t)s0 * DIM + coff];
    acc.x += __uint_as_float(w0.x << 16);
    acc.y += __uint_as_float(w0.x & 0xFFFF0000u);
    acc.z += __uint_as_float(w0.y << 16);
    acc.w += __uint_as_float(w0.y & 0xFFFF0000u);
  }
  acc.x += __shfl_xor(acc.x, 32);
  acc.y += __shfl_xor(acc.y, 32);
  acc.z += __shfl_xor(acc.z, 32);
  acc.w += __shfl_xor(acc.w, 32);
  if (half == 0) {
    float isi = rsqrtf(fmaxf((float)(e - s), 1.0f));
    float4 o = {acc.x * isi, acc.y * isi, acc.z * isi, acc.w * isi};
    *(float4*)&agg[(size_t)row * DIM + l32 * 4] = o;
  }
}

// ---------------------------------------------------------------- conv: agg@W + b, relu, +res (+ optional fused gate)
__launch_bounds__(256, 4)
__global__ void k_conv(const float* __restrict__ agg, const float* __restrict__ W,
                       const float* __restrict__ bias, const float* __restrict__ hres,
                       float* __restrict__ outp,
                       const float* __restrict__ gWp, const float* __restrict__ gbp,
                       float* __restrict__ gatep) {
  __shared__ float As[32][DIM];
  __shared__ float Ws[32][DIM];
  __shared__ float gsh[32];
  int t = threadIdx.x;
  int row0 = blockIdx.x * 32;

  for (int i = t * 4; i < 32 * DIM; i += 1024) {
    *(float4*)&As[i >> 7][i & 127] = *(const float4*)&agg[(size_t)(row0 + (i >> 7)) * DIM + (i & 127)];
  }

  int tx = t & 31, ty = t >> 5;
  int c0 = tx * 4, r0 = ty * 4;
  float4 acc0 = {0.f,0.f,0.f,0.f}, acc1 = {0.f,0.f,0.f,0.f};
  float4 acc2 = {0.f,0.f,0.f,0.f}, acc3 = {0.f,0.f,0.f,0.f};

  for (int k0 = 0; k0 < DIM; k0 += 32) {
    __syncthreads();
    for (int i = t * 4; i < 32 * DIM; i += 1024) {
      *(float4*)&Ws[i >> 7][i & 127] = *(const float4*)&W[(size_t)(k0 + (i >> 7)) * DIM + (i & 127)];
    }
    __syncthreads();
#pragma unroll 4
    for (int k = 0; k < 32; k += 4) {
      float4 w0 = *(float4*)&Ws[k + 0][c0];
      float4 w1 = *(float4*)&Ws[k + 1][c0];
      float4 w2 = *(float4*)&Ws[k + 2][c0];
      float4 w3 = *(float4*)&Ws[k + 3][c0];
      float4 a0 = *(float4*)&As[r0 + 0][k0 + k];
      float4 a1 = *(float4*)&As[r0 + 1][k0 + k];
      float4 a2 = *(float4*)&As[r0 + 2][k0 + k];
      float4 a3 = *(float4*)&As[r0 + 3][k0 + k];
      acc0.x += a0.x*w0.x + a0.y*w1.x + a0.z*w2.x + a0.w*w3.x;
      acc0.y += a0.x*w0.y + a0.y*w1.y + a0.z*w2.y + a0.w*w3.y;
      acc0.z += a0.x*w0.z + a0.y*w1.z + a0.z*w2.z + a0.w*w3.z;
      acc0.w += a0.x*w0.w + a0.y*w1.w + a0.z*w2.w + a0.w*w3.w;
      acc1.x += a1.x*w0.x + a1.y*w1.x + a1.z*w2.x + a1.w*w3.x;
      acc1.y += a1.x*w0.y + a1.y*w1.y + a1.z*w2.y + a1.w*w3.y;
      acc1.z += a1.x*w0.z + a1.y*w1.z + a1.z*w2.z + a1.w*w3.z;
      acc1.w += a1.x*w0.w + a1.y*w1.w + a1.z*w2.w + a1.w*w3.w;
      acc2.x += a2.x*w0.x + a2.y*w1.x + a2.z*w2.x + a2.w*w3.x;
      acc2.y += a2.x*w0.y + a2.y*w1.y + a2.z*w2.y + a2.w*w3.y;
      acc2.z += a2.x*w0.z + a2.y*w1.z + a2.z*w2.z + a2.w*w3.z;
      acc2.w += a2.x*w0.w + a2.y*w1.w + a2.z*w2.w + a2.w*w3.w;
      acc3.x += a3.x*w0.x + a3.y*w1.x + a3.z*w2.x + a3.w*w3.x;
      acc3.y += a3.x*w0.y + a3.y*w1.y + a3.z*w2.y + a3.w*w3.y;
      acc3.z += a3.x*w0.z + a3.y*w1.z + a3.z*w2.z + a3.w*w3.z;
      acc3.w += a3.x*w0.w + a3.y*w1.w + a3.z*w2.w + a3.w*w3.w;
    }
  }

  float4 bv = *(const float4*)&bias[c0];
  float4 o0, o1, o2, o3;
  {
    float4 hv = *(const float4*)&hres[(size_t)(row0 + r0 + 0) * DIM + c0];
    o0 = {hv.x + fmaxf(acc0.x + bv.x, 0.f), hv.y + fmaxf(acc0.y + bv.y, 0.f),
          hv.z + fmaxf(acc0.z + bv.z, 0.f), hv.w + fmaxf(acc0.w + bv.w, 0.f)};
    *(float4*)&outp[(size_t)(row0 + r0 + 0) * DIM + c0] = o0;
  }
  {
    float4 hv = *(const float4*)&hres[(size_t)(row0 + r0 + 1) * DIM + c0];
    o1 = {hv.x + fmaxf(acc1.x + bv.x, 0.f), hv.y + fmaxf(acc1.y + bv.y, 0.f),
          hv.z + fmaxf(acc1.z + bv.z, 0.f), hv.w + fmaxf(acc1.w + bv.w, 0.f)};
    *(float4*)&outp[(size_t)(row0 + r0 + 1) * DIM + c0] = o1;
  }
  {
    float4 hv = *(const float4*)&hres[(size_t)(row0 + r0 + 2) * DIM + c0];
    o2 = {hv.x + fmaxf(acc2.x + bv.x, 0.f), hv.y + fmaxf(acc2.y + bv.y, 0.f),
          hv.z + fmaxf(acc2.z + bv.z, 0.f), hv.w + fmaxf(acc2.w + bv.w, 0.f)};
    *(float4*)&outp[(size_t)(row0 + r0 + 2) * DIM + c0] = o2;
  }
  {
    float4 hv = *(const float4*)&hres[(size_t)(row0 + r0 + 3) * DIM + c0];
    o3 = {hv.x + fmaxf(acc3.x + bv.x, 0.f), hv.y + fmaxf(acc3.y + bv.y, 0.f),
          hv.z + fmaxf(acc3.z + bv.z, 0.f), hv.w + fmaxf(acc3.w + bv.w, 0.f)};
    *(float4*)&outp[(size_t)(row0 + r0 + 3) * DIM + c0] = o3;
  }

  if (gatep) {   // fused gate = h2 @ gate_W + gate_b (per 32-row block)
    __syncthreads();
    if (t < 32) gsh[t] = 0.f;
    __syncthreads();
    float4 gw = *(const float4*)&gWp[c0];
    atomicAdd(&gsh[r0 + 0], o0.x*gw.x + o0.y*gw.y + o0.z*gw.z + o0.w*gw.w);
    atomicAdd(&gsh[r0 + 1], o1.x*gw.x + o1.y*gw.y + o1.z*gw.z + o1.w*gw.w);
    atomicAdd(&gsh[r0 + 2], o2.x*gw.x + o2.y*gw.y + o2.z*gw.z + o2.w*gw.w);
    atomicAdd(&gsh[r0 + 3], o3.x*gw.x + o3.y*gw.y + o3.z*gw.z + o3.w*gw.w);
    __syncthreads();
    if (t < 32) gatep[row0 + t] = gsh[t] + gbp[0];
  }
}

// ---------------------------------------------------------------- per-graph softmax stats
__global__ void k_gstats(const float* __restrict__ gate, const int* __restrict__ starts,
                         float* __restrict__ gmax, float* __restrict__ gden) {
  int g = blockIdx.x;
  int s = starts[g], e = starts[g + 1];
  int t = threadIdx.x;
  __shared__ float red[256];
  float m = -INFINITY;
  for (int i = s + t; i < e; i += 256) m = fmaxf(m, gate[i]);
  red[t] = m; __syncthreads();
  for (int w = 128; w; w >>= 1) { if (t < w) red[t] = fmaxf(red[t], red[t + w]); __syncthreads(); }
  float mg = red[0]; __syncthreads();
  float ssum = 0.f;
  for (int i = s + t; i < e; i += 256) ssum += expf(gate[i] - mg);
  red[t] = ssum; __syncthreads();
  for (int w = 128; w; w >>= 1) { if (t < w) red[t] += red[t + w]; __syncthreads(); }
  if (t == 0) { gmax[g] = mg; gden[g] = red[0]; }
}

// ---------------------------------------------------------------- weighted pooling
__global__ void k_pool(const float* __restrict__ h2, const float* __restrict__ gate,
                       const int* __restrict__ starts, const float* __restrict__ gmax,
                       const float* __restrict__ gden, float* __restrict__ outp) {
  int g = blockIdx.x >> 3, part = blockIdx.x & 7;
  int s = starts[g], e = starts[g + 1];
  int d = threadIdx.x;
  float mg = gmax[g];
  float dn = gden[g];
  float invden = dn > 0.f ? 1.0f / dn : 0.f;
  float acc = 0.f;
  for (int i = s + part; i < e; i += 8) {
    float w = expf(gate[i] - mg) * invden;
    acc += w * h2[(size_t)i * DIM + d];
  }
  atomicAdd(&outp[g * DIM + d], acc);
}

// ---------------------------------------------------------------- launch
extern "C" void kernel_launch(void* const* d_in, const int* in_sizes, int n_in,
                              void* d_out, int out_size, void* d_ws, size_t ws_size,
                              hipStream_t stream) {
  const float* h    = (const float*)d_in[0];
  const int*   src  = (const int*)d_in[1];
  const int*   dst  = (const int*)d_in[2];
  const int*   gid  = (const int*)d_in[3];
  const float* W1   = (const float*)d_in[5];
  const float* b1   = (const float*)d_in[6];
  const float* W2   = (const float*)d_in[7];
  const float* b2   = (const float*)d_in[8];
  const float* gW   = (const float*)d_in[9];
  const float* gb   = (const float*)d_in[10];
  const float* gamma= (const float*)d_in[11];
  const float* beta = (const float*)d_in[12];
  float* out = (float*)d_out;

  char* ws = (char*)d_ws;
  float* agg     = (float*)ws; ws += (size_t)N_NODES * DIM * 4;
  float* h12     = (float*)ws; ws += (size_t)N_NODES * DIM * 4;
  unsigned short* xb = (unsigned short*)ws; ws += (size_t)N_NODES * DIM * 2;
  int*   csr     = (int*)ws;   ws += (size_t)N_EDGES * 4;
  int*   rowstart= (int*)ws;   ws += (N_NODES + 1) * 4;
  int*   cnt     = (int*)ws;   ws += N_NODES * 4;
  int*   cntO    = (int*)ws;   ws += N_NODES * 4;
  float* gate    = (float*)ws; ws += N_NODES * 4;
  float* sums    = (float*)ws; ws += 2 * DIM * 4;
  float* scale   = (float*)ws; ws += DIM * 4;
  float* shift   = (float*)ws; ws += DIM * 4;
  float* gmax    = (float*)ws; ws += NG * 4;
  float* gden    = (float*)ws; ws += NG * 4;
  int*   starts  = (int*)ws;   ws += (NG + 1) * 4;
  int*   bsum    = (int*)ws;   ws += NB * 4;
  int*   boff    = (int*)ws;   ws += NB * 4;
  int*   rank    = (int*)agg;  // alias: rank dead before spmm writes agg

  hipMemsetAsync(cntO,  0, N_NODES * 4, stream);
  hipMemsetAsync(cnt,   0, N_NODES * 4, stream);
  hipMemsetAsync(sums,  0, 2 * DIM * 4, stream);
  hipMemsetAsync(d_out, 0, (size_t)out_size * 4, stream);

  // graph structure (built once, used by both layers)
  k_histO<<<8 * HNBLK, 1024, 0, stream>>>(src, cntO);
  k_rank<<<(N_EDGES + 255) / 256, 256, 0, stream>>>(dst, cnt, rank);
  k_scan_part<<<NB, 256, 0, stream>>>(cnt, bsum);
  k_scan_mid<<<1, 128, 0, stream>>>(bsum, boff, rowstart);
  k_scan_fin<<<NB, 256, 0, stream>>>(cnt, boff, rowstart);
  k_scatter<<<(N_EDGES + 255) / 256, 256, 0, stream>>>(src, dst, rowstart, rank, csr);
  k_starts_init<<<1, NG + 1, 0, stream>>>(starts);
  k_starts_fill<<<(N_NODES + 255) / 256, 256, 0, stream>>>(gid, starts);

  // init_avg_h -> out[NG*DIM ..]
  k_seg_accum<<<NG * 8, DIM, 0, stream>>>(h, starts, out + NG * DIM);
  k_avg_div<<<NG, DIM, 0, stream>>>(starts, out + NG * DIM);

  // layer 1
  k_bnstats<<<NB, 256, 0, stream>>>(h, sums);
  k_bnfin<<<1, DIM, 0, stream>>>(sums, gamma, beta, scale, shift);
  k_bnx<<<N_NODES * 32 / 256, 256, 0, stream>>>(h, scale, shift, cntO, xb);
  k_spmm_pull<<<N_NODES / 4, dim3(64, 4), 0, stream>>>(xb, csr, rowstart, agg);
  k_conv<<<N_NODES / 32, 256, 0, stream>>>(agg, W1, b1, h, h12, nullptr, nullptr, nullptr);

  // layer 2
  hipMemsetAsync(sums, 0, 2 * DIM * 4, stream);
  k_bnstats<<<NB, 256, 0, stream>>>(h12, sums);
  k_bnfin<<<1, DIM, 0, stream>>>(sums, gamma, beta, scale, shift);
  k_bnx<<<N_NODES * 32 / 256, 256, 0, stream>>>(h12, scale, shift, cntO, xb);
  k_spmm_pull<<<N_NODES / 4, dim3(64, 4), 0, stream>>>(xb, csr, rowstart, agg);
  k_conv<<<N_NODES / 32, 256, 0, stream>>>(agg, W2, b2, h12, h12, gW, gb, gate);

  // pooling
  k_gstats<<<NG, 256, 0, stream>>>(gate, starts, gmax, gden);
  k_pool<<<NG * 8, DIM, 0, stream>>>(h12, gate, starts, gmax, gden, out);
}

// Round 9
// 518.844 us; speedup vs baseline: 14.2957x; 1.2252x over previous
//
#include <hip/hip_runtime.h>
#include <math.h>

#define N_NODES 100000
#define N_EDGES 1600000
#define DIM     128
#define NG      64
#define BN_EPS  1e-5f
#define NB      98     // scan blocks
#define HRANGE  12500  // nodes per histogram range (50 KB LDS)
#define HNBLK   8      // blocks per range

typedef __attribute__((ext_vector_type(8))) short bf16x8;
typedef __attribute__((ext_vector_type(4))) float f32x4;

__device__ __forceinline__ unsigned short f2bf(float f) {
  unsigned b = __float_as_uint(f);
  unsigned r = (b + 0x7FFFu + ((b >> 16) & 1u)) >> 16;   // RNE
  return (unsigned short)r;
}

// ---------------------------------------------------------------- out-degree histogram
__launch_bounds__(1024)
__global__ void k_histO(const int* __restrict__ src, int* __restrict__ cntO) {
  __shared__ int histo[HRANGE];   // 50 KB
  int t = threadIdx.x;
  int range = blockIdx.x >> 3, blk = blockIdx.x & 7;
  int lo = range * HRANGE;
  for (int j = t; j < HRANGE; j += 1024) histo[j] = 0;
  __syncthreads();
  const int SLICE = N_EDGES / HNBLK;            // 200000
  const int4* sp = (const int4*)(src + blk * SLICE);
  const int n4 = SLICE / 4;                     // 50000
  for (int q = t; q < n4; q += 1024) {
    int4 v = sp[q];
    unsigned a = (unsigned)(v.x - lo), b = (unsigned)(v.y - lo);
    unsigned c = (unsigned)(v.z - lo), d = (unsigned)(v.w - lo);
    if (a < (unsigned)HRANGE) atomicAdd(&histo[a], 1);
    if (b < (unsigned)HRANGE) atomicAdd(&histo[b], 1);
    if (c < (unsigned)HRANGE) atomicAdd(&histo[c], 1);
    if (d < (unsigned)HRANGE) atomicAdd(&histo[d], 1);
  }
  __syncthreads();
  for (int j = t; j < HRANGE; j += 1024) {
    int v = histo[j];
    if (v) atomicAdd(&cntO[lo + j], v);
  }
}

// ---------------------------------------------------------------- in-degree count + per-edge rank
__global__ void k_rank(const int* __restrict__ dst, int* __restrict__ cnt,
                       int* __restrict__ rank) {
  int e = blockIdx.x * blockDim.x + threadIdx.x;
  if (e < N_EDGES) rank[e] = atomicAdd(&cnt[dst[e]], 1);
}

// ---------------------------------------------------------------- 3-pass scan of cnt -> rowstart
__global__ void k_scan_part(const int* __restrict__ cnt, int* __restrict__ bsum) {
  int b = blockIdx.x, t = threadIdx.x;
  int base = b * 1024 + t * 4;
  int s = 0;
#pragma unroll
  for (int j = 0; j < 4; ++j) { int i = base + j; if (i < N_NODES) s += cnt[i]; }
  __shared__ int red[256];
  red[t] = s; __syncthreads();
  for (int w = 128; w; w >>= 1) { if (t < w) red[t] += red[t + w]; __syncthreads(); }
  if (t == 0) bsum[b] = red[0];
}

__global__ void k_scan_mid(const int* __restrict__ bsum, int* __restrict__ boff,
                           int* __restrict__ rowstart) {
  int t = threadIdx.x;  // 128 >= NB
  __shared__ int sh[128];
  int own = (t < NB) ? bsum[t] : 0;
  sh[t] = own;
  __syncthreads();
  for (int off = 1; off < 128; off <<= 1) {
    int v = (t >= off) ? sh[t - off] : 0;
    __syncthreads();
    sh[t] += v;
    __syncthreads();
  }
  if (t < NB) boff[t] = sh[t] - own;
  if (t == NB - 1) rowstart[N_NODES] = sh[t];
}

__global__ void k_scan_fin(const int* __restrict__ cnt, const int* __restrict__ boff,
                           int* __restrict__ rowstart) {
  int b = blockIdx.x, t = threadIdx.x;
  int base = b * 1024 + t * 4;
  int v0 = 0, v1 = 0, v2 = 0, v3 = 0;
  if (base + 0 < N_NODES) v0 = cnt[base + 0];
  if (base + 1 < N_NODES) v1 = cnt[base + 1];
  if (base + 2 < N_NODES) v2 = cnt[base + 2];
  if (base + 3 < N_NODES) v3 = cnt[base + 3];
  int tsum = v0 + v1 + v2 + v3;
  __shared__ int sh[256];
  sh[t] = tsum;
  __syncthreads();
  for (int off = 1; off < 256; off <<= 1) {
    int v = (t >= off) ? sh[t - off] : 0;
    __syncthreads();
    sh[t] += v;
    __syncthreads();
  }
  int run = boff[b] + sh[t] - tsum;
  if (base + 0 < N_NODES) rowstart[base + 0] = run; run += v0;
  if (base + 1 < N_NODES) rowstart[base + 1] = run; run += v1;
  if (base + 2 < N_NODES) rowstart[base + 2] = run; run += v2;
  if (base + 3 < N_NODES) rowstart[base + 3] = run;
}

// ---------------------------------------------------------------- scatter (no atomics)
__global__ void k_scatter(const int* __restrict__ src, const int* __restrict__ dst,
                          const int* __restrict__ rowstart, const int* __restrict__ rank,
                          int* __restrict__ csr) {
  int e = blockIdx.x * blockDim.x + threadIdx.x;
  if (e < N_EDGES) {
    int d = dst[e];
    csr[rowstart[d] + rank[e]] = src[e];
  }
}

// ---------------------------------------------------------------- graph CSR starts
__global__ void k_starts_init(int* __restrict__ starts) {
  int g = threadIdx.x;
  if (g <= NG) starts[g] = N_NODES;
}

__global__ void k_starts_fill(const int* __restrict__ gid, int* __restrict__ starts) {
  int i = blockIdx.x * blockDim.x + threadIdx.x;
  if (i >= N_NODES) return;
  int gi = gid[i];
  if (i == 0) {
    for (int g = 0; g <= gi; ++g) starts[g] = 0;
  } else {
    int gp = gid[i - 1];
    if (gp != gi) for (int g = gp + 1; g <= gi; ++g) starts[g] = i;
  }
}

// ---------------------------------------------------------------- init_avg accumulation (float4 + LDS reduce)
__launch_bounds__(256)
__global__ void k_seg_accum(const float* __restrict__ h, const int* __restrict__ starts,
                            float* __restrict__ outp) {
  __shared__ float ls[8][DIM];
  int g = blockIdx.x >> 5, part = blockIdx.x & 31;
  int s = starts[g], e = starts[g + 1];
  int t = threadIdx.x;
  int col4 = (t & 31) * 4, rg = t >> 5;
  float4 acc = {0.f, 0.f, 0.f, 0.f};
  for (int i = s + part + rg * 32; i < e; i += 256) {
    float4 v = *(const float4*)&h[(size_t)i * DIM + col4];
    acc.x += v.x; acc.y += v.y; acc.z += v.z; acc.w += v.w;
  }
  *(float4*)&ls[rg][col4] = acc;
  __syncthreads();
  if (t < DIM) {
    float a = 0.f;
#pragma unroll
    for (int j = 0; j < 8; ++j) a += ls[j][t];
    atomicAdd(&outp[g * DIM + t], a);
  }
}

__global__ void k_avg_div(const int* __restrict__ starts, float* __restrict__ outp) {
  int g = blockIdx.x, d = threadIdx.x;
  float cnt = fmaxf((float)(starts[g + 1] - starts[g]), 1.0f);
  outp[g * DIM + d] /= cnt;
}

// ---------------------------------------------------------------- BN column stats
__launch_bounds__(256)
__global__ void k_bnstats(const float* __restrict__ x, float* __restrict__ sums) {
  __shared__ float ls[8][DIM];
  __shared__ float ls2[8][DIM];
  int t = threadIdx.x;
  int col4 = (t & 31) * 4, rg = t >> 5;
  float4 s = {0.f,0.f,0.f,0.f}, s2 = {0.f,0.f,0.f,0.f};
  int rend = min(blockIdx.x * 1024 + 1024, N_NODES);
  for (int r = blockIdx.x * 1024 + rg; r < rend; r += 8) {
    float4 v = *(const float4*)&x[(size_t)r * DIM + col4];
    s.x += v.x; s.y += v.y; s.z += v.z; s.w += v.w;
    s2.x += v.x*v.x; s2.y += v.y*v.y; s2.z += v.z*v.z; s2.w += v.w*v.w;
  }
  *(float4*)&ls[rg][col4] = s;
  *(float4*)&ls2[rg][col4] = s2;
  __syncthreads();
  if (t < DIM) {
    float a = 0.f, b = 0.f;
#pragma unroll
    for (int j = 0; j < 8; ++j) { a += ls[j][t]; b += ls2[j][t]; }
    atomicAdd(&sums[t], a);
    atomicAdd(&sums[DIM + t], b);
  }
}

__global__ void k_bnfin(const float* __restrict__ sums, const float* __restrict__ gamma,
                        const float* __restrict__ beta, float* __restrict__ scale,
                        float* __restrict__ shift) {
  int d = threadIdx.x;
  float m = sums[d] * (1.0f / N_NODES);
  float v = sums[DIM + d] * (1.0f / N_NODES) - m * m;
  float rs = rsqrtf(fmaxf(v, 0.f) + BN_EPS) * gamma[d];
  scale[d] = rs;
  shift[d] = beta[d] - m * rs;
}

// ---------------------------------------------------------------- xb = bf16((x*scale + shift) * rsqrt(outdeg))
__launch_bounds__(256)
__global__ void k_bnx(const float* __restrict__ x, const float* __restrict__ scale,
                      const float* __restrict__ shift, const int* __restrict__ cntO,
                      unsigned short* __restrict__ xb) {
  int idx = blockIdx.x * 256 + threadIdx.x;
  int row = idx >> 5, c4 = (idx & 31) * 4;
  float4 v  = *(const float4*)&x[(size_t)row * DIM + c4];
  float4 sc = *(const float4*)&scale[c4];
  float4 sh = *(const float4*)&shift[c4];
  float f = rsqrtf(fmaxf((float)cntO[row], 1.0f));
  ushort4 o;
  o.x = f2bf((v.x * sc.x + sh.x) * f);
  o.y = f2bf((v.y * sc.y + sh.y) * f);
  o.z = f2bf((v.z * sc.z + sh.z) * f);
  o.w = f2bf((v.w * sc.w + sh.w) * f);
  *(ushort4*)&xb[(size_t)row * DIM + c4] = o;
}

// ---------------------------------------------------------------- W -> bf16 transposed (WbT[c][k])
__global__ void k_prepW(const float* __restrict__ W1, const float* __restrict__ W2,
                        unsigned short* __restrict__ WbT1, unsigned short* __restrict__ WbT2) {
  int idx = blockIdx.x * 256 + threadIdx.x;   // 32768
  int which = idx >> 14;
  int i = idx & 16383;
  int k = i >> 7, c = i & 127;
  const float* W = which ? W2 : W1;
  unsigned short* O = which ? WbT2 : WbT1;
  O[c * DIM + k] = f2bf(W[k * DIM + c]);
}

// ---------------------------------------------------------------- pull-mode SpMM -> bf16 agg
__launch_bounds__(256, 8)
__global__ void k_spmm_pull(const unsigned short* __restrict__ xb, const int* __restrict__ csr,
                            const int* __restrict__ rowstart, unsigned short* __restrict__ aggb) {
  int row = blockIdx.x * 4 + threadIdx.y;
  int l = threadIdx.x;
  int half = l >> 5, l32 = l & 31;
  int s = rowstart[row], e = rowstart[row + 1];
  float4 acc = {0.f, 0.f, 0.f, 0.f};
  const size_t coff = (size_t)l32 * 4;
  int i = s + half;
  for (; i + 6 < e; i += 8) {
    int s0 = csr[i], s1 = csr[i + 2], s2 = csr[i + 4], s3 = csr[i + 6];
    uint2 w0 = *(const uint2*)&xb[(size_t)s0 * DIM + coff];
    uint2 w1 = *(const uint2*)&xb[(size_t)s1 * DIM + coff];
    uint2 w2 = *(const uint2*)&xb[(size_t)s2 * DIM + coff];
    uint2 w3 = *(const uint2*)&xb[(size_t)s3 * DIM + coff];
    acc.x += __uint_as_float(w0.x << 16) + __uint_as_float(w1.x << 16)
           + __uint_as_float(w2.x << 16) + __uint_as_float(w3.x << 16);
    acc.y += __uint_as_float(w0.x & 0xFFFF0000u) + __uint_as_float(w1.x & 0xFFFF0000u)
           + __uint_as_float(w2.x & 0xFFFF0000u) + __uint_as_float(w3.x & 0xFFFF0000u);
    acc.z += __uint_as_float(w0.y << 16) + __uint_as_float(w1.y << 16)
           + __uint_as_float(w2.y << 16) + __uint_as_float(w3.y << 16);
    acc.w += __uint_as_float(w0.y & 0xFFFF0000u) + __uint_as_float(w1.y & 0xFFFF0000u)
           + __uint_as_float(w2.y & 0xFFFF0000u) + __uint_as_float(w3.y & 0xFFFF0000u);
  }
  for (; i < e; i += 2) {
    int s0 = csr[i];
    uint2 w0 = *(const uint2*)&xb[(size_t)s0 * DIM + coff];
    acc.x += __uint_as_float(w0.x << 16);
    acc.y += __uint_as_float(w0.x & 0xFFFF0000u);
    acc.z += __uint_as_float(w0.y << 16);
    acc.w += __uint_as_float(w0.y & 0xFFFF0000u);
  }
  acc.x += __shfl_xor(acc.x, 32);
  acc.y += __shfl_xor(acc.y, 32);
  acc.z += __shfl_xor(acc.z, 32);
  acc.w += __shfl_xor(acc.w, 32);
  if (half == 0) {
    float isi = rsqrtf(fmaxf((float)(e - s), 1.0f));
    ushort4 o;
    o.x = f2bf(acc.x * isi);
    o.y = f2bf(acc.y * isi);
    o.z = f2bf(acc.z * isi);
    o.w = f2bf(acc.w * isi);
    *(ushort4*)&aggb[(size_t)row * DIM + l32 * 4] = o;
  }
}

// ---------------------------------------------------------------- MFMA conv: relu(aggb@W + b) + hres (+ fused gate)
// 64 rows x 128 cols / block, 4 waves (2x2), mfma_f32_16x16x32_bf16.
// LDS rows padded to 136 ushorts (272 B) -> bank spread without breaking 16B alignment.
__launch_bounds__(256)
__global__ void k_conv(const unsigned short* __restrict__ aggb,
                       const unsigned short* __restrict__ WbT,
                       const float* __restrict__ bias, const float* __restrict__ hres,
                       float* __restrict__ outp,
                       const float* __restrict__ gWp, const float* __restrict__ gbp,
                       float* __restrict__ gatep) {
  __shared__ unsigned short As[64 * 136];    // 17408 B
  __shared__ unsigned short Ws[128 * 136];   // 34816 B (aliased as Of[64][132] f32 in epilogue)
  __shared__ float gsh[64];
  float* Of = (float*)Ws;
  int t = threadIdx.x;
  int row0 = blockIdx.x * 64;

  if (gatep && t < 64) gsh[t] = 0.f;

  // stage A: 64 rows x 128 bf16 (zero-pad OOB rows)
  for (int i = t; i < 1024; i += 256) {        // int4 units (8 bf16)
    int r = i >> 4, q = i & 15;
    int row = row0 + r;
    int4 v = {0, 0, 0, 0};
    if (row < N_NODES) v = *(const int4*)&aggb[(size_t)row * DIM + q * 8];
    *(int4*)&As[r * 136 + q * 8] = v;
  }
  // stage W^T: 128 cols x 128 k bf16
  for (int i = t; i < 2048; i += 256) {
    int c = i >> 4, q = i & 15;
    *(int4*)&Ws[c * 136 + q * 8] = *(const int4*)&WbT[(size_t)c * DIM + q * 8];
  }
  __syncthreads();

  int wid = t >> 6, l = t & 63;
  int wr = wid >> 1, wc = wid & 1;
  int lr = l & 15, lq = l >> 4;
  f32x4 acc[2][4] = {};
  const unsigned short* Ab = &As[(wr * 32 + lr) * 136 + lq * 8];
  const unsigned short* Bb = &Ws[(wc * 64 + lr) * 136 + lq * 8];
#pragma unroll
  for (int kk = 0; kk < 4; ++kk) {
    bf16x8 a0 = *(const bf16x8*)(Ab + kk * 32);
    bf16x8 a1 = *(const bf16x8*)(Ab + 16 * 136 + kk * 32);
    bf16x8 b0 = *(const bf16x8*)(Bb + kk * 32);
    bf16x8 b1 = *(const bf16x8*)(Bb + 16 * 136 + kk * 32);
    bf16x8 b2 = *(const bf16x8*)(Bb + 32 * 136 + kk * 32);
    bf16x8 b3 = *(const bf16x8*)(Bb + 48 * 136 + kk * 32);
    acc[0][0] = __builtin_amdgcn_mfma_f32_16x16x32_bf16(a0, b0, acc[0][0], 0, 0, 0);
    acc[0][1] = __builtin_amdgcn_mfma_f32_16x16x32_bf16(a0, b1, acc[0][1], 0, 0, 0);
    acc[0][2] = __builtin_amdgcn_mfma_f32_16x16x32_bf16(a0, b2, acc[0][2], 0, 0, 0);
    acc[0][3] = __builtin_amdgcn_mfma_f32_16x16x32_bf16(a0, b3, acc[0][3], 0, 0, 0);
    acc[1][0] = __builtin_amdgcn_mfma_f32_16x16x32_bf16(a1, b0, acc[1][0], 0, 0, 0);
    acc[1][1] = __builtin_amdgcn_mfma_f32_16x16x32_bf16(a1, b1, acc[1][1], 0, 0, 0);
    acc[1][2] = __builtin_amdgcn_mfma_f32_16x16x32_bf16(a1, b2, acc[1][2], 0, 0, 0);
    acc[1][3] = __builtin_amdgcn_mfma_f32_16x16x32_bf16(a1, b3, acc[1][3], 0, 0, 0);
  }
  __syncthreads();   // all waves done reading Ws before Of overwrites it

  // scatter accumulators to Of: D layout col=lane&15, row=(lane>>4)*4+reg  [m89-verified]
#pragma unroll
  for (int rt = 0; rt < 2; ++rt) {
#pragma unroll
    for (int ct = 0; ct < 4; ++ct) {
      int rr = wr * 32 + rt * 16 + lq * 4;
      int cc = wc * 64 + ct * 16 + lr;
#pragma unroll
      for (int i = 0; i < 4; ++i)
        Of[(rr + i) * 132 + cc] = acc[rt][ct][i];
    }
  }
  __syncthreads();

  // coalesced epilogue: bias + relu + residual (+ gate partial)
#pragma unroll
  for (int i = 0; i < 8; ++i) {
    int fi = t + i * 256;
    int r = fi >> 5, c4 = (fi & 31) * 4;
    int row = row0 + r;
    if (row < N_NODES) {
      float4 o  = *(float4*)&Of[r * 132 + c4];
      float4 bv = *(const float4*)&bias[c4];
      float4 hv = *(const float4*)&hres[(size_t)row * DIM + c4];
      float4 y = {hv.x + fmaxf(o.x + bv.x, 0.f), hv.y + fmaxf(o.y + bv.y, 0.f),
                  hv.z + fmaxf(o.z + bv.z, 0.f), hv.w + fmaxf(o.w + bv.w, 0.f)};
      *(float4*)&outp[(size_t)row * DIM + c4] = y;
      if (gatep) {
        float4 gw = *(const float4*)&gWp[c4];
        atomicAdd(&gsh[r], y.x * gw.x + y.y * gw.y + y.z * gw.z + y.w * gw.w);
      }
    }
  }
  if (gatep) {
    __syncthreads();
    int row = row0 + t;
    if (t < 64 && row < N_NODES) gatep[row] = gsh[t] + gbp[0];
  }
}

// ---------------------------------------------------------------- per-graph softmax stats
__global__ void k_gstats(const float* __restrict__ gate, const int* __restrict__ starts,
                         float* __restrict__ gmax, float* __restrict__ gden) {
  int g = blockIdx.x;
  int s = starts[g], e = starts[g + 1];
  int t = threadIdx.x;
  __shared__ float red[256];
  float m = -INFINITY;
  for (int i = s + t; i < e; i += 256) m = fmaxf(m, gate[i]);
  red[t] = m; __syncthreads();
  for (int w = 128; w; w >>= 1) { if (t < w) red[t] = fmaxf(red[t], red[t + w]); __syncthreads(); }
  float mg = red[0]; __syncthreads();
  float ssum = 0.f;
  for (int i = s + t; i < e; i += 256) ssum += expf(gate[i] - mg);
  red[t] = ssum; __syncthreads();
  for (int w = 128; w; w >>= 1) { if (t < w) red[t] += red[t + w]; __syncthreads(); }
  if (t == 0) { gmax[g] = mg; gden[g] = red[0]; }
}

// ---------------------------------------------------------------- weighted pooling
__global__ void k_pool(const float* __restrict__ h2, const float* __restrict__ gate,
                       const int* __restrict__ starts, const float* __restrict__ gmax,
                       const float* __restrict__ gden, float* __restrict__ outp) {
  int g = blockIdx.x >> 3, part = blockIdx.x & 7;
  int s = starts[g], e = starts[g + 1];
  int d = threadIdx.x;
  float mg = gmax[g];
  float dn = gden[g];
  float invden = dn > 0.f ? 1.0f / dn : 0.f;
  float acc = 0.f;
  for (int i = s + part; i < e; i += 8) {
    float w = expf(gate[i] - mg) * invden;
    acc += w * h2[(size_t)i * DIM + d];
  }
  atomicAdd(&outp[g * DIM + d], acc);
}

// ---------------------------------------------------------------- launch
extern "C" void kernel_launch(void* const* d_in, const int* in_sizes, int n_in,
                              void* d_out, int out_size, void* d_ws, size_t ws_size,
                              hipStream_t stream) {
  const float* h    = (const float*)d_in[0];
  const int*   src  = (const int*)d_in[1];
  const int*   dst  = (const int*)d_in[2];
  const int*   gid  = (const int*)d_in[3];
  const float* W1   = (const float*)d_in[5];
  const float* b1   = (const float*)d_in[6];
  const float* W2   = (const float*)d_in[7];
  const float* b2   = (const float*)d_in[8];
  const float* gW   = (const float*)d_in[9];
  const float* gb   = (const float*)d_in[10];
  const float* gamma= (const float*)d_in[11];
  const float* beta = (const float*)d_in[12];
  float* out = (float*)d_out;

  char* ws = (char*)d_ws;
  float* h12     = (float*)ws; ws += (size_t)N_NODES * DIM * 4;
  unsigned short* xb   = (unsigned short*)ws; ws += (size_t)N_NODES * DIM * 2;
  unsigned short* aggb = (unsigned short*)ws; ws += (size_t)N_NODES * DIM * 2;
  int*   csr     = (int*)ws;   ws += (size_t)N_EDGES * 4;
  unsigned short* WbT1 = (unsigned short*)ws; ws += DIM * DIM * 2;
  unsigned short* WbT2 = (unsigned short*)ws; ws += DIM * DIM * 2;
  int*   rowstart= (int*)ws;   ws += (N_NODES + 1) * 4;
  int*   cnt     = (int*)ws;   ws += N_NODES * 4;
  int*   cntO    = (int*)ws;   ws += N_NODES * 4;
  float* gate    = (float*)ws; ws += N_NODES * 4;
  float* sums    = (float*)ws; ws += 2 * DIM * 4;
  float* scale   = (float*)ws; ws += DIM * 4;
  float* shift   = (float*)ws; ws += DIM * 4;
  float* gmax    = (float*)ws; ws += NG * 4;
  float* gden    = (float*)ws; ws += NG * 4;
  int*   starts  = (int*)ws;   ws += (NG + 1) * 4;
  int*   bsum    = (int*)ws;   ws += NB * 4;
  int*   boff    = (int*)ws;   ws += NB * 4;
  int*   rank    = (int*)h12;  // alias: rank dead before conv1 writes h12

  hipMemsetAsync(cntO,  0, N_NODES * 4, stream);
  hipMemsetAsync(cnt,   0, N_NODES * 4, stream);
  hipMemsetAsync(sums,  0, 2 * DIM * 4, stream);
  hipMemsetAsync(d_out, 0, (size_t)out_size * 4, stream);

  // graph structure (built once, used by both layers)
  k_histO<<<8 * HNBLK, 1024, 0, stream>>>(src, cntO);
  k_rank<<<(N_EDGES + 255) / 256, 256, 0, stream>>>(dst, cnt, rank);
  k_scan_part<<<NB, 256, 0, stream>>>(cnt, bsum);
  k_scan_mid<<<1, 128, 0, stream>>>(bsum, boff, rowstart);
  k_scan_fin<<<NB, 256, 0, stream>>>(cnt, boff, rowstart);
  k_scatter<<<(N_EDGES + 255) / 256, 256, 0, stream>>>(src, dst, rowstart, rank, csr);
  k_starts_init<<<1, NG + 1, 0, stream>>>(starts);
  k_starts_fill<<<(N_NODES + 255) / 256, 256, 0, stream>>>(gid, starts);
  k_prepW<<<128, 256, 0, stream>>>(W1, W2, WbT1, WbT2);

  // init_avg_h -> out[NG*DIM ..]
  k_seg_accum<<<NG * 32, 256, 0, stream>>>(h, starts, out + NG * DIM);
  k_avg_div<<<NG, DIM, 0, stream>>>(starts, out + NG * DIM);

  // layer 1
  k_bnstats<<<NB, 256, 0, stream>>>(h, sums);
  k_bnfin<<<1, DIM, 0, stream>>>(sums, gamma, beta, scale, shift);
  k_bnx<<<N_NODES * 32 / 256, 256, 0, stream>>>(h, scale, shift, cntO, xb);
  k_spmm_pull<<<N_NODES / 4, dim3(64, 4), 0, stream>>>(xb, csr, rowstart, aggb);
  k_conv<<<(N_NODES + 63) / 64, 256, 0, stream>>>(aggb, WbT1, b1, h, h12,
                                                  nullptr, nullptr, nullptr);

  // layer 2
  hipMemsetAsync(sums, 0, 2 * DIM * 4, stream);
  k_bnstats<<<NB, 256, 0, stream>>>(h12, sums);
  k_bnfin<<<1, DIM, 0, stream>>>(sums, gamma, beta, scale, shift);
  k_bnx<<<N_NODES * 32 / 256, 256, 0, stream>>>(h12, scale, shift, cntO, xb);
  k_spmm_pull<<<N_NODES / 4, dim3(64, 4), 0, stream>>>(xb, csr, rowstart, aggb);
  k_conv<<<(N_NODES + 63) / 64, 256, 0, stream>>>(aggb, WbT2, b2, h12, h12,
                                                  gW, gb, gate);

  // pooling
  k_gstats<<<NG, 256, 0, stream>>>(gate, starts, gmax, gden);
  k_pool<<<NG * 8, DIM, 0, stream>>>(h12, gate, starts, gmax, gden, out);
}

// Round 10
// 440.676 us; speedup vs baseline: 16.8315x; 1.1774x over previous
//
#include <hip/hip_runtime.h>
#include <math.h>

#define N_NODES 100000
#define N_EDGES 1600000
#define DIM     128
#define NG      64
#define BN_EPS  1e-5f
#define NB      98       // scan blocks (1024 nodes each)
#define HRANGE  12500    // nodes per LDS range (50 KB)
#define NSLICE  16       // edge slices
#define ESLICE  (N_EDGES / NSLICE)   // 100000
#define NBLK_CONV 1563   // ceil(N_NODES/64)

typedef __attribute__((ext_vector_type(8))) short bf16x8;
typedef __attribute__((ext_vector_type(4))) float f32x4;

__device__ __forceinline__ unsigned short f2bf(float f) {
  unsigned b = __float_as_uint(f);
  unsigned r = (b + 0x7FFFu + ((b >> 16) & 1u)) >> 16;   // RNE
  return (unsigned short)r;
}

// ---------------------------------------------------------------- out-degree histogram (src)
__launch_bounds__(1024)
__global__ void k_histO(const int* __restrict__ src, int* __restrict__ cntO) {
  __shared__ int histo[HRANGE];
  int t = threadIdx.x;
  int range = blockIdx.x >> 3, blk = blockIdx.x & 7;
  int lo = range * HRANGE;
  for (int j = t; j < HRANGE; j += 1024) histo[j] = 0;
  __syncthreads();
  const int SLICE = N_EDGES / 8;
  const int4* sp = (const int4*)(src + blk * SLICE);
  const int n4 = SLICE / 4;
  for (int q = t; q < n4; q += 1024) {
    int4 v = sp[q];
    unsigned a = (unsigned)(v.x - lo), b = (unsigned)(v.y - lo);
    unsigned c = (unsigned)(v.z - lo), d = (unsigned)(v.w - lo);
    if (a < (unsigned)HRANGE) atomicAdd(&histo[a], 1);
    if (b < (unsigned)HRANGE) atomicAdd(&histo[b], 1);
    if (c < (unsigned)HRANGE) atomicAdd(&histo[c], 1);
    if (d < (unsigned)HRANGE) atomicAdd(&histo[d], 1);
  }
  __syncthreads();
  for (int j = t; j < HRANGE; j += 1024) {
    int v = histo[j];
    if (v) atomicAdd(&cntO[lo + j], v);
  }
}

// ---------------------------------------------------------------- in-degree per-slice histogram (dst)
// block = (range, slice); exclusive writes, no global atomics
__launch_bounds__(1024)
__global__ void k_histD(const int* __restrict__ dst, int* __restrict__ cnt_slice) {
  __shared__ int histo[HRANGE];
  int t = threadIdx.x;
  int range = blockIdx.x >> 4, slice = blockIdx.x & 15;
  int lo = range * HRANGE;
  for (int j = t; j < HRANGE; j += 1024) histo[j] = 0;
  __syncthreads();
  const int4* dp = (const int4*)(dst + slice * ESLICE);
  for (int q = t; q < ESLICE / 4; q += 1024) {
    int4 v = dp[q];
    unsigned a = (unsigned)(v.x - lo), b = (unsigned)(v.y - lo);
    unsigned c = (unsigned)(v.z - lo), d = (unsigned)(v.w - lo);
    if (a < (unsigned)HRANGE) atomicAdd(&histo[a], 1);
    if (b < (unsigned)HRANGE) atomicAdd(&histo[b], 1);
    if (c < (unsigned)HRANGE) atomicAdd(&histo[c], 1);
    if (d < (unsigned)HRANGE) atomicAdd(&histo[d], 1);
  }
  __syncthreads();
  for (int j = t; j < HRANGE; j += 1024)
    cnt_slice[(size_t)slice * N_NODES + lo + j] = histo[j];
}

// ---------------------------------------------------------------- scan pass 1: block sums (+ write total cnt)
__global__ void k_scan_part(const int* __restrict__ cnt_slice, int* __restrict__ cnt,
                            int* __restrict__ bsum) {
  int b = blockIdx.x, t = threadIdx.x;
  int base = b * 1024 + t * 4;
  int tot = 0;
#pragma unroll
  for (int j = 0; j < 4; ++j) {
    int i = base + j;
    if (i < N_NODES) {
      int c = 0;
#pragma unroll
      for (int s = 0; s < NSLICE; ++s) c += cnt_slice[(size_t)s * N_NODES + i];
      cnt[i] = c;
      tot += c;
    }
  }
  __shared__ int red[256];
  red[t] = tot; __syncthreads();
  for (int w = 128; w; w >>= 1) { if (t < w) red[t] += red[t + w]; __syncthreads(); }
  if (t == 0) bsum[b] = red[0];
}

__global__ void k_scan_mid(const int* __restrict__ bsum, int* __restrict__ boff,
                           int* __restrict__ rowstart) {
  int t = threadIdx.x;  // 128 >= NB
  __shared__ int sh[128];
  int own = (t < NB) ? bsum[t] : 0;
  sh[t] = own;
  __syncthreads();
  for (int off = 1; off < 128; off <<= 1) {
    int v = (t >= off) ? sh[t - off] : 0;
    __syncthreads();
    sh[t] += v;
    __syncthreads();
  }
  if (t < NB) boff[t] = sh[t] - own;
  if (t == NB - 1) rowstart[N_NODES] = sh[t];
}

__global__ void k_scan_fin(const int* __restrict__ cnt, const int* __restrict__ boff,
                           int* __restrict__ rowstart) {
  int b = blockIdx.x, t = threadIdx.x;
  int base = b * 1024 + t * 4;
  int v0 = 0, v1 = 0, v2 = 0, v3 = 0;
  if (base + 0 < N_NODES) v0 = cnt[base + 0];
  if (base + 1 < N_NODES) v1 = cnt[base + 1];
  if (base + 2 < N_NODES) v2 = cnt[base + 2];
  if (base + 3 < N_NODES) v3 = cnt[base + 3];
  int tsum = v0 + v1 + v2 + v3;
  __shared__ int sh[256];
  sh[t] = tsum;
  __syncthreads();
  for (int off = 1; off < 256; off <<= 1) {
    int v = (t >= off) ? sh[t - off] : 0;
    __syncthreads();
    sh[t] += v;
    __syncthreads();
  }
  int run = boff[b] + sh[t] - tsum;
  if (base + 0 < N_NODES) rowstart[base + 0] = run; run += v0;
  if (base + 1 < N_NODES) rowstart[base + 1] = run; run += v1;
  if (base + 2 < N_NODES) rowstart[base + 2] = run; run += v2;
  if (base + 3 < N_NODES) rowstart[base + 3] = run;
}

// ---------------------------------------------------------------- exclusive prefix over slices per node (in place)
__global__ void k_sliceoff(int* __restrict__ cnt_slice) {
  int i = blockIdx.x * 256 + threadIdx.x;
  if (i < N_NODES) {
    int run = 0;
#pragma unroll
    for (int s = 0; s < NSLICE; ++s) {
      int v = cnt_slice[(size_t)s * N_NODES + i];
      cnt_slice[(size_t)s * N_NODES + i] = run;
      run += v;
    }
  }
}

// ---------------------------------------------------------------- scatter via LDS cursor (no global atomics)
__launch_bounds__(1024)
__global__ void k_scatter_slice(const int* __restrict__ src, const int* __restrict__ dst,
                                const int* __restrict__ rowstart,
                                const int* __restrict__ cnt_slice, int* __restrict__ csr) {
  __shared__ int cur[HRANGE];
  int t = threadIdx.x;
  int range = blockIdx.x >> 4, slice = blockIdx.x & 15;
  int lo = range * HRANGE;
  for (int j = t; j < HRANGE; j += 1024)
    cur[j] = rowstart[lo + j] + cnt_slice[(size_t)slice * N_NODES + lo + j];
  __syncthreads();
  const int4* dp = (const int4*)(dst + slice * ESLICE);
  const int4* sp = (const int4*)(src + slice * ESLICE);
  for (int q = t; q < ESLICE / 4; q += 1024) {
    int4 d = dp[q];
    int4 s = sp[q];
    unsigned o;
    o = (unsigned)(d.x - lo); if (o < (unsigned)HRANGE) { int p = atomicAdd(&cur[o], 1); csr[p] = s.x; }
    o = (unsigned)(d.y - lo); if (o < (unsigned)HRANGE) { int p = atomicAdd(&cur[o], 1); csr[p] = s.y; }
    o = (unsigned)(d.z - lo); if (o < (unsigned)HRANGE) { int p = atomicAdd(&cur[o], 1); csr[p] = s.z; }
    o = (unsigned)(d.w - lo); if (o < (unsigned)HRANGE) { int p = atomicAdd(&cur[o], 1); csr[p] = s.w; }
  }
}

// ---------------------------------------------------------------- graph CSR starts
__global__ void k_starts_init(int* __restrict__ starts) {
  int g = threadIdx.x;
  if (g <= NG) starts[g] = N_NODES;
}

__global__ void k_starts_fill(const int* __restrict__ gid, int* __restrict__ starts) {
  int i = blockIdx.x * blockDim.x + threadIdx.x;
  if (i >= N_NODES) return;
  int gi = gid[i];
  if (i == 0) {
    for (int g = 0; g <= gi; ++g) starts[g] = 0;
  } else {
    int gp = gid[i - 1];
    if (gp != gi) for (int g = gp + 1; g <= gi; ++g) starts[g] = i;
  }
}

// ---------------------------------------------------------------- fused: BN column stats + per-graph init_avg sums (one pass over h)
__launch_bounds__(256)
__global__ void k_stats1(const float* __restrict__ x, const int* __restrict__ gid,
                         float* __restrict__ sums, float* __restrict__ initavg) {
  __shared__ float ls[8][DIM];
  __shared__ float ls2[8][DIM];
  __shared__ float lseg[4][8][DIM];   // 16 KB: graph slots relative to block's first graph
  __shared__ int g0s;
  int t = threadIdx.x;
  int col4 = (t & 31) * 4, rg = t >> 5;
  for (int i = t; i < 4 * 8 * DIM; i += 256) ((float*)lseg)[i] = 0.f;
  int base = blockIdx.x * 1024;
  if (t == 0) g0s = gid[base];
  __syncthreads();
  int g0 = g0s;
  float4 s = {0.f,0.f,0.f,0.f}, s2 = {0.f,0.f,0.f,0.f};
  float4 acc = {0.f,0.f,0.f,0.f};
  int curg = g0;
  int rend = min(base + 1024, N_NODES);
  for (int r = base + rg; r < rend; r += 8) {
    float4 v = *(const float4*)&x[(size_t)r * DIM + col4];
    s.x += v.x; s.y += v.y; s.z += v.z; s.w += v.w;
    s2.x += v.x*v.x; s2.y += v.y*v.y; s2.z += v.z*v.z; s2.w += v.w*v.w;
    int g = gid[r];
    if (g != curg) {
      int slot = curg - g0;
      if (slot < 4) {
        lseg[slot][rg][col4+0] = acc.x; lseg[slot][rg][col4+1] = acc.y;
        lseg[slot][rg][col4+2] = acc.z; lseg[slot][rg][col4+3] = acc.w;
      } else {
        atomicAdd(&initavg[curg * DIM + col4+0], acc.x);
        atomicAdd(&initavg[curg * DIM + col4+1], acc.y);
        atomicAdd(&initavg[curg * DIM + col4+2], acc.z);
        atomicAdd(&initavg[curg * DIM + col4+3], acc.w);
      }
      acc.x = acc.y = acc.z = acc.w = 0.f;
      curg = g;
    }
    acc.x += v.x; acc.y += v.y; acc.z += v.z; acc.w += v.w;
  }
  {
    int slot = curg - g0;
    if (slot < 4) {
      lseg[slot][rg][col4+0] = acc.x; lseg[slot][rg][col4+1] = acc.y;
      lseg[slot][rg][col4+2] = acc.z; lseg[slot][rg][col4+3] = acc.w;
    } else {
      atomicAdd(&initavg[curg * DIM + col4+0], acc.x);
      atomicAdd(&initavg[curg * DIM + col4+1], acc.y);
      atomicAdd(&initavg[curg * DIM + col4+2], acc.z);
      atomicAdd(&initavg[curg * DIM + col4+3], acc.w);
    }
  }
  *(float4*)&ls[rg][col4] = s;
  *(float4*)&ls2[rg][col4] = s2;
  __syncthreads();
  if (t < DIM) {
    float a = 0.f, b = 0.f;
#pragma unroll
    for (int j = 0; j < 8; ++j) { a += ls[j][t]; b += ls2[j][t]; }
    atomicAdd(&sums[t], a);
    atomicAdd(&sums[DIM + t], b);
#pragma unroll
    for (int slot = 0; slot < 4; ++slot) {
      float v = 0.f;
#pragma unroll
      for (int j = 0; j < 8; ++j) v += lseg[slot][j][t];
      int g = g0 + slot;
      if (g < NG && v != 0.f) atomicAdd(&initavg[g * DIM + t], v);
    }
  }
}

__global__ void k_avg_div(const int* __restrict__ starts, float* __restrict__ outp) {
  int g = blockIdx.x, d = threadIdx.x;
  float cnt = fmaxf((float)(starts[g + 1] - starts[g]), 1.0f);
  outp[g * DIM + d] /= cnt;
}

__global__ void k_bnfin(const float* __restrict__ sums, const float* __restrict__ gamma,
                        const float* __restrict__ beta, float* __restrict__ scale,
                        float* __restrict__ shift) {
  int d = threadIdx.x;
  float m = sums[d] * (1.0f / N_NODES);
  float v = sums[DIM + d] * (1.0f / N_NODES) - m * m;
  float rs = rsqrtf(fmaxf(v, 0.f) + BN_EPS) * gamma[d];
  scale[d] = rs;
  shift[d] = beta[d] - m * rs;
}

// ---------------------------------------------------------------- layer-2 stats from conv1 partials
__global__ void k_colred(const float* __restrict__ psum, const float* __restrict__ psq,
                         const float* __restrict__ gamma, const float* __restrict__ beta,
                         float* __restrict__ scale, float* __restrict__ shift) {
  int c = blockIdx.x, t = threadIdx.x;
  __shared__ float r1[256], r2[256];
  float a = 0.f, b = 0.f;
  for (int j = t; j < NBLK_CONV; j += 256) {
    a += psum[(size_t)c * NBLK_CONV + j];
    b += psq[(size_t)c * NBLK_CONV + j];
  }
  r1[t] = a; r2[t] = b; __syncthreads();
  for (int w = 128; w; w >>= 1) { if (t < w) { r1[t] += r1[t + w]; r2[t] += r2[t + w]; } __syncthreads(); }
  if (t == 0) {
    float m = r1[0] * (1.0f / N_NODES);
    float v = r2[0] * (1.0f / N_NODES) - m * m;
    float rs = rsqrtf(fmaxf(v, 0.f) + BN_EPS) * gamma[c];
    scale[c] = rs;
    shift[c] = beta[c] - m * rs;
  }
}

// ---------------------------------------------------------------- xb = bf16((x*scale + shift) * rsqrt(outdeg))
__launch_bounds__(256)
__global__ void k_bnx(const float* __restrict__ x, const float* __restrict__ scale,
                      const float* __restrict__ shift, const int* __restrict__ cntO,
                      unsigned short* __restrict__ xb) {
  int idx = blockIdx.x * 256 + threadIdx.x;
  int row = idx >> 5, c4 = (idx & 31) * 4;
  float4 v  = *(const float4*)&x[(size_t)row * DIM + c4];
  float4 sc = *(const float4*)&scale[c4];
  float4 sh = *(const float4*)&shift[c4];
  float f = rsqrtf(fmaxf((float)cntO[row], 1.0f));
  ushort4 o;
  o.x = f2bf((v.x * sc.x + sh.x) * f);
  o.y = f2bf((v.y * sc.y + sh.y) * f);
  o.z = f2bf((v.z * sc.z + sh.z) * f);
  o.w = f2bf((v.w * sc.w + sh.w) * f);
  *(ushort4*)&xb[(size_t)row * DIM + c4] = o;
}

// ---------------------------------------------------------------- W -> bf16 transposed
__global__ void k_prepW(const float* __restrict__ W1, const float* __restrict__ W2,
                        unsigned short* __restrict__ WbT1, unsigned short* __restrict__ WbT2) {
  int idx = blockIdx.x * 256 + threadIdx.x;
  int which = idx >> 14;
  int i = idx & 16383;
  int k = i >> 7, c = i & 127;
  const float* W = which ? W2 : W1;
  unsigned short* O = which ? WbT2 : WbT1;
  O[c * DIM + k] = f2bf(W[k * DIM + c]);
}

// ---------------------------------------------------------------- pull-mode SpMM -> bf16 agg
__launch_bounds__(256, 8)
__global__ void k_spmm_pull(const unsigned short* __restrict__ xb, const int* __restrict__ csr,
                            const int* __restrict__ rowstart, unsigned short* __restrict__ aggb) {
  int row = blockIdx.x * 4 + threadIdx.y;
  int l = threadIdx.x;
  int half = l >> 5, l32 = l & 31;
  int s = rowstart[row], e = rowstart[row + 1];
  float4 acc = {0.f, 0.f, 0.f, 0.f};
  const size_t coff = (size_t)l32 * 4;
  int i = s + half;
  for (; i + 6 < e; i += 8) {
    int s0 = csr[i], s1 = csr[i + 2], s2 = csr[i + 4], s3 = csr[i + 6];
    uint2 w0 = *(const uint2*)&xb[(size_t)s0 * DIM + coff];
    uint2 w1 = *(const uint2*)&xb[(size_t)s1 * DIM + coff];
    uint2 w2 = *(const uint2*)&xb[(size_t)s2 * DIM + coff];
    uint2 w3 = *(const uint2*)&xb[(size_t)s3 * DIM + coff];
    acc.x += __uint_as_float(w0.x << 16) + __uint_as_float(w1.x << 16)
           + __uint_as_float(w2.x << 16) + __uint_as_float(w3.x << 16);
    acc.y += __uint_as_float(w0.x & 0xFFFF0000u) + __uint_as_float(w1.x & 0xFFFF0000u)
           + __uint_as_float(w2.x & 0xFFFF0000u) + __uint_as_float(w3.x & 0xFFFF0000u);
    acc.z += __uint_as_float(w0.y << 16) + __uint_as_float(w1.y << 16)
           + __uint_as_float(w2.y << 16) + __uint_as_float(w3.y << 16);
    acc.w += __uint_as_float(w0.y & 0xFFFF0000u) + __uint_as_float(w1.y & 0xFFFF0000u)
           + __uint_as_float(w2.y & 0xFFFF0000u) + __uint_as_float(w3.y & 0xFFFF0000u);
  }
  for (; i < e; i += 2) {
    int s0 = csr[i];
    uint2 w0 = *(const uint2*)&xb[(size_t)s0 * DIM + coff];
    acc.x += __uint_as_float(w0.x << 16);
    acc.y += __uint_as_float(w0.x & 0xFFFF0000u);
    acc.z += __uint_as_float(w0.y << 16);
    acc.w += __uint_as_float(w0.y & 0xFFFF0000u);
  }
  acc.x += __shfl_xor(acc.x, 32);
  acc.y += __shfl_xor(acc.y, 32);
  acc.z += __shfl_xor(acc.z, 32);
  acc.w += __shfl_xor(acc.w, 32);
  if (half == 0) {
    float isi = rsqrtf(fmaxf((float)(e - s), 1.0f));
    ushort4 o;
    o.x = f2bf(acc.x * isi);
    o.y = f2bf(acc.y * isi);
    o.z = f2bf(acc.z * isi);
    o.w = f2bf(acc.w * isi);
    *(ushort4*)&aggb[(size_t)row * DIM + l32 * 4] = o;
  }
}

// ---------------------------------------------------------------- MFMA conv (+ optional gate, + optional column-stat partials)
__launch_bounds__(256)
__global__ void k_conv(const unsigned short* __restrict__ aggb,
                       const unsigned short* __restrict__ WbT,
                       const float* __restrict__ bias, const float* __restrict__ hres,
                       float* __restrict__ outp,
                       const float* __restrict__ gWp, const float* __restrict__ gbp,
                       float* __restrict__ gatep,
                       float* __restrict__ psum, float* __restrict__ psq) {
  __shared__ unsigned short As[64 * 136];    // 17408 B (re-used as stats scratch in epilogue)
  __shared__ unsigned short Ws[128 * 136];   // 34816 B (aliased as Of[64][132] f32 in epilogue)
  __shared__ float gsh[64];
  float* Of = (float*)Ws;
  int t = threadIdx.x;
  int row0 = blockIdx.x * 64;

  if (gatep && t < 64) gsh[t] = 0.f;

  for (int i = t; i < 1024; i += 256) {
    int r = i >> 4, q = i & 15;
    int row = row0 + r;
    int4 v = {0, 0, 0, 0};
    if (row < N_NODES) v = *(const int4*)&aggb[(size_t)row * DIM + q * 8];
    *(int4*)&As[r * 136 + q * 8] = v;
  }
  for (int i = t; i < 2048; i += 256) {
    int c = i >> 4, q = i & 15;
    *(int4*)&Ws[c * 136 + q * 8] = *(const int4*)&WbT[(size_t)c * DIM + q * 8];
  }
  __syncthreads();

  int wid = t >> 6, l = t & 63;
  int wr = wid >> 1, wc = wid & 1;
  int lr = l & 15, lq = l >> 4;
  f32x4 acc[2][4] = {};
  const unsigned short* Ab = &As[(wr * 32 + lr) * 136 + lq * 8];
  const unsigned short* Bb = &Ws[(wc * 64 + lr) * 136 + lq * 8];
#pragma unroll
  for (int kk = 0; kk < 4; ++kk) {
    bf16x8 a0 = *(const bf16x8*)(Ab + kk * 32);
    bf16x8 a1 = *(const bf16x8*)(Ab + 16 * 136 + kk * 32);
    bf16x8 b0 = *(const bf16x8*)(Bb + kk * 32);
    bf16x8 b1 = *(const bf16x8*)(Bb + 16 * 136 + kk * 32);
    bf16x8 b2 = *(const bf16x8*)(Bb + 32 * 136 + kk * 32);
    bf16x8 b3 = *(const bf16x8*)(Bb + 48 * 136 + kk * 32);
    acc[0][0] = __builtin_amdgcn_mfma_f32_16x16x32_bf16(a0, b0, acc[0][0], 0, 0, 0);
    acc[0][1] = __builtin_amdgcn_mfma_f32_16x16x32_bf16(a0, b1, acc[0][1], 0, 0, 0);
    acc[0][2] = __builtin_amdgcn_mfma_f32_16x16x32_bf16(a0, b2, acc[0][2], 0, 0, 0);
    acc[0][3] = __builtin_amdgcn_mfma_f32_16x16x32_bf16(a0, b3, acc[0][3], 0, 0, 0);
    acc[1][0] = __builtin_amdgcn_mfma_f32_16x16x32_bf16(a1, b0, acc[1][0], 0, 0, 0);
    acc[1][1] = __builtin_amdgcn_mfma_f32_16x16x32_bf16(a1, b1, acc[1][1], 0, 0, 0);
    acc[1][2] = __builtin_amdgcn_mfma_f32_16x16x32_bf16(a1, b2, acc[1][2], 0, 0, 0);
    acc[1][3] = __builtin_amdgcn_mfma_f32_16x16x32_bf16(a1, b3, acc[1][3], 0, 0, 0);
  }
  __syncthreads();

#pragma unroll
  for (int rt = 0; rt < 2; ++rt) {
#pragma unroll
    for (int ct = 0; ct < 4; ++ct) {
      int rr = wr * 32 + rt * 16 + lq * 4;
      int cc = wc * 64 + ct * 16 + lr;
#pragma unroll
      for (int i = 0; i < 4; ++i)
        Of[(rr + i) * 132 + cc] = acc[rt][ct][i];
    }
  }
  __syncthreads();

  float st[4] = {0.f, 0.f, 0.f, 0.f}, st2[4] = {0.f, 0.f, 0.f, 0.f};
#pragma unroll
  for (int i = 0; i < 8; ++i) {
    int fi = t + i * 256;
    int r = fi >> 5, c4 = (fi & 31) * 4;
    int row = row0 + r;
    if (row < N_NODES) {
      float4 o  = *(float4*)&Of[r * 132 + c4];
      float4 bv = *(const float4*)&bias[c4];
      float4 hv = *(const float4*)&hres[(size_t)row * DIM + c4];
      float4 y = {hv.x + fmaxf(o.x + bv.x, 0.f), hv.y + fmaxf(o.y + bv.y, 0.f),
                  hv.z + fmaxf(o.z + bv.z, 0.f), hv.w + fmaxf(o.w + bv.w, 0.f)};
      *(float4*)&outp[(size_t)row * DIM + c4] = y;
      if (gatep) {
        float4 gw = *(const float4*)&gWp[c4];
        atomicAdd(&gsh[r], y.x * gw.x + y.y * gw.y + y.z * gw.z + y.w * gw.w);
      }
      if (psum) {
        st[0] += y.x; st[1] += y.y; st[2] += y.z; st[3] += y.w;
        st2[0] += y.x*y.x; st2[1] += y.y*y.y; st2[2] += y.z*y.z; st2[3] += y.w*y.w;
      }
    }
  }
  if (gatep) {
    __syncthreads();
    int row = row0 + t;
    if (t < 64 && row < N_NODES) gatep[row] = gsh[t] + gbp[0];
  }
  if (psum) {   // column partials via As scratch (dead after MFMA)
    float* sls  = (float*)As;        // [8][128]
    float* sls2 = sls + 8 * DIM;     // [8][128]  (8 KB total < 17408 B)
    int rg = t >> 5, c4 = (t & 31) * 4;
    __syncthreads();
#pragma unroll
    for (int i = 0; i < 4; ++i) {
      sls[rg * DIM + c4 + i]  = st[i];
      sls2[rg * DIM + c4 + i] = st2[i];
    }
    __syncthreads();
    if (t < DIM) {
      float a = 0.f, b = 0.f;
#pragma unroll
      for (int j = 0; j < 8; ++j) { a += sls[j * DIM + t]; b += sls2[j * DIM + t]; }
      psum[(size_t)t * NBLK_CONV + blockIdx.x] = a;
      psq[(size_t)t * NBLK_CONV + blockIdx.x]  = b;
    }
  }
}

// ---------------------------------------------------------------- per-graph softmax stats
__global__ void k_gstats(const float* __restrict__ gate, const int* __restrict__ starts,
                         float* __restrict__ gmax, float* __restrict__ gden) {
  int g = blockIdx.x;
  int s = starts[g], e = starts[g + 1];
  int t = threadIdx.x;
  __shared__ float red[256];
  float m = -INFINITY;
  for (int i = s + t; i < e; i += 256) m = fmaxf(m, gate[i]);
  red[t] = m; __syncthreads();
  for (int w = 128; w; w >>= 1) { if (t < w) red[t] = fmaxf(red[t], red[t + w]); __syncthreads(); }
  float mg = red[0]; __syncthreads();
  float ssum = 0.f;
  for (int i = s + t; i < e; i += 256) ssum += expf(gate[i] - mg);
  red[t] = ssum; __syncthreads();
  for (int w = 128; w; w >>= 1) { if (t < w) red[t] += red[t + w]; __syncthreads(); }
  if (t == 0) { gmax[g] = mg; gden[g] = red[0]; }
}

// ---------------------------------------------------------------- weighted pooling
__global__ void k_pool(const float* __restrict__ h2, const float* __restrict__ gate,
                       const int* __restrict__ starts, const float* __restrict__ gmax,
                       const float* __restrict__ gden, float* __restrict__ outp) {
  int g = blockIdx.x >> 3, part = blockIdx.x & 7;
  int s = starts[g], e = starts[g + 1];
  int d = threadIdx.x;
  float mg = gmax[g];
  float dn = gden[g];
  float invden = dn > 0.f ? 1.0f / dn : 0.f;
  float acc = 0.f;
  for (int i = s + part; i < e; i += 8) {
    float w = expf(gate[i] - mg) * invden;
    acc += w * h2[(size_t)i * DIM + d];
  }
  atomicAdd(&outp[g * DIM + d], acc);
}

// ---------------------------------------------------------------- launch
extern "C" void kernel_launch(void* const* d_in, const int* in_sizes, int n_in,
                              void* d_out, int out_size, void* d_ws, size_t ws_size,
                              hipStream_t stream) {
  const float* h    = (const float*)d_in[0];
  const int*   src  = (const int*)d_in[1];
  const int*   dst  = (const int*)d_in[2];
  const int*   gid  = (const int*)d_in[3];
  const float* W1   = (const float*)d_in[5];
  const float* b1   = (const float*)d_in[6];
  const float* W2   = (const float*)d_in[7];
  const float* b2   = (const float*)d_in[8];
  const float* gW   = (const float*)d_in[9];
  const float* gb   = (const float*)d_in[10];
  const float* gamma= (const float*)d_in[11];
  const float* beta = (const float*)d_in[12];
  float* out = (float*)d_out;

  char* ws = (char*)d_ws;
  float* h12     = (float*)ws; ws += (size_t)N_NODES * DIM * 4;
  unsigned short* xb   = (unsigned short*)ws; ws += (size_t)N_NODES * DIM * 2;
  unsigned short* aggb = (unsigned short*)ws; ws += (size_t)N_NODES * DIM * 2;
  int*   csr     = (int*)ws;   ws += (size_t)N_EDGES * 4;
  int*   cnt_slice = (int*)ws; ws += (size_t)NSLICE * N_NODES * 4;
  float* psum    = (float*)ws; ws += (size_t)DIM * NBLK_CONV * 4;
  float* psq     = (float*)ws; ws += (size_t)DIM * NBLK_CONV * 4;
  unsigned short* WbT1 = (unsigned short*)ws; ws += DIM * DIM * 2;
  unsigned short* WbT2 = (unsigned short*)ws; ws += DIM * DIM * 2;
  int*   rowstart= (int*)ws;   ws += (N_NODES + 1) * 4;
  int*   cnt     = (int*)ws;   ws += N_NODES * 4;
  int*   cntO    = (int*)ws;   ws += N_NODES * 4;
  float* gate    = (float*)ws; ws += N_NODES * 4;
  float* sums    = (float*)ws; ws += 2 * DIM * 4;
  float* scale   = (float*)ws; ws += DIM * 4;
  float* shift   = (float*)ws; ws += DIM * 4;
  float* gmax    = (float*)ws; ws += NG * 4;
  float* gden    = (float*)ws; ws += NG * 4;
  int*   starts  = (int*)ws;   ws += (NG + 1) * 4;
  int*   bsum    = (int*)ws;   ws += NB * 4;
  int*   boff    = (int*)ws;   ws += NB * 4;

  hipMemsetAsync(cntO,  0, N_NODES * 4, stream);
  hipMemsetAsync(sums,  0, 2 * DIM * 4, stream);
  hipMemsetAsync(d_out, 0, (size_t)out_size * 4, stream);

  // graph structure
  k_histO<<<64, 1024, 0, stream>>>(src, cntO);
  k_histD<<<8 * NSLICE, 1024, 0, stream>>>(dst, cnt_slice);
  k_scan_part<<<NB, 256, 0, stream>>>(cnt_slice, cnt, bsum);
  k_scan_mid<<<1, 128, 0, stream>>>(bsum, boff, rowstart);
  k_scan_fin<<<NB, 256, 0, stream>>>(cnt, boff, rowstart);
  k_sliceoff<<<(N_NODES + 255) / 256, 256, 0, stream>>>(cnt_slice);
  k_scatter_slice<<<8 * NSLICE, 1024, 0, stream>>>(src, dst, rowstart, cnt_slice, csr);
  k_starts_init<<<1, NG + 1, 0, stream>>>(starts);
  k_starts_fill<<<(N_NODES + 255) / 256, 256, 0, stream>>>(gid, starts);
  k_prepW<<<128, 256, 0, stream>>>(W1, W2, WbT1, WbT2);

  // layer 1 (stats fused with init_avg accumulation)
  k_stats1<<<NB, 256, 0, stream>>>(h, gid, sums, out + NG * DIM);
  k_avg_div<<<NG, DIM, 0, stream>>>(starts, out + NG * DIM);
  k_bnfin<<<1, DIM, 0, stream>>>(sums, gamma, beta, scale, shift);
  k_bnx<<<N_NODES * 32 / 256, 256, 0, stream>>>(h, scale, shift, cntO, xb);
  k_spmm_pull<<<N_NODES / 4, dim3(64, 4), 0, stream>>>(xb, csr, rowstart, aggb);
  k_conv<<<NBLK_CONV, 256, 0, stream>>>(aggb, WbT1, b1, h, h12,
                                        nullptr, nullptr, nullptr, psum, psq);

  // layer 2 (stats from conv1 partials)
  k_colred<<<DIM, 256, 0, stream>>>(psum, psq, gamma, beta, scale, shift);
  k_bnx<<<N_NODES * 32 / 256, 256, 0, stream>>>(h12, scale, shift, cntO, xb);
  k_spmm_pull<<<N_NODES / 4, dim3(64, 4), 0, stream>>>(xb, csr, rowstart, aggb);
  k_conv<<<NBLK_CONV, 256, 0, stream>>>(aggb, WbT2, b2, h12, h12,
                                        gW, gb, gate, nullptr, nullptr);

  // pooling
  k_gstats<<<NG, 256, 0, stream>>>(gate, starts, gmax, gden);
  k_pool<<<NG * 8, DIM, 0, stream>>>(h12, gate, starts, gmax, gden, out);
}

// Round 11
// 432.346 us; speedup vs baseline: 17.1558x; 1.0193x over previous
//
#include <hip/hip_runtime.h>
#include <math.h>

#define N_NODES 100000
#define N_EDGES 1600000
#define DIM     128
#define NG      64
#define BN_EPS  1e-5f
#define NB      98       // scan blocks (1024 nodes each)
#define HRANGE  12500    // nodes per LDS range (50 KB)
#define NSLICE  16       // edge slices
#define ESLICE  (N_EDGES / NSLICE)   // 100000
#define NBLK_CONV 1563   // ceil(N_NODES/64)
#define SB      128      // rows per stats block
#define NSB     782      // ceil(N_NODES/SB)

typedef __attribute__((ext_vector_type(8))) short bf16x8;
typedef __attribute__((ext_vector_type(4))) float f32x4;

__device__ __forceinline__ unsigned short f2bf(float f) {
  unsigned b = __float_as_uint(f);
  unsigned r = (b + 0x7FFFu + ((b >> 16) & 1u)) >> 16;   // RNE
  return (unsigned short)r;
}

// ---------------------------------------------------------------- out-degree histogram (src)
__launch_bounds__(1024)
__global__ void k_histO(const int* __restrict__ src, int* __restrict__ cntO) {
  __shared__ int histo[HRANGE];
  int t = threadIdx.x;
  int range = blockIdx.x >> 3, blk = blockIdx.x & 7;
  int lo = range * HRANGE;
  for (int j = t; j < HRANGE; j += 1024) histo[j] = 0;
  __syncthreads();
  const int SLICE = N_EDGES / 8;
  const int4* sp = (const int4*)(src + blk * SLICE);
  const int n4 = SLICE / 4;
  for (int q = t; q < n4; q += 1024) {
    int4 v = sp[q];
    unsigned a = (unsigned)(v.x - lo), b = (unsigned)(v.y - lo);
    unsigned c = (unsigned)(v.z - lo), d = (unsigned)(v.w - lo);
    if (a < (unsigned)HRANGE) atomicAdd(&histo[a], 1);
    if (b < (unsigned)HRANGE) atomicAdd(&histo[b], 1);
    if (c < (unsigned)HRANGE) atomicAdd(&histo[c], 1);
    if (d < (unsigned)HRANGE) atomicAdd(&histo[d], 1);
  }
  __syncthreads();
  for (int j = t; j < HRANGE; j += 1024) {
    int v = histo[j];
    if (v) atomicAdd(&cntO[lo + j], v);
  }
}

// ---------------------------------------------------------------- in-degree per-slice histogram (dst)
__launch_bounds__(1024)
__global__ void k_histD(const int* __restrict__ dst, int* __restrict__ cnt_slice) {
  __shared__ int histo[HRANGE];
  int t = threadIdx.x;
  int range = blockIdx.x >> 4, slice = blockIdx.x & 15;
  int lo = range * HRANGE;
  for (int j = t; j < HRANGE; j += 1024) histo[j] = 0;
  __syncthreads();
  const int4* dp = (const int4*)(dst + slice * ESLICE);
  for (int q = t; q < ESLICE / 4; q += 1024) {
    int4 v = dp[q];
    unsigned a = (unsigned)(v.x - lo), b = (unsigned)(v.y - lo);
    unsigned c = (unsigned)(v.z - lo), d = (unsigned)(v.w - lo);
    if (a < (unsigned)HRANGE) atomicAdd(&histo[a], 1);
    if (b < (unsigned)HRANGE) atomicAdd(&histo[b], 1);
    if (c < (unsigned)HRANGE) atomicAdd(&histo[c], 1);
    if (d < (unsigned)HRANGE) atomicAdd(&histo[d], 1);
  }
  __syncthreads();
  for (int j = t; j < HRANGE; j += 1024)
    cnt_slice[(size_t)slice * N_NODES + lo + j] = histo[j];
}

// ---------------------------------------------------------------- scan pass 1
__global__ void k_scan_part(const int* __restrict__ cnt_slice, int* __restrict__ cnt,
                            int* __restrict__ bsum) {
  int b = blockIdx.x, t = threadIdx.x;
  int base = b * 1024 + t * 4;
  int tot = 0;
#pragma unroll
  for (int j = 0; j < 4; ++j) {
    int i = base + j;
    if (i < N_NODES) {
      int c = 0;
#pragma unroll
      for (int s = 0; s < NSLICE; ++s) c += cnt_slice[(size_t)s * N_NODES + i];
      cnt[i] = c;
      tot += c;
    }
  }
  __shared__ int red[256];
  red[t] = tot; __syncthreads();
  for (int w = 128; w; w >>= 1) { if (t < w) red[t] += red[t + w]; __syncthreads(); }
  if (t == 0) bsum[b] = red[0];
}

__global__ void k_scan_mid(const int* __restrict__ bsum, int* __restrict__ boff,
                           int* __restrict__ rowstart) {
  int t = threadIdx.x;
  __shared__ int sh[128];
  int own = (t < NB) ? bsum[t] : 0;
  sh[t] = own;
  __syncthreads();
  for (int off = 1; off < 128; off <<= 1) {
    int v = (t >= off) ? sh[t - off] : 0;
    __syncthreads();
    sh[t] += v;
    __syncthreads();
  }
  if (t < NB) boff[t] = sh[t] - own;
  if (t == NB - 1) rowstart[N_NODES] = sh[t];
}

__global__ void k_scan_fin(const int* __restrict__ cnt, const int* __restrict__ boff,
                           int* __restrict__ rowstart) {
  int b = blockIdx.x, t = threadIdx.x;
  int base = b * 1024 + t * 4;
  int v0 = 0, v1 = 0, v2 = 0, v3 = 0;
  if (base + 0 < N_NODES) v0 = cnt[base + 0];
  if (base + 1 < N_NODES) v1 = cnt[base + 1];
  if (base + 2 < N_NODES) v2 = cnt[base + 2];
  if (base + 3 < N_NODES) v3 = cnt[base + 3];
  int tsum = v0 + v1 + v2 + v3;
  __shared__ int sh[256];
  sh[t] = tsum;
  __syncthreads();
  for (int off = 1; off < 256; off <<= 1) {
    int v = (t >= off) ? sh[t - off] : 0;
    __syncthreads();
    sh[t] += v;
    __syncthreads();
  }
  int run = boff[b] + sh[t] - tsum;
  if (base + 0 < N_NODES) rowstart[base + 0] = run; run += v0;
  if (base + 1 < N_NODES) rowstart[base + 1] = run; run += v1;
  if (base + 2 < N_NODES) rowstart[base + 2] = run; run += v2;
  if (base + 3 < N_NODES) rowstart[base + 3] = run;
}

// ---------------------------------------------------------------- exclusive prefix over slices per node
__global__ void k_sliceoff(int* __restrict__ cnt_slice) {
  int i = blockIdx.x * 256 + threadIdx.x;
  if (i < N_NODES) {
    int run = 0;
#pragma unroll
    for (int s = 0; s < NSLICE; ++s) {
      int v = cnt_slice[(size_t)s * N_NODES + i];
      cnt_slice[(size_t)s * N_NODES + i] = run;
      run += v;
    }
  }
}

// ---------------------------------------------------------------- scatter via LDS cursor
__launch_bounds__(1024)
__global__ void k_scatter_slice(const int* __restrict__ src, const int* __restrict__ dst,
                                const int* __restrict__ rowstart,
                                const int* __restrict__ cnt_slice, int* __restrict__ csr) {
  __shared__ int cur[HRANGE];
  int t = threadIdx.x;
  int range = blockIdx.x >> 4, slice = blockIdx.x & 15;
  int lo = range * HRANGE;
  for (int j = t; j < HRANGE; j += 1024)
    cur[j] = rowstart[lo + j] + cnt_slice[(size_t)slice * N_NODES + lo + j];
  __syncthreads();
  const int4* dp = (const int4*)(dst + slice * ESLICE);
  const int4* sp = (const int4*)(src + slice * ESLICE);
  for (int q = t; q < ESLICE / 4; q += 1024) {
    int4 d = dp[q];
    int4 s = sp[q];
    unsigned o;
    o = (unsigned)(d.x - lo); if (o < (unsigned)HRANGE) { int p = atomicAdd(&cur[o], 1); csr[p] = s.x; }
    o = (unsigned)(d.y - lo); if (o < (unsigned)HRANGE) { int p = atomicAdd(&cur[o], 1); csr[p] = s.y; }
    o = (unsigned)(d.z - lo); if (o < (unsigned)HRANGE) { int p = atomicAdd(&cur[o], 1); csr[p] = s.z; }
    o = (unsigned)(d.w - lo); if (o < (unsigned)HRANGE) { int p = atomicAdd(&cur[o], 1); csr[p] = s.w; }
  }
}

// ---------------------------------------------------------------- graph CSR starts (merged init+fill)
__global__ void k_starts_fill(const int* __restrict__ gid, int* __restrict__ starts) {
  int i = blockIdx.x * blockDim.x + threadIdx.x;
  if (i >= N_NODES) return;
  int gi = gid[i];
  if (i == 0) {
    for (int g = 0; g <= gi; ++g) starts[g] = 0;
  } else {
    int gp = gid[i - 1];
    if (gp != gi) for (int g = gp + 1; g <= gi; ++g) starts[g] = i;
  }
  if (i == N_NODES - 1) {
    for (int g = gi + 1; g <= NG; ++g) starts[g] = N_NODES;
  }
}

// ---------------------------------------------------------------- fused BN col stats + init_avg sums (128-row blocks)
__launch_bounds__(256)
__global__ void k_stats1(const float* __restrict__ x, const int* __restrict__ gid,
                         float* __restrict__ sums, float* __restrict__ initavg) {
  __shared__ float ls[8][DIM];
  __shared__ float ls2[8][DIM];
  __shared__ float lseg[4][8][DIM];   // 16 KB: graph slots relative to block's first graph
  int t = threadIdx.x;
  int col4 = (t & 31) * 4, rg = t >> 5;
  for (int i = t; i < 4 * 8 * DIM; i += 256) ((float*)lseg)[i] = 0.f;
  int base = blockIdx.x * SB;
  int rend = min(base + SB, N_NODES);
  int g0 = gid[base];
  int gl = gid[rend - 1];
  __syncthreads();
  float4 s = {0.f,0.f,0.f,0.f}, s2 = {0.f,0.f,0.f,0.f};
  float4 acc = {0.f,0.f,0.f,0.f};
  if (g0 == gl) {
    // fast path: whole block inside one graph — no per-row gid reads
    for (int r = base + rg; r < rend; r += 8) {
      float4 v = *(const float4*)&x[(size_t)r * DIM + col4];
      s.x += v.x; s.y += v.y; s.z += v.z; s.w += v.w;
      s2.x += v.x*v.x; s2.y += v.y*v.y; s2.z += v.z*v.z; s2.w += v.w*v.w;
      acc.x += v.x; acc.y += v.y; acc.z += v.z; acc.w += v.w;
    }
    lseg[0][rg][col4+0] = acc.x; lseg[0][rg][col4+1] = acc.y;
    lseg[0][rg][col4+2] = acc.z; lseg[0][rg][col4+3] = acc.w;
  } else {
    int curg = g0;
    for (int r = base + rg; r < rend; r += 8) {
      float4 v = *(const float4*)&x[(size_t)r * DIM + col4];
      s.x += v.x; s.y += v.y; s.z += v.z; s.w += v.w;
      s2.x += v.x*v.x; s2.y += v.y*v.y; s2.z += v.z*v.z; s2.w += v.w*v.w;
      int g = gid[r];
      if (g != curg) {
        int slot = curg - g0;
        if (slot < 4) {
          lseg[slot][rg][col4+0] = acc.x; lseg[slot][rg][col4+1] = acc.y;
          lseg[slot][rg][col4+2] = acc.z; lseg[slot][rg][col4+3] = acc.w;
        } else {
          atomicAdd(&initavg[curg * DIM + col4+0], acc.x);
          atomicAdd(&initavg[curg * DIM + col4+1], acc.y);
          atomicAdd(&initavg[curg * DIM + col4+2], acc.z);
          atomicAdd(&initavg[curg * DIM + col4+3], acc.w);
        }
        acc.x = acc.y = acc.z = acc.w = 0.f;
        curg = g;
      }
      acc.x += v.x; acc.y += v.y; acc.z += v.z; acc.w += v.w;
    }
    int slot = curg - g0;
    if (slot < 4) {
      lseg[slot][rg][col4+0] = acc.x; lseg[slot][rg][col4+1] = acc.y;
      lseg[slot][rg][col4+2] = acc.z; lseg[slot][rg][col4+3] = acc.w;
    } else {
      atomicAdd(&initavg[curg * DIM + col4+0], acc.x);
      atomicAdd(&initavg[curg * DIM + col4+1], acc.y);
      atomicAdd(&initavg[curg * DIM + col4+2], acc.z);
      atomicAdd(&initavg[curg * DIM + col4+3], acc.w);
    }
  }
  *(float4*)&ls[rg][col4] = s;
  *(float4*)&ls2[rg][col4] = s2;
  __syncthreads();
  if (t < DIM) {
    float a = 0.f, b = 0.f;
#pragma unroll
    for (int j = 0; j < 8; ++j) { a += ls[j][t]; b += ls2[j][t]; }
    atomicAdd(&sums[t], a);
    atomicAdd(&sums[DIM + t], b);
#pragma unroll
    for (int slot = 0; slot < 4; ++slot) {
      float v = 0.f;
#pragma unroll
      for (int j = 0; j < 8; ++j) v += lseg[slot][j][t];
      int g = g0 + slot;
      if (g < NG && v != 0.f) atomicAdd(&initavg[g * DIM + t], v);
    }
  }
}

__global__ void k_avg_div(const int* __restrict__ starts, float* __restrict__ outp) {
  int g = blockIdx.x, d = threadIdx.x;
  float cnt = fmaxf((float)(starts[g + 1] - starts[g]), 1.0f);
  outp[g * DIM + d] /= cnt;
}

// ---------------------------------------------------------------- layer-2 col sums from conv1 partials -> sums[]
__global__ void k_colred(const float* __restrict__ psum, const float* __restrict__ psq,
                         float* __restrict__ sums) {
  int c = blockIdx.x, t = threadIdx.x;
  __shared__ float r1[256], r2[256];
  float a = 0.f, b = 0.f;
  for (int j = t; j < NBLK_CONV; j += 256) {
    a += psum[(size_t)c * NBLK_CONV + j];
    b += psq[(size_t)c * NBLK_CONV + j];
  }
  r1[t] = a; r2[t] = b; __syncthreads();
  for (int w = 128; w; w >>= 1) { if (t < w) { r1[t] += r1[t + w]; r2[t] += r2[t + w]; } __syncthreads(); }
  if (t == 0) { sums[c] = r1[0]; sums[DIM + c] = r2[0]; }
}

// ---------------------------------------------------------------- xb = bf16(BN(x) * rsqrt(outdeg)); scale/shift from sums inline
__launch_bounds__(256)
__global__ void k_bnx(const float* __restrict__ x, const float* __restrict__ sums,
                      const float* __restrict__ gamma, const float* __restrict__ beta,
                      const int* __restrict__ cntO, unsigned short* __restrict__ xb) {
  int idx = blockIdx.x * 256 + threadIdx.x;
  int row = idx >> 5, c4 = (idx & 31) * 4;
  float4 sm = *(const float4*)&sums[c4];
  float4 sq = *(const float4*)&sums[DIM + c4];
  float4 ga = *(const float4*)&gamma[c4];
  float4 be = *(const float4*)&beta[c4];
  const float inv = 1.0f / N_NODES;
  float4 sc, sh;
  {
    float m = sm.x * inv, va = sq.x * inv - m * m;
    sc.x = rsqrtf(fmaxf(va, 0.f) + BN_EPS) * ga.x; sh.x = be.x - m * sc.x;
    m = sm.y * inv; va = sq.y * inv - m * m;
    sc.y = rsqrtf(fmaxf(va, 0.f) + BN_EPS) * ga.y; sh.y = be.y - m * sc.y;
    m = sm.z * inv; va = sq.z * inv - m * m;
    sc.z = rsqrtf(fmaxf(va, 0.f) + BN_EPS) * ga.z; sh.z = be.z - m * sc.z;
    m = sm.w * inv; va = sq.w * inv - m * m;
    sc.w = rsqrtf(fmaxf(va, 0.f) + BN_EPS) * ga.w; sh.w = be.w - m * sc.w;
  }
  float4 v = *(const float4*)&x[(size_t)row * DIM + c4];
  float f = rsqrtf(fmaxf((float)cntO[row], 1.0f));
  ushort4 o;
  o.x = f2bf((v.x * sc.x + sh.x) * f);
  o.y = f2bf((v.y * sc.y + sh.y) * f);
  o.z = f2bf((v.z * sc.z + sh.z) * f);
  o.w = f2bf((v.w * sc.w + sh.w) * f);
  *(ushort4*)&xb[(size_t)row * DIM + c4] = o;
}

// ---------------------------------------------------------------- W -> bf16 transposed
__global__ void k_prepW(const float* __restrict__ W1, const float* __restrict__ W2,
                        unsigned short* __restrict__ WbT1, unsigned short* __restrict__ WbT2) {
  int idx = blockIdx.x * 256 + threadIdx.x;
  int which = idx >> 14;
  int i = idx & 16383;
  int k = i >> 7, c = i & 127;
  const float* W = which ? W2 : W1;
  unsigned short* O = which ? WbT2 : WbT1;
  O[c * DIM + k] = f2bf(W[k * DIM + c]);
}

// ---------------------------------------------------------------- pull-mode SpMM -> bf16 agg
__launch_bounds__(256, 8)
__global__ void k_spmm_pull(const unsigned short* __restrict__ xb, const int* __restrict__ csr,
                            const int* __restrict__ rowstart, unsigned short* __restrict__ aggb) {
  int row = blockIdx.x * 4 + threadIdx.y;
  int l = threadIdx.x;
  int half = l >> 5, l32 = l & 31;
  int s = rowstart[row], e = rowstart[row + 1];
  float4 acc = {0.f, 0.f, 0.f, 0.f};
  const size_t coff = (size_t)l32 * 4;
  int i = s + half;
  for (; i + 6 < e; i += 8) {
    int s0 = csr[i], s1 = csr[i + 2], s2 = csr[i + 4], s3 = csr[i + 6];
    uint2 w0 = *(const uint2*)&xb[(size_t)s0 * DIM + coff];
    uint2 w1 = *(const uint2*)&xb[(size_t)s1 * DIM + coff];
    uint2 w2 = *(const uint2*)&xb[(size_t)s2 * DIM + coff];
    uint2 w3 = *(const uint2*)&xb[(size_t)s3 * DIM + coff];
    acc.x += __uint_as_float(w0.x << 16) + __uint_as_float(w1.x << 16)
           + __uint_as_float(w2.x << 16) + __uint_as_float(w3.x << 16);
    acc.y += __uint_as_float(w0.x & 0xFFFF0000u) + __uint_as_float(w1.x & 0xFFFF0000u)
           + __uint_as_float(w2.x & 0xFFFF0000u) + __uint_as_float(w3.x & 0xFFFF0000u);
    acc.z += __uint_as_float(w0.y << 16) + __uint_as_float(w1.y << 16)
           + __uint_as_float(w2.y << 16) + __uint_as_float(w3.y << 16);
    acc.w += __uint_as_float(w0.y & 0xFFFF0000u) + __uint_as_float(w1.y & 0xFFFF0000u)
           + __uint_as_float(w2.y & 0xFFFF0000u) + __uint_as_float(w3.y & 0xFFFF0000u);
  }
  for (; i < e; i += 2) {
    int s0 = csr[i];
    uint2 w0 = *(const uint2*)&xb[(size_t)s0 * DIM + coff];
    acc.x += __uint_as_float(w0.x << 16);
    acc.y += __uint_as_float(w0.x & 0xFFFF0000u);
    acc.z += __uint_as_float(w0.y << 16);
    acc.w += __uint_as_float(w0.y & 0xFFFF0000u);
  }
  acc.x += __shfl_xor(acc.x, 32);
  acc.y += __shfl_xor(acc.y, 32);
  acc.z += __shfl_xor(acc.z, 32);
  acc.w += __shfl_xor(acc.w, 32);
  if (half == 0) {
    float isi = rsqrtf(fmaxf((float)(e - s), 1.0f));
    ushort4 o;
    o.x = f2bf(acc.x * isi);
    o.y = f2bf(acc.y * isi);
    o.z = f2bf(acc.z * isi);
    o.w = f2bf(acc.w * isi);
    *(ushort4*)&aggb[(size_t)row * DIM + l32 * 4] = o;
  }
}

// ---------------------------------------------------------------- MFMA conv (+ optional gate, + optional column-stat partials)
__launch_bounds__(256)
__global__ void k_conv(const unsigned short* __restrict__ aggb,
                       const unsigned short* __restrict__ WbT,
                       const float* __restrict__ bias, const float* __restrict__ hres,
                       float* __restrict__ outp,
                       const float* __restrict__ gWp, const float* __restrict__ gbp,
                       float* __restrict__ gatep,
                       float* __restrict__ psum, float* __restrict__ psq) {
  __shared__ unsigned short As[64 * 136];    // 17408 B (stats scratch in epilogue)
  __shared__ unsigned short Ws[128 * 136];   // 34816 B (aliased as Of[64][132] f32)
  __shared__ float gsh[64];
  float* Of = (float*)Ws;
  int t = threadIdx.x;
  int row0 = blockIdx.x * 64;

  if (gatep && t < 64) gsh[t] = 0.f;

  for (int i = t; i < 1024; i += 256) {
    int r = i >> 4, q = i & 15;
    int row = row0 + r;
    int4 v = {0, 0, 0, 0};
    if (row < N_NODES) v = *(const int4*)&aggb[(size_t)row * DIM + q * 8];
    *(int4*)&As[r * 136 + q * 8] = v;
  }
  for (int i = t; i < 2048; i += 256) {
    int c = i >> 4, q = i & 15;
    *(int4*)&Ws[c * 136 + q * 8] = *(const int4*)&WbT[(size_t)c * DIM + q * 8];
  }
  __syncthreads();

  int wid = t >> 6, l = t & 63;
  int wr = wid >> 1, wc = wid & 1;
  int lr = l & 15, lq = l >> 4;
  f32x4 acc[2][4] = {};
  const unsigned short* Ab = &As[(wr * 32 + lr) * 136 + lq * 8];
  const unsigned short* Bb = &Ws[(wc * 64 + lr) * 136 + lq * 8];
#pragma unroll
  for (int kk = 0; kk < 4; ++kk) {
    bf16x8 a0 = *(const bf16x8*)(Ab + kk * 32);
    bf16x8 a1 = *(const bf16x8*)(Ab + 16 * 136 + kk * 32);
    bf16x8 b0 = *(const bf16x8*)(Bb + kk * 32);
    bf16x8 b1 = *(const bf16x8*)(Bb + 16 * 136 + kk * 32);
    bf16x8 b2 = *(const bf16x8*)(Bb + 32 * 136 + kk * 32);
    bf16x8 b3 = *(const bf16x8*)(Bb + 48 * 136 + kk * 32);
    acc[0][0] = __builtin_amdgcn_mfma_f32_16x16x32_bf16(a0, b0, acc[0][0], 0, 0, 0);
    acc[0][1] = __builtin_amdgcn_mfma_f32_16x16x32_bf16(a0, b1, acc[0][1], 0, 0, 0);
    acc[0][2] = __builtin_amdgcn_mfma_f32_16x16x32_bf16(a0, b2, acc[0][2], 0, 0, 0);
    acc[0][3] = __builtin_amdgcn_mfma_f32_16x16x32_bf16(a0, b3, acc[0][3], 0, 0, 0);
    acc[1][0] = __builtin_amdgcn_mfma_f32_16x16x32_bf16(a1, b0, acc[1][0], 0, 0, 0);
    acc[1][1] = __builtin_amdgcn_mfma_f32_16x16x32_bf16(a1, b1, acc[1][1], 0, 0, 0);
    acc[1][2] = __builtin_amdgcn_mfma_f32_16x16x32_bf16(a1, b2, acc[1][2], 0, 0, 0);
    acc[1][3] = __builtin_amdgcn_mfma_f32_16x16x32_bf16(a1, b3, acc[1][3], 0, 0, 0);
  }
  __syncthreads();

#pragma unroll
  for (int rt = 0; rt < 2; ++rt) {
#pragma unroll
    for (int ct = 0; ct < 4; ++ct) {
      int rr = wr * 32 + rt * 16 + lq * 4;
      int cc = wc * 64 + ct * 16 + lr;
#pragma unroll
      for (int i = 0; i < 4; ++i)
        Of[(rr + i) * 132 + cc] = acc[rt][ct][i];
    }
  }
  __syncthreads();

  float st[4] = {0.f, 0.f, 0.f, 0.f}, st2[4] = {0.f, 0.f, 0.f, 0.f};
#pragma unroll
  for (int i = 0; i < 8; ++i) {
    int fi = t + i * 256;
    int r = fi >> 5, c4 = (fi & 31) * 4;
    int row = row0 + r;
    if (row < N_NODES) {
      float4 o  = *(float4*)&Of[r * 132 + c4];
      float4 bv = *(const float4*)&bias[c4];
      float4 hv = *(const float4*)&hres[(size_t)row * DIM + c4];
      float4 y = {hv.x + fmaxf(o.x + bv.x, 0.f), hv.y + fmaxf(o.y + bv.y, 0.f),
                  hv.z + fmaxf(o.z + bv.z, 0.f), hv.w + fmaxf(o.w + bv.w, 0.f)};
      *(float4*)&outp[(size_t)row * DIM + c4] = y;
      if (gatep) {
        float4 gw = *(const float4*)&gWp[c4];
        atomicAdd(&gsh[r], y.x * gw.x + y.y * gw.y + y.z * gw.z + y.w * gw.w);
      }
      if (psum) {
        st[0] += y.x; st[1] += y.y; st[2] += y.z; st[3] += y.w;
        st2[0] += y.x*y.x; st2[1] += y.y*y.y; st2[2] += y.z*y.z; st2[3] += y.w*y.w;
      }
    }
  }
  if (gatep) {
    __syncthreads();
    int row = row0 + t;
    if (t < 64 && row < N_NODES) gatep[row] = gsh[t] + gbp[0];
  }
  if (psum) {
    float* sls  = (float*)As;
    float* sls2 = sls + 8 * DIM;
    int rg = t >> 5, c4 = (t & 31) * 4;
    __syncthreads();
#pragma unroll
    for (int i = 0; i < 4; ++i) {
      sls[rg * DIM + c4 + i]  = st[i];
      sls2[rg * DIM + c4 + i] = st2[i];
    }
    __syncthreads();
    if (t < DIM) {
      float a = 0.f, b = 0.f;
#pragma unroll
      for (int j = 0; j < 8; ++j) { a += sls[j * DIM + t]; b += sls2[j * DIM + t]; }
      psum[(size_t)t * NBLK_CONV + blockIdx.x] = a;
      psq[(size_t)t * NBLK_CONV + blockIdx.x]  = b;
    }
  }
}

// ---------------------------------------------------------------- per-graph softmax stats
__global__ void k_gstats(const float* __restrict__ gate, const int* __restrict__ starts,
                         float* __restrict__ gmax, float* __restrict__ gden) {
  int g = blockIdx.x;
  int s = starts[g], e = starts[g + 1];
  int t = threadIdx.x;
  __shared__ float red[256];
  float m = -INFINITY;
  for (int i = s + t; i < e; i += 256) m = fmaxf(m, gate[i]);
  red[t] = m; __syncthreads();
  for (int w = 128; w; w >>= 1) { if (t < w) red[t] = fmaxf(red[t], red[t + w]); __syncthreads(); }
  float mg = red[0]; __syncthreads();
  float ssum = 0.f;
  for (int i = s + t; i < e; i += 256) ssum += expf(gate[i] - mg);
  red[t] = ssum; __syncthreads();
  for (int w = 128; w; w >>= 1) { if (t < w) red[t] += red[t + w]; __syncthreads(); }
  if (t == 0) { gmax[g] = mg; gden[g] = red[0]; }
}

// ---------------------------------------------------------------- weighted pooling
__global__ void k_pool(const float* __restrict__ h2, const float* __restrict__ gate,
                       const int* __restrict__ starts, const float* __restrict__ gmax,
                       const float* __restrict__ gden, float* __restrict__ outp) {
  int g = blockIdx.x >> 3, part = blockIdx.x & 7;
  int s = starts[g], e = starts[g + 1];
  int d = threadIdx.x;
  float mg = gmax[g];
  float dn = gden[g];
  float invden = dn > 0.f ? 1.0f / dn : 0.f;
  float acc = 0.f;
  for (int i = s + part; i < e; i += 8) {
    float w = expf(gate[i] - mg) * invden;
    acc += w * h2[(size_t)i * DIM + d];
  }
  atomicAdd(&outp[g * DIM + d], acc);
}

// ---------------------------------------------------------------- launch
extern "C" void kernel_launch(void* const* d_in, const int* in_sizes, int n_in,
                              void* d_out, int out_size, void* d_ws, size_t ws_size,
                              hipStream_t stream) {
  const float* h    = (const float*)d_in[0];
  const int*   src  = (const int*)d_in[1];
  const int*   dst  = (const int*)d_in[2];
  const int*   gid  = (const int*)d_in[3];
  const float* W1   = (const float*)d_in[5];
  const float* b1   = (const float*)d_in[6];
  const float* W2   = (const float*)d_in[7];
  const float* b2   = (const float*)d_in[8];
  const float* gW   = (const float*)d_in[9];
  const float* gb   = (const float*)d_in[10];
  const float* gamma= (const float*)d_in[11];
  const float* beta = (const float*)d_in[12];
  float* out = (float*)d_out;

  char* ws = (char*)d_ws;
  float* h12     = (float*)ws; ws += (size_t)N_NODES * DIM * 4;
  unsigned short* xb   = (unsigned short*)ws; ws += (size_t)N_NODES * DIM * 2;
  unsigned short* aggb = (unsigned short*)ws; ws += (size_t)N_NODES * DIM * 2;
  int*   csr     = (int*)ws;   ws += (size_t)N_EDGES * 4;
  int*   cnt_slice = (int*)ws; ws += (size_t)NSLICE * N_NODES * 4;
  float* psum    = (float*)ws; ws += (size_t)DIM * NBLK_CONV * 4;
  float* psq     = (float*)ws; ws += (size_t)DIM * NBLK_CONV * 4;
  unsigned short* WbT1 = (unsigned short*)ws; ws += DIM * DIM * 2;
  unsigned short* WbT2 = (unsigned short*)ws; ws += DIM * DIM * 2;
  int*   rowstart= (int*)ws;   ws += (N_NODES + 1) * 4;
  int*   cnt     = (int*)ws;   ws += N_NODES * 4;
  int*   cntO    = (int*)ws;   ws += N_NODES * 4;
  float* gate    = (float*)ws; ws += N_NODES * 4;
  float* sums    = (float*)ws; ws += 2 * DIM * 4;
  float* gmax    = (float*)ws; ws += NG * 4;
  float* gden    = (float*)ws; ws += NG * 4;
  int*   starts  = (int*)ws;   ws += (NG + 1) * 4;
  int*   bsum    = (int*)ws;   ws += NB * 4;
  int*   boff    = (int*)ws;   ws += NB * 4;

  hipMemsetAsync(cntO,  0, N_NODES * 4, stream);
  hipMemsetAsync(sums,  0, 2 * DIM * 4, stream);
  hipMemsetAsync(d_out, 0, (size_t)out_size * 4, stream);

  // graph structure
  k_histO<<<64, 1024, 0, stream>>>(src, cntO);
  k_histD<<<8 * NSLICE, 1024, 0, stream>>>(dst, cnt_slice);
  k_scan_part<<<NB, 256, 0, stream>>>(cnt_slice, cnt, bsum);
  k_scan_mid<<<1, 128, 0, stream>>>(bsum, boff, rowstart);
  k_scan_fin<<<NB, 256, 0, stream>>>(cnt, boff, rowstart);
  k_sliceoff<<<(N_NODES + 255) / 256, 256, 0, stream>>>(cnt_slice);
  k_scatter_slice<<<8 * NSLICE, 1024, 0, stream>>>(src, dst, rowstart, cnt_slice, csr);
  k_starts_fill<<<(N_NODES + 255) / 256, 256, 0, stream>>>(gid, starts);
  k_prepW<<<128, 256, 0, stream>>>(W1, W2, WbT1, WbT2);

  // layer 1 (stats fused with init_avg accumulation)
  k_stats1<<<NSB, 256, 0, stream>>>(h, gid, sums, out + NG * DIM);
  k_avg_div<<<NG, DIM, 0, stream>>>(starts, out + NG * DIM);
  k_bnx<<<N_NODES * 32 / 256, 256, 0, stream>>>(h, sums, gamma, beta, cntO, xb);
  k_spmm_pull<<<N_NODES / 4, dim3(64, 4), 0, stream>>>(xb, csr, rowstart, aggb);
  k_conv<<<NBLK_CONV, 256, 0, stream>>>(aggb, WbT1, b1, h, h12,
                                        nullptr, nullptr, nullptr, psum, psq);

  // layer 2 (stats from conv1 partials)
  k_colred<<<DIM, 256, 0, stream>>>(psum, psq, sums);
  k_bnx<<<N_NODES * 32 / 256, 256, 0, stream>>>(h12, sums, gamma, beta, cntO, xb);
  k_spmm_pull<<<N_NODES / 4, dim3(64, 4), 0, stream>>>(xb, csr, rowstart, aggb);
  k_conv<<<NBLK_CONV, 256, 0, stream>>>(aggb, WbT2, b2, h12, h12,
                                        gW, gb, gate, nullptr, nullptr);

  // pooling
  k_gstats<<<NG, 256, 0, stream>>>(gate, starts, gmax, gden);
  k_pool<<<NG * 8, DIM, 0, stream>>>(h12, gate, starts, gmax, gden, out);
}

// Round 12
// 417.953 us; speedup vs baseline: 17.7466x; 1.0344x over previous
//
#include <hip/hip_runtime.h>
#include <math.h>

#define N_NODES 100000
#define N_EDGES 1600000
#define DIM     128
#define NG      64
#define BN_EPS  1e-5f
#define NB      98       // scan blocks (1024 nodes each)
#define HRANGE  12500    // nodes per LDS range (50 KB)
#define NSLICE  32       // edge slices
#define ESLICE  (N_EDGES / NSLICE)   // 50000
#define NBLK_CONV 1563   // ceil(N_NODES/64)
#define SB      128      // rows per stats block
#define NSB     782      // ceil(N_NODES/SB)

typedef __attribute__((ext_vector_type(8))) short bf16x8;
typedef __attribute__((ext_vector_type(4))) float f32x4;

__device__ __forceinline__ unsigned short f2bf(float f) {
  unsigned b = __float_as_uint(f);
  unsigned r = (b + 0x7FFFu + ((b >> 16) & 1u)) >> 16;   // RNE
  return (unsigned short)r;
}

// ---------------------------------------------------------------- out-degree histogram (src), 256 blocks
__launch_bounds__(1024)
__global__ void k_histO(const int* __restrict__ src, int* __restrict__ cntO) {
  __shared__ int histo[HRANGE];
  int t = threadIdx.x;
  int range = blockIdx.x >> 5, blk = blockIdx.x & 31;
  int lo = range * HRANGE;
  for (int j = t; j < HRANGE; j += 1024) histo[j] = 0;
  __syncthreads();
  const int4* sp = (const int4*)(src + blk * ESLICE);
  for (int q = t; q < ESLICE / 4; q += 1024) {
    int4 v = sp[q];
    unsigned a = (unsigned)(v.x - lo), b = (unsigned)(v.y - lo);
    unsigned c = (unsigned)(v.z - lo), d = (unsigned)(v.w - lo);
    if (a < (unsigned)HRANGE) atomicAdd(&histo[a], 1);
    if (b < (unsigned)HRANGE) atomicAdd(&histo[b], 1);
    if (c < (unsigned)HRANGE) atomicAdd(&histo[c], 1);
    if (d < (unsigned)HRANGE) atomicAdd(&histo[d], 1);
  }
  __syncthreads();
  for (int j = t; j < HRANGE; j += 1024) {
    int v = histo[j];
    if (v) atomicAdd(&cntO[lo + j], v);
  }
}

// ---------------------------------------------------------------- in-degree per-slice histogram (dst), 256 blocks
__launch_bounds__(1024)
__global__ void k_histD(const int* __restrict__ dst, int* __restrict__ cnt_slice) {
  __shared__ int histo[HRANGE];
  int t = threadIdx.x;
  int range = blockIdx.x >> 5, slice = blockIdx.x & 31;
  int lo = range * HRANGE;
  for (int j = t; j < HRANGE; j += 1024) histo[j] = 0;
  __syncthreads();
  const int4* dp = (const int4*)(dst + slice * ESLICE);
  for (int q = t; q < ESLICE / 4; q += 1024) {
    int4 v = dp[q];
    unsigned a = (unsigned)(v.x - lo), b = (unsigned)(v.y - lo);
    unsigned c = (unsigned)(v.z - lo), d = (unsigned)(v.w - lo);
    if (a < (unsigned)HRANGE) atomicAdd(&histo[a], 1);
    if (b < (unsigned)HRANGE) atomicAdd(&histo[b], 1);
    if (c < (unsigned)HRANGE) atomicAdd(&histo[c], 1);
    if (d < (unsigned)HRANGE) atomicAdd(&histo[d], 1);
  }
  __syncthreads();
  for (int j = t; j < HRANGE; j += 1024)
    cnt_slice[(size_t)slice * N_NODES + lo + j] = histo[j];
}

// ---------------------------------------------------------------- scan pass 1 (+ fused slice exclusive-prefix)
__global__ void k_scan_part(int* __restrict__ cnt_slice, int* __restrict__ cnt,
                            int* __restrict__ bsum) {
  int b = blockIdx.x, t = threadIdx.x;
  int base = b * 1024 + t * 4;
  int tot = 0;
#pragma unroll
  for (int j = 0; j < 4; ++j) {
    int i = base + j;
    if (i < N_NODES) {
      int run = 0;
#pragma unroll
      for (int s = 0; s < NSLICE; ++s) {
        int v = cnt_slice[(size_t)s * N_NODES + i];
        cnt_slice[(size_t)s * N_NODES + i] = run;   // exclusive prefix in place
        run += v;
      }
      cnt[i] = run;
      tot += run;
    }
  }
  __shared__ int red[256];
  red[t] = tot; __syncthreads();
  for (int w = 128; w; w >>= 1) { if (t < w) red[t] += red[t + w]; __syncthreads(); }
  if (t == 0) bsum[b] = red[0];
}

__global__ void k_scan_mid(const int* __restrict__ bsum, int* __restrict__ boff,
                           int* __restrict__ rowstart) {
  int t = threadIdx.x;
  __shared__ int sh[128];
  int own = (t < NB) ? bsum[t] : 0;
  sh[t] = own;
  __syncthreads();
  for (int off = 1; off < 128; off <<= 1) {
    int v = (t >= off) ? sh[t - off] : 0;
    __syncthreads();
    sh[t] += v;
    __syncthreads();
  }
  if (t < NB) boff[t] = sh[t] - own;
  if (t == NB - 1) rowstart[N_NODES] = sh[t];
}

__global__ void k_scan_fin(const int* __restrict__ cnt, const int* __restrict__ boff,
                           int* __restrict__ rowstart) {
  int b = blockIdx.x, t = threadIdx.x;
  int base = b * 1024 + t * 4;
  int v0 = 0, v1 = 0, v2 = 0, v3 = 0;
  if (base + 0 < N_NODES) v0 = cnt[base + 0];
  if (base + 1 < N_NODES) v1 = cnt[base + 1];
  if (base + 2 < N_NODES) v2 = cnt[base + 2];
  if (base + 3 < N_NODES) v3 = cnt[base + 3];
  int tsum = v0 + v1 + v2 + v3;
  __shared__ int sh[256];
  sh[t] = tsum;
  __syncthreads();
  for (int off = 1; off < 256; off <<= 1) {
    int v = (t >= off) ? sh[t - off] : 0;
    __syncthreads();
    sh[t] += v;
    __syncthreads();
  }
  int run = boff[b] + sh[t] - tsum;
  if (base + 0 < N_NODES) rowstart[base + 0] = run; run += v0;
  if (base + 1 < N_NODES) rowstart[base + 1] = run; run += v1;
  if (base + 2 < N_NODES) rowstart[base + 2] = run; run += v2;
  if (base + 3 < N_NODES) rowstart[base + 3] = run;
}

// ---------------------------------------------------------------- scatter via LDS cursor, 256 blocks
__launch_bounds__(1024)
__global__ void k_scatter_slice(const int* __restrict__ src, const int* __restrict__ dst,
                                const int* __restrict__ rowstart,
                                const int* __restrict__ cnt_slice, int* __restrict__ csr) {
  __shared__ int cur[HRANGE];
  int t = threadIdx.x;
  int range = blockIdx.x >> 5, slice = blockIdx.x & 31;
  int lo = range * HRANGE;
  for (int j = t; j < HRANGE; j += 1024)
    cur[j] = rowstart[lo + j] + cnt_slice[(size_t)slice * N_NODES + lo + j];
  __syncthreads();
  const int4* dp = (const int4*)(dst + slice * ESLICE);
  const int4* sp = (const int4*)(src + slice * ESLICE);
  for (int q = t; q < ESLICE / 4; q += 1024) {
    int4 d = dp[q];
    int4 s = sp[q];
    unsigned o;
    o = (unsigned)(d.x - lo); if (o < (unsigned)HRANGE) { int p = atomicAdd(&cur[o], 1); csr[p] = s.x; }
    o = (unsigned)(d.y - lo); if (o < (unsigned)HRANGE) { int p = atomicAdd(&cur[o], 1); csr[p] = s.y; }
    o = (unsigned)(d.z - lo); if (o < (unsigned)HRANGE) { int p = atomicAdd(&cur[o], 1); csr[p] = s.z; }
    o = (unsigned)(d.w - lo); if (o < (unsigned)HRANGE) { int p = atomicAdd(&cur[o], 1); csr[p] = s.w; }
  }
}

// ---------------------------------------------------------------- graph CSR starts
__global__ void k_starts_fill(const int* __restrict__ gid, int* __restrict__ starts) {
  int i = blockIdx.x * blockDim.x + threadIdx.x;
  if (i >= N_NODES) return;
  int gi = gid[i];
  if (i == 0) {
    for (int g = 0; g <= gi; ++g) starts[g] = 0;
  } else {
    int gp = gid[i - 1];
    if (gp != gi) for (int g = gp + 1; g <= gi; ++g) starts[g] = i;
  }
  if (i == N_NODES - 1) {
    for (int g = gi + 1; g <= NG; ++g) starts[g] = N_NODES;
  }
}

// ---------------------------------------------------------------- fused BN col stats + init_avg sums
__launch_bounds__(256)
__global__ void k_stats1(const float* __restrict__ x, const int* __restrict__ gid,
                         float* __restrict__ sums, float* __restrict__ initavg) {
  __shared__ float ls[8][DIM];
  __shared__ float ls2[8][DIM];
  __shared__ float lseg[4][8][DIM];
  int t = threadIdx.x;
  int col4 = (t & 31) * 4, rg = t >> 5;
  for (int i = t; i < 4 * 8 * DIM; i += 256) ((float*)lseg)[i] = 0.f;
  int base = blockIdx.x * SB;
  int rend = min(base + SB, N_NODES);
  int g0 = gid[base];
  int gl = gid[rend - 1];
  __syncthreads();
  float4 s = {0.f,0.f,0.f,0.f}, s2 = {0.f,0.f,0.f,0.f};
  float4 acc = {0.f,0.f,0.f,0.f};
  if (g0 == gl) {
    for (int r = base + rg; r < rend; r += 8) {
      float4 v = *(const float4*)&x[(size_t)r * DIM + col4];
      s.x += v.x; s.y += v.y; s.z += v.z; s.w += v.w;
      s2.x += v.x*v.x; s2.y += v.y*v.y; s2.z += v.z*v.z; s2.w += v.w*v.w;
      acc.x += v.x; acc.y += v.y; acc.z += v.z; acc.w += v.w;
    }
    lseg[0][rg][col4+0] = acc.x; lseg[0][rg][col4+1] = acc.y;
    lseg[0][rg][col4+2] = acc.z; lseg[0][rg][col4+3] = acc.w;
  } else {
    int curg = g0;
    for (int r = base + rg; r < rend; r += 8) {
      float4 v = *(const float4*)&x[(size_t)r * DIM + col4];
      s.x += v.x; s.y += v.y; s.z += v.z; s.w += v.w;
      s2.x += v.x*v.x; s2.y += v.y*v.y; s2.z += v.z*v.z; s2.w += v.w*v.w;
      int g = gid[r];
      if (g != curg) {
        int slot = curg - g0;
        if (slot < 4) {
          lseg[slot][rg][col4+0] = acc.x; lseg[slot][rg][col4+1] = acc.y;
          lseg[slot][rg][col4+2] = acc.z; lseg[slot][rg][col4+3] = acc.w;
        } else {
          atomicAdd(&initavg[curg * DIM + col4+0], acc.x);
          atomicAdd(&initavg[curg * DIM + col4+1], acc.y);
          atomicAdd(&initavg[curg * DIM + col4+2], acc.z);
          atomicAdd(&initavg[curg * DIM + col4+3], acc.w);
        }
        acc.x = acc.y = acc.z = acc.w = 0.f;
        curg = g;
      }
      acc.x += v.x; acc.y += v.y; acc.z += v.z; acc.w += v.w;
    }
    int slot = curg - g0;
    if (slot < 4) {
      lseg[slot][rg][col4+0] = acc.x; lseg[slot][rg][col4+1] = acc.y;
      lseg[slot][rg][col4+2] = acc.z; lseg[slot][rg][col4+3] = acc.w;
    } else {
      atomicAdd(&initavg[curg * DIM + col4+0], acc.x);
      atomicAdd(&initavg[curg * DIM + col4+1], acc.y);
      atomicAdd(&initavg[curg * DIM + col4+2], acc.z);
      atomicAdd(&initavg[curg * DIM + col4+3], acc.w);
    }
  }
  *(float4*)&ls[rg][col4] = s;
  *(float4*)&ls2[rg][col4] = s2;
  __syncthreads();
  if (t < DIM) {
    float a = 0.f, b = 0.f;
#pragma unroll
    for (int j = 0; j < 8; ++j) { a += ls[j][t]; b += ls2[j][t]; }
    atomicAdd(&sums[t], a);
    atomicAdd(&sums[DIM + t], b);
#pragma unroll
    for (int slot = 0; slot < 4; ++slot) {
      float v = 0.f;
#pragma unroll
      for (int j = 0; j < 8; ++j) v += lseg[slot][j][t];
      int g = g0 + slot;
      if (g < NG && v != 0.f) atomicAdd(&initavg[g * DIM + t], v);
    }
  }
}

__global__ void k_avg_div(const int* __restrict__ starts, float* __restrict__ outp) {
  int g = blockIdx.x, d = threadIdx.x;
  float cnt = fmaxf((float)(starts[g + 1] - starts[g]), 1.0f);
  outp[g * DIM + d] /= cnt;
}

// ---------------------------------------------------------------- layer-2 col sums from conv1 partials
__global__ void k_colred(const float* __restrict__ psum, const float* __restrict__ psq,
                         float* __restrict__ sums) {
  int c = blockIdx.x, t = threadIdx.x;
  __shared__ float r1[256], r2[256];
  float a = 0.f, b = 0.f;
  for (int j = t; j < NBLK_CONV; j += 256) {
    a += psum[(size_t)c * NBLK_CONV + j];
    b += psq[(size_t)c * NBLK_CONV + j];
  }
  r1[t] = a; r2[t] = b; __syncthreads();
  for (int w = 128; w; w >>= 1) { if (t < w) { r1[t] += r1[t + w]; r2[t] += r2[t + w]; } __syncthreads(); }
  if (t == 0) { sums[c] = r1[0]; sums[DIM + c] = r2[0]; }
}

// ---------------------------------------------------------------- xb = bf16(BN(x) * rsqrt(outdeg))
__launch_bounds__(256)
__global__ void k_bnx(const float* __restrict__ x, const float* __restrict__ sums,
                      const float* __restrict__ gamma, const float* __restrict__ beta,
                      const int* __restrict__ cntO, unsigned short* __restrict__ xb) {
  int idx = blockIdx.x * 256 + threadIdx.x;
  int row = idx >> 5, c4 = (idx & 31) * 4;
  float4 sm = *(const float4*)&sums[c4];
  float4 sq = *(const float4*)&sums[DIM + c4];
  float4 ga = *(const float4*)&gamma[c4];
  float4 be = *(const float4*)&beta[c4];
  const float inv = 1.0f / N_NODES;
  float4 sc, sh;
  {
    float m = sm.x * inv, va = sq.x * inv - m * m;
    sc.x = rsqrtf(fmaxf(va, 0.f) + BN_EPS) * ga.x; sh.x = be.x - m * sc.x;
    m = sm.y * inv; va = sq.y * inv - m * m;
    sc.y = rsqrtf(fmaxf(va, 0.f) + BN_EPS) * ga.y; sh.y = be.y - m * sc.y;
    m = sm.z * inv; va = sq.z * inv - m * m;
    sc.z = rsqrtf(fmaxf(va, 0.f) + BN_EPS) * ga.z; sh.z = be.z - m * sc.z;
    m = sm.w * inv; va = sq.w * inv - m * m;
    sc.w = rsqrtf(fmaxf(va, 0.f) + BN_EPS) * ga.w; sh.w = be.w - m * sc.w;
  }
  float4 v = *(const float4*)&x[(size_t)row * DIM + c4];
  float f = rsqrtf(fmaxf((float)cntO[row], 1.0f));
  ushort4 o;
  o.x = f2bf((v.x * sc.x + sh.x) * f);
  o.y = f2bf((v.y * sc.y + sh.y) * f);
  o.z = f2bf((v.z * sc.z + sh.z) * f);
  o.w = f2bf((v.w * sc.w + sh.w) * f);
  *(ushort4*)&xb[(size_t)row * DIM + c4] = o;
}

// ---------------------------------------------------------------- W -> bf16 transposed
__global__ void k_prepW(const float* __restrict__ W1, const float* __restrict__ W2,
                        unsigned short* __restrict__ WbT1, unsigned short* __restrict__ WbT2) {
  int idx = blockIdx.x * 256 + threadIdx.x;
  int which = idx >> 14;
  int i = idx & 16383;
  int k = i >> 7, c = i & 127;
  const float* W = which ? W2 : W1;
  unsigned short* O = which ? WbT2 : WbT1;
  O[c * DIM + k] = f2bf(W[k * DIM + c]);
}

// ---------------------------------------------------------------- pull-mode SpMM -> bf16 agg (8 neighbors in flight)
__launch_bounds__(256, 8)
__global__ void k_spmm_pull(const unsigned short* __restrict__ xb, const int* __restrict__ csr,
                            const int* __restrict__ rowstart, unsigned short* __restrict__ aggb) {
  int row = blockIdx.x * 4 + threadIdx.y;
  int l = threadIdx.x;
  int half = l >> 5, l32 = l & 31;
  int s = rowstart[row], e = rowstart[row + 1];
  float4 acc = {0.f, 0.f, 0.f, 0.f};
  const size_t coff = (size_t)l32 * 4;
  int i = s + half;
  for (; i + 14 < e; i += 16) {        // 8 neighbors per half per iter
    int s0 = csr[i],      s1 = csr[i + 2],  s2 = csr[i + 4],  s3 = csr[i + 6];
    int s4 = csr[i + 8],  s5 = csr[i + 10], s6 = csr[i + 12], s7 = csr[i + 14];
    uint2 w0 = *(const uint2*)&xb[(size_t)s0 * DIM + coff];
    uint2 w1 = *(const uint2*)&xb[(size_t)s1 * DIM + coff];
    uint2 w2 = *(const uint2*)&xb[(size_t)s2 * DIM + coff];
    uint2 w3 = *(const uint2*)&xb[(size_t)s3 * DIM + coff];
    uint2 w4 = *(const uint2*)&xb[(size_t)s4 * DIM + coff];
    uint2 w5 = *(const uint2*)&xb[(size_t)s5 * DIM + coff];
    uint2 w6 = *(const uint2*)&xb[(size_t)s6 * DIM + coff];
    uint2 w7 = *(const uint2*)&xb[(size_t)s7 * DIM + coff];
    acc.x += (__uint_as_float(w0.x << 16) + __uint_as_float(w1.x << 16))
           + (__uint_as_float(w2.x << 16) + __uint_as_float(w3.x << 16))
           + (__uint_as_float(w4.x << 16) + __uint_as_float(w5.x << 16))
           + (__uint_as_float(w6.x << 16) + __uint_as_float(w7.x << 16));
    acc.y += (__uint_as_float(w0.x & 0xFFFF0000u) + __uint_as_float(w1.x & 0xFFFF0000u))
           + (__uint_as_float(w2.x & 0xFFFF0000u) + __uint_as_float(w3.x & 0xFFFF0000u))
           + (__uint_as_float(w4.x & 0xFFFF0000u) + __uint_as_float(w5.x & 0xFFFF0000u))
           + (__uint_as_float(w6.x & 0xFFFF0000u) + __uint_as_float(w7.x & 0xFFFF0000u));
    acc.z += (__uint_as_float(w0.y << 16) + __uint_as_float(w1.y << 16))
           + (__uint_as_float(w2.y << 16) + __uint_as_float(w3.y << 16))
           + (__uint_as_float(w4.y << 16) + __uint_as_float(w5.y << 16))
           + (__uint_as_float(w6.y << 16) + __uint_as_float(w7.y << 16));
    acc.w += (__uint_as_float(w0.y & 0xFFFF0000u) + __uint_as_float(w1.y & 0xFFFF0000u))
           + (__uint_as_float(w2.y & 0xFFFF0000u) + __uint_as_float(w3.y & 0xFFFF0000u))
           + (__uint_as_float(w4.y & 0xFFFF0000u) + __uint_as_float(w5.y & 0xFFFF0000u))
           + (__uint_as_float(w6.y & 0xFFFF0000u) + __uint_as_float(w7.y & 0xFFFF0000u));
  }
  for (; i + 6 < e; i += 8) {          // 4 neighbors
    int s0 = csr[i], s1 = csr[i + 2], s2 = csr[i + 4], s3 = csr[i + 6];
    uint2 w0 = *(const uint2*)&xb[(size_t)s0 * DIM + coff];
    uint2 w1 = *(const uint2*)&xb[(size_t)s1 * DIM + coff];
    uint2 w2 = *(const uint2*)&xb[(size_t)s2 * DIM + coff];
    uint2 w3 = *(const uint2*)&xb[(size_t)s3 * DIM + coff];
    acc.x += __uint_as_float(w0.x << 16) + __uint_as_float(w1.x << 16)
           + __uint_as_float(w2.x << 16) + __uint_as_float(w3.x << 16);
    acc.y += __uint_as_float(w0.x & 0xFFFF0000u) + __uint_as_float(w1.x & 0xFFFF0000u)
           + __uint_as_float(w2.x & 0xFFFF0000u) + __uint_as_float(w3.x & 0xFFFF0000u);
    acc.z += __uint_as_float(w0.y << 16) + __uint_as_float(w1.y << 16)
           + __uint_as_float(w2.y << 16) + __uint_as_float(w3.y << 16);
    acc.w += __uint_as_float(w0.y & 0xFFFF0000u) + __uint_as_float(w1.y & 0xFFFF0000u)
           + __uint_as_float(w2.y & 0xFFFF0000u) + __uint_as_float(w3.y & 0xFFFF0000u);
  }
  for (; i < e; i += 2) {
    int s0 = csr[i];
    uint2 w0 = *(const uint2*)&xb[(size_t)s0 * DIM + coff];
    acc.x += __uint_as_float(w0.x << 16);
    acc.y += __uint_as_float(w0.x & 0xFFFF0000u);
    acc.z += __uint_as_float(w0.y << 16);
    acc.w += __uint_as_float(w0.y & 0xFFFF0000u);
  }
  acc.x += __shfl_xor(acc.x, 32);
  acc.y += __shfl_xor(acc.y, 32);
  acc.z += __shfl_xor(acc.z, 32);
  acc.w += __shfl_xor(acc.w, 32);
  if (half == 0) {
    float isi = rsqrtf(fmaxf((float)(e - s), 1.0f));
    ushort4 o;
    o.x = f2bf(acc.x * isi);
    o.y = f2bf(acc.y * isi);
    o.z = f2bf(acc.z * isi);
    o.w = f2bf(acc.w * isi);
    *(ushort4*)&aggb[(size_t)row * DIM + l32 * 4] = o;
  }
}

// ---------------------------------------------------------------- MFMA conv (+ optional gate, + optional column-stat partials)
__launch_bounds__(256)
__global__ void k_conv(const unsigned short* __restrict__ aggb,
                       const unsigned short* __restrict__ WbT,
                       const float* __restrict__ bias, const float* __restrict__ hres,
                       float* __restrict__ outp,
                       const float* __restrict__ gWp, const float* __restrict__ gbp,
                       float* __restrict__ gatep,
                       float* __restrict__ psum, float* __restrict__ psq) {
  __shared__ unsigned short As[64 * 136];
  __shared__ unsigned short Ws[128 * 136];
  __shared__ float gsh[64];
  float* Of = (float*)Ws;
  int t = threadIdx.x;
  int row0 = blockIdx.x * 64;

  if (gatep && t < 64) gsh[t] = 0.f;

  for (int i = t; i < 1024; i += 256) {
    int r = i >> 4, q = i & 15;
    int row = row0 + r;
    int4 v = {0, 0, 0, 0};
    if (row < N_NODES) v = *(const int4*)&aggb[(size_t)row * DIM + q * 8];
    *(int4*)&As[r * 136 + q * 8] = v;
  }
  for (int i = t; i < 2048; i += 256) {
    int c = i >> 4, q = i & 15;
    *(int4*)&Ws[c * 136 + q * 8] = *(const int4*)&WbT[(size_t)c * DIM + q * 8];
  }
  __syncthreads();

  int wid = t >> 6, l = t & 63;
  int wr = wid >> 1, wc = wid & 1;
  int lr = l & 15, lq = l >> 4;
  f32x4 acc[2][4] = {};
  const unsigned short* Ab = &As[(wr * 32 + lr) * 136 + lq * 8];
  const unsigned short* Bb = &Ws[(wc * 64 + lr) * 136 + lq * 8];
#pragma unroll
  for (int kk = 0; kk < 4; ++kk) {
    bf16x8 a0 = *(const bf16x8*)(Ab + kk * 32);
    bf16x8 a1 = *(const bf16x8*)(Ab + 16 * 136 + kk * 32);
    bf16x8 b0 = *(const bf16x8*)(Bb + kk * 32);
    bf16x8 b1 = *(const bf16x8*)(Bb + 16 * 136 + kk * 32);
    bf16x8 b2 = *(const bf16x8*)(Bb + 32 * 136 + kk * 32);
    bf16x8 b3 = *(const bf16x8*)(Bb + 48 * 136 + kk * 32);
    acc[0][0] = __builtin_amdgcn_mfma_f32_16x16x32_bf16(a0, b0, acc[0][0], 0, 0, 0);
    acc[0][1] = __builtin_amdgcn_mfma_f32_16x16x32_bf16(a0, b1, acc[0][1], 0, 0, 0);
    acc[0][2] = __builtin_amdgcn_mfma_f32_16x16x32_bf16(a0, b2, acc[0][2], 0, 0, 0);
    acc[0][3] = __builtin_amdgcn_mfma_f32_16x16x32_bf16(a0, b3, acc[0][3], 0, 0, 0);
    acc[1][0] = __builtin_amdgcn_mfma_f32_16x16x32_bf16(a1, b0, acc[1][0], 0, 0, 0);
    acc[1][1] = __builtin_amdgcn_mfma_f32_16x16x32_bf16(a1, b1, acc[1][1], 0, 0, 0);
    acc[1][2] = __builtin_amdgcn_mfma_f32_16x16x32_bf16(a1, b2, acc[1][2], 0, 0, 0);
    acc[1][3] = __builtin_amdgcn_mfma_f32_16x16x32_bf16(a1, b3, acc[1][3], 0, 0, 0);
  }
  __syncthreads();

#pragma unroll
  for (int rt = 0; rt < 2; ++rt) {
#pragma unroll
    for (int ct = 0; ct < 4; ++ct) {
      int rr = wr * 32 + rt * 16 + lq * 4;
      int cc = wc * 64 + ct * 16 + lr;
#pragma unroll
      for (int i = 0; i < 4; ++i)
        Of[(rr + i) * 132 + cc] = acc[rt][ct][i];
    }
  }
  __syncthreads();

  float st[4] = {0.f, 0.f, 0.f, 0.f}, st2[4] = {0.f, 0.f, 0.f, 0.f};
#pragma unroll
  for (int i = 0; i < 8; ++i) {
    int fi = t + i * 256;
    int r = fi >> 5, c4 = (fi & 31) * 4;
    int row = row0 + r;
    if (row < N_NODES) {
      float4 o  = *(float4*)&Of[r * 132 + c4];
      float4 bv = *(const float4*)&bias[c4];
      float4 hv = *(const float4*)&hres[(size_t)row * DIM + c4];
      float4 y = {hv.x + fmaxf(o.x + bv.x, 0.f), hv.y + fmaxf(o.y + bv.y, 0.f),
                  hv.z + fmaxf(o.z + bv.z, 0.f), hv.w + fmaxf(o.w + bv.w, 0.f)};
      *(float4*)&outp[(size_t)row * DIM + c4] = y;
      if (gatep) {
        float4 gw = *(const float4*)&gWp[c4];
        atomicAdd(&gsh[r], y.x * gw.x + y.y * gw.y + y.z * gw.z + y.w * gw.w);
      }
      if (psum) {
        st[0] += y.x; st[1] += y.y; st[2] += y.z; st[3] += y.w;
        st2[0] += y.x*y.x; st2[1] += y.y*y.y; st2[2] += y.z*y.z; st2[3] += y.w*y.w;
      }
    }
  }
  if (gatep) {
    __syncthreads();
    int row = row0 + t;
    if (t < 64 && row < N_NODES) gatep[row] = gsh[t] + gbp[0];
  }
  if (psum) {
    float* sls  = (float*)As;
    float* sls2 = sls + 8 * DIM;
    int rg = t >> 5, c4 = (t & 31) * 4;
    __syncthreads();
#pragma unroll
    for (int i = 0; i < 4; ++i) {
      sls[rg * DIM + c4 + i]  = st[i];
      sls2[rg * DIM + c4 + i] = st2[i];
    }
    __syncthreads();
    if (t < DIM) {
      float a = 0.f, b = 0.f;
#pragma unroll
      for (int j = 0; j < 8; ++j) { a += sls[j * DIM + t]; b += sls2[j * DIM + t]; }
      psum[(size_t)t * NBLK_CONV + blockIdx.x] = a;
      psq[(size_t)t * NBLK_CONV + blockIdx.x]  = b;
    }
  }
}

// ---------------------------------------------------------------- per-graph softmax stats
__global__ void k_gstats(const float* __restrict__ gate, const int* __restrict__ starts,
                         float* __restrict__ gmax, float* __restrict__ gden) {
  int g = blockIdx.x;
  int s = starts[g], e = starts[g + 1];
  int t = threadIdx.x;
  __shared__ float red[256];
  float m = -INFINITY;
  for (int i = s + t; i < e; i += 256) m = fmaxf(m, gate[i]);
  red[t] = m; __syncthreads();
  for (int w = 128; w; w >>= 1) { if (t < w) red[t] = fmaxf(red[t], red[t + w]); __syncthreads(); }
  float mg = red[0]; __syncthreads();
  float ssum = 0.f;
  for (int i = s + t; i < e; i += 256) ssum += expf(gate[i] - mg);
  red[t] = ssum; __syncthreads();
  for (int w = 128; w; w >>= 1) { if (t < w) red[t] += red[t + w]; __syncthreads(); }
  if (t == 0) { gmax[g] = mg; gden[g] = red[0]; }
}

// ---------------------------------------------------------------- weighted pooling
__global__ void k_pool(const float* __restrict__ h2, const float* __restrict__ gate,
                       const int* __restrict__ starts, const float* __restrict__ gmax,
                       const float* __restrict__ gden, float* __restrict__ outp) {
  int g = blockIdx.x >> 3, part = blockIdx.x & 7;
  int s = starts[g], e = starts[g + 1];
  int d = threadIdx.x;
  float mg = gmax[g];
  float dn = gden[g];
  float invden = dn > 0.f ? 1.0f / dn : 0.f;
  float acc = 0.f;
  for (int i = s + part; i < e; i += 8) {
    float w = expf(gate[i] - mg) * invden;
    acc += w * h2[(size_t)i * DIM + d];
  }
  atomicAdd(&outp[g * DIM + d], acc);
}

// ---------------------------------------------------------------- launch
extern "C" void kernel_launch(void* const* d_in, const int* in_sizes, int n_in,
                              void* d_out, int out_size, void* d_ws, size_t ws_size,
                              hipStream_t stream) {
  const float* h    = (const float*)d_in[0];
  const int*   src  = (const int*)d_in[1];
  const int*   dst  = (const int*)d_in[2];
  const int*   gid  = (const int*)d_in[3];
  const float* W1   = (const float*)d_in[5];
  const float* b1   = (const float*)d_in[6];
  const float* W2   = (const float*)d_in[7];
  const float* b2   = (const float*)d_in[8];
  const float* gW   = (const float*)d_in[9];
  const float* gb   = (const float*)d_in[10];
  const float* gamma= (const float*)d_in[11];
  const float* beta = (const float*)d_in[12];
  float* out = (float*)d_out;

  char* ws = (char*)d_ws;
  float* h12     = (float*)ws; ws += (size_t)N_NODES * DIM * 4;
  unsigned short* xb   = (unsigned short*)ws; ws += (size_t)N_NODES * DIM * 2;
  unsigned short* aggb = (unsigned short*)ws; ws += (size_t)N_NODES * DIM * 2;
  int*   csr     = (int*)ws;   ws += (size_t)N_EDGES * 4;
  int*   cnt_slice = (int*)ws; ws += (size_t)NSLICE * N_NODES * 4;
  float* psum    = (float*)ws; ws += (size_t)DIM * NBLK_CONV * 4;
  float* psq     = (float*)ws; ws += (size_t)DIM * NBLK_CONV * 4;
  unsigned short* WbT1 = (unsigned short*)ws; ws += DIM * DIM * 2;
  unsigned short* WbT2 = (unsigned short*)ws; ws += DIM * DIM * 2;
  int*   rowstart= (int*)ws;   ws += (N_NODES + 1) * 4;
  int*   cnt     = (int*)ws;   ws += N_NODES * 4;
  int*   cntO    = (int*)ws;   ws += N_NODES * 4;
  float* gate    = (float*)ws; ws += N_NODES * 4;
  float* sums    = (float*)ws; ws += 2 * DIM * 4;
  float* gmax    = (float*)ws; ws += NG * 4;
  float* gden    = (float*)ws; ws += NG * 4;
  int*   starts  = (int*)ws;   ws += (NG + 1) * 4;
  int*   bsum    = (int*)ws;   ws += NB * 4;
  int*   boff    = (int*)ws;   ws += NB * 4;

  hipMemsetAsync(cntO,  0, N_NODES * 4, stream);
  hipMemsetAsync(sums,  0, 2 * DIM * 4, stream);
  hipMemsetAsync(d_out, 0, (size_t)out_size * 4, stream);

  // graph structure
  k_histO<<<256, 1024, 0, stream>>>(src, cntO);
  k_histD<<<256, 1024, 0, stream>>>(dst, cnt_slice);
  k_scan_part<<<NB, 256, 0, stream>>>(cnt_slice, cnt, bsum);
  k_scan_mid<<<1, 128, 0, stream>>>(bsum, boff, rowstart);
  k_scan_fin<<<NB, 256, 0, stream>>>(cnt, boff, rowstart);
  k_scatter_slice<<<256, 1024, 0, stream>>>(src, dst, rowstart, cnt_slice, csr);
  k_starts_fill<<<(N_NODES + 255) / 256, 256, 0, stream>>>(gid, starts);
  k_prepW<<<128, 256, 0, stream>>>(W1, W2, WbT1, WbT2);

  // layer 1 (stats fused with init_avg accumulation)
  k_stats1<<<NSB, 256, 0, stream>>>(h, gid, sums, out + NG * DIM);
  k_avg_div<<<NG, DIM, 0, stream>>>(starts, out + NG * DIM);
  k_bnx<<<N_NODES * 32 / 256, 256, 0, stream>>>(h, sums, gamma, beta, cntO, xb);
  k_spmm_pull<<<N_NODES / 4, dim3(64, 4), 0, stream>>>(xb, csr, rowstart, aggb);
  k_conv<<<NBLK_CONV, 256, 0, stream>>>(aggb, WbT1, b1, h, h12,
                                        nullptr, nullptr, nullptr, psum, psq);

  // layer 2 (stats from conv1 partials)
  k_colred<<<DIM, 256, 0, stream>>>(psum, psq, sums);
  k_bnx<<<N_NODES * 32 / 256, 256, 0, stream>>>(h12, sums, gamma, beta, cntO, xb);
  k_spmm_pull<<<N_NODES / 4, dim3(64, 4), 0, stream>>>(xb, csr, rowstart, aggb);
  k_conv<<<NBLK_CONV, 256, 0, stream>>>(aggb, WbT2, b2, h12, h12,
                                        gW, gb, gate, nullptr, nullptr);

  // pooling
  k_gstats<<<NG, 256, 0, stream>>>(gate, starts, gmax, gden);
  k_pool<<<NG * 8, DIM, 0, stream>>>(h12, gate, starts, gmax, gden, out);
}

// Round 13
// 368.740 us; speedup vs baseline: 20.1151x; 1.1335x over previous
//
#include <hip/hip_runtime.h>
#include <math.h>

#define N_NODES 100000
#define N_EDGES 1600000
#define DIM     128
#define NG      64
#define BN_EPS  1e-5f
#define NB      98       // scan blocks (1024 nodes each)
#define HRANGE  12500    // nodes per LDS range (50 KB)
#define NSLICE  32       // edge slices
#define ESLICE  (N_EDGES / NSLICE)   // 50000
#define NBLK_CONV 1563   // ceil(N_NODES/64)
#define SB      128      // rows per stats block
#define NSB     782      // ceil(N_NODES/SB)

typedef __attribute__((ext_vector_type(8))) short bf16x8;
typedef __attribute__((ext_vector_type(4))) float f32x4;

__device__ __forceinline__ unsigned short f2bf(float f) {
  unsigned b = __float_as_uint(f);
  unsigned r = (b + 0x7FFFu + ((b >> 16) & 1u)) >> 16;   // RNE
  return (unsigned short)r;
}

// ---------------------------------------------------------------- out-degree histogram (src), 256 blocks
__launch_bounds__(1024)
__global__ void k_histO(const int* __restrict__ src, int* __restrict__ cntO) {
  __shared__ int histo[HRANGE];
  int t = threadIdx.x;
  int range = blockIdx.x >> 5, blk = blockIdx.x & 31;
  int lo = range * HRANGE;
  for (int j = t; j < HRANGE; j += 1024) histo[j] = 0;
  __syncthreads();
  const int4* sp = (const int4*)(src + blk * ESLICE);
  for (int q = t; q < ESLICE / 4; q += 1024) {
    int4 v = sp[q];
    unsigned a = (unsigned)(v.x - lo), b = (unsigned)(v.y - lo);
    unsigned c = (unsigned)(v.z - lo), d = (unsigned)(v.w - lo);
    if (a < (unsigned)HRANGE) atomicAdd(&histo[a], 1);
    if (b < (unsigned)HRANGE) atomicAdd(&histo[b], 1);
    if (c < (unsigned)HRANGE) atomicAdd(&histo[c], 1);
    if (d < (unsigned)HRANGE) atomicAdd(&histo[d], 1);
  }
  __syncthreads();
  for (int j = t; j < HRANGE; j += 1024) {
    int v = histo[j];
    if (v) atomicAdd(&cntO[lo + j], v);
  }
}

// ---------------------------------------------------------------- in-degree per-slice histogram (dst), 256 blocks
__launch_bounds__(1024)
__global__ void k_histD(const int* __restrict__ dst, int* __restrict__ cnt_slice) {
  __shared__ int histo[HRANGE];
  int t = threadIdx.x;
  int range = blockIdx.x >> 5, slice = blockIdx.x & 31;
  int lo = range * HRANGE;
  for (int j = t; j < HRANGE; j += 1024) histo[j] = 0;
  __syncthreads();
  const int4* dp = (const int4*)(dst + slice * ESLICE);
  for (int q = t; q < ESLICE / 4; q += 1024) {
    int4 v = dp[q];
    unsigned a = (unsigned)(v.x - lo), b = (unsigned)(v.y - lo);
    unsigned c = (unsigned)(v.z - lo), d = (unsigned)(v.w - lo);
    if (a < (unsigned)HRANGE) atomicAdd(&histo[a], 1);
    if (b < (unsigned)HRANGE) atomicAdd(&histo[b], 1);
    if (c < (unsigned)HRANGE) atomicAdd(&histo[c], 1);
    if (d < (unsigned)HRANGE) atomicAdd(&histo[d], 1);
  }
  __syncthreads();
  for (int j = t; j < HRANGE; j += 1024)
    cnt_slice[(size_t)slice * N_NODES + lo + j] = histo[j];
}

// ---------------------------------------------------------------- scan pass 1 (+ fused slice exclusive-prefix)
__global__ void k_scan_part(int* __restrict__ cnt_slice, int* __restrict__ cnt,
                            int* __restrict__ bsum) {
  int b = blockIdx.x, t = threadIdx.x;
  int base = b * 1024 + t * 4;
  int tot = 0;
#pragma unroll
  for (int j = 0; j < 4; ++j) {
    int i = base + j;
    if (i < N_NODES) {
      int run = 0;
#pragma unroll
      for (int s = 0; s < NSLICE; ++s) {
        int v = cnt_slice[(size_t)s * N_NODES + i];
        cnt_slice[(size_t)s * N_NODES + i] = run;   // exclusive prefix in place
        run += v;
      }
      cnt[i] = run;
      tot += run;
    }
  }
  __shared__ int red[256];
  red[t] = tot; __syncthreads();
  for (int w = 128; w; w >>= 1) { if (t < w) red[t] += red[t + w]; __syncthreads(); }
  if (t == 0) bsum[b] = red[0];
}

__global__ void k_scan_mid(const int* __restrict__ bsum, int* __restrict__ boff,
                           int* __restrict__ rowstart) {
  int t = threadIdx.x;
  __shared__ int sh[128];
  int own = (t < NB) ? bsum[t] : 0;
  sh[t] = own;
  __syncthreads();
  for (int off = 1; off < 128; off <<= 1) {
    int v = (t >= off) ? sh[t - off] : 0;
    __syncthreads();
    sh[t] += v;
    __syncthreads();
  }
  if (t < NB) boff[t] = sh[t] - own;
  if (t == NB - 1) rowstart[N_NODES] = sh[t];
}

__global__ void k_scan_fin(const int* __restrict__ cnt, const int* __restrict__ boff,
                           int* __restrict__ rowstart) {
  int b = blockIdx.x, t = threadIdx.x;
  int base = b * 1024 + t * 4;
  int v0 = 0, v1 = 0, v2 = 0, v3 = 0;
  if (base + 0 < N_NODES) v0 = cnt[base + 0];
  if (base + 1 < N_NODES) v1 = cnt[base + 1];
  if (base + 2 < N_NODES) v2 = cnt[base + 2];
  if (base + 3 < N_NODES) v3 = cnt[base + 3];
  int tsum = v0 + v1 + v2 + v3;
  __shared__ int sh[256];
  sh[t] = tsum;
  __syncthreads();
  for (int off = 1; off < 256; off <<= 1) {
    int v = (t >= off) ? sh[t - off] : 0;
    __syncthreads();
    sh[t] += v;
    __syncthreads();
  }
  int run = boff[b] + sh[t] - tsum;
  if (base + 0 < N_NODES) rowstart[base + 0] = run; run += v0;
  if (base + 1 < N_NODES) rowstart[base + 1] = run; run += v1;
  if (base + 2 < N_NODES) rowstart[base + 2] = run; run += v2;
  if (base + 3 < N_NODES) rowstart[base + 3] = run;
}

// ---------------------------------------------------------------- scatter via LDS cursor, 256 blocks
__launch_bounds__(1024)
__global__ void k_scatter_slice(const int* __restrict__ src, const int* __restrict__ dst,
                                const int* __restrict__ rowstart,
                                const int* __restrict__ cnt_slice, int* __restrict__ csr) {
  __shared__ int cur[HRANGE];
  int t = threadIdx.x;
  int range = blockIdx.x >> 5, slice = blockIdx.x & 31;
  int lo = range * HRANGE;
  for (int j = t; j < HRANGE; j += 1024)
    cur[j] = rowstart[lo + j] + cnt_slice[(size_t)slice * N_NODES + lo + j];
  __syncthreads();
  const int4* dp = (const int4*)(dst + slice * ESLICE);
  const int4* sp = (const int4*)(src + slice * ESLICE);
  for (int q = t; q < ESLICE / 4; q += 1024) {
    int4 d = dp[q];
    int4 s = sp[q];
    unsigned o;
    o = (unsigned)(d.x - lo); if (o < (unsigned)HRANGE) { int p = atomicAdd(&cur[o], 1); csr[p] = s.x; }
    o = (unsigned)(d.y - lo); if (o < (unsigned)HRANGE) { int p = atomicAdd(&cur[o], 1); csr[p] = s.y; }
    o = (unsigned)(d.z - lo); if (o < (unsigned)HRANGE) { int p = atomicAdd(&cur[o], 1); csr[p] = s.z; }
    o = (unsigned)(d.w - lo); if (o < (unsigned)HRANGE) { int p = atomicAdd(&cur[o], 1); csr[p] = s.w; }
  }
}

// ---------------------------------------------------------------- graph CSR starts
__global__ void k_starts_fill(const int* __restrict__ gid, int* __restrict__ starts) {
  int i = blockIdx.x * blockDim.x + threadIdx.x;
  if (i >= N_NODES) return;
  int gi = gid[i];
  if (i == 0) {
    for (int g = 0; g <= gi; ++g) starts[g] = 0;
  } else {
    int gp = gid[i - 1];
    if (gp != gi) for (int g = gp + 1; g <= gi; ++g) starts[g] = i;
  }
  if (i == N_NODES - 1) {
    for (int g = gi + 1; g <= NG; ++g) starts[g] = N_NODES;
  }
}

// ---------------------------------------------------------------- fused BN col stats + init_avg sums
__launch_bounds__(256)
__global__ void k_stats1(const float* __restrict__ x, const int* __restrict__ gid,
                         float* __restrict__ sums, float* __restrict__ initavg) {
  __shared__ float ls[8][DIM];
  __shared__ float ls2[8][DIM];
  __shared__ float lseg[4][8][DIM];
  int t = threadIdx.x;
  int col4 = (t & 31) * 4, rg = t >> 5;
  for (int i = t; i < 4 * 8 * DIM; i += 256) ((float*)lseg)[i] = 0.f;
  int base = blockIdx.x * SB;
  int rend = min(base + SB, N_NODES);
  int g0 = gid[base];
  int gl = gid[rend - 1];
  __syncthreads();
  float4 s = {0.f,0.f,0.f,0.f}, s2 = {0.f,0.f,0.f,0.f};
  float4 acc = {0.f,0.f,0.f,0.f};
  if (g0 == gl) {
    for (int r = base + rg; r < rend; r += 8) {
      float4 v = *(const float4*)&x[(size_t)r * DIM + col4];
      s.x += v.x; s.y += v.y; s.z += v.z; s.w += v.w;
      s2.x += v.x*v.x; s2.y += v.y*v.y; s2.z += v.z*v.z; s2.w += v.w*v.w;
      acc.x += v.x; acc.y += v.y; acc.z += v.z; acc.w += v.w;
    }
    lseg[0][rg][col4+0] = acc.x; lseg[0][rg][col4+1] = acc.y;
    lseg[0][rg][col4+2] = acc.z; lseg[0][rg][col4+3] = acc.w;
  } else {
    int curg = g0;
    for (int r = base + rg; r < rend; r += 8) {
      float4 v = *(const float4*)&x[(size_t)r * DIM + col4];
      s.x += v.x; s.y += v.y; s.z += v.z; s.w += v.w;
      s2.x += v.x*v.x; s2.y += v.y*v.y; s2.z += v.z*v.z; s2.w += v.w*v.w;
      int g = gid[r];
      if (g != curg) {
        int slot = curg - g0;
        if (slot < 4) {
          lseg[slot][rg][col4+0] = acc.x; lseg[slot][rg][col4+1] = acc.y;
          lseg[slot][rg][col4+2] = acc.z; lseg[slot][rg][col4+3] = acc.w;
        } else {
          atomicAdd(&initavg[curg * DIM + col4+0], acc.x);
          atomicAdd(&initavg[curg * DIM + col4+1], acc.y);
          atomicAdd(&initavg[curg * DIM + col4+2], acc.z);
          atomicAdd(&initavg[curg * DIM + col4+3], acc.w);
        }
        acc.x = acc.y = acc.z = acc.w = 0.f;
        curg = g;
      }
      acc.x += v.x; acc.y += v.y; acc.z += v.z; acc.w += v.w;
    }
    int slot = curg - g0;
    if (slot < 4) {
      lseg[slot][rg][col4+0] = acc.x; lseg[slot][rg][col4+1] = acc.y;
      lseg[slot][rg][col4+2] = acc.z; lseg[slot][rg][col4+3] = acc.w;
    } else {
      atomicAdd(&initavg[curg * DIM + col4+0], acc.x);
      atomicAdd(&initavg[curg * DIM + col4+1], acc.y);
      atomicAdd(&initavg[curg * DIM + col4+2], acc.z);
      atomicAdd(&initavg[curg * DIM + col4+3], acc.w);
    }
  }
  *(float4*)&ls[rg][col4] = s;
  *(float4*)&ls2[rg][col4] = s2;
  __syncthreads();
  if (t < DIM) {
    float a = 0.f, b = 0.f;
#pragma unroll
    for (int j = 0; j < 8; ++j) { a += ls[j][t]; b += ls2[j][t]; }
    atomicAdd(&sums[t], a);
    atomicAdd(&sums[DIM + t], b);
#pragma unroll
    for (int slot = 0; slot < 4; ++slot) {
      float v = 0.f;
#pragma unroll
      for (int j = 0; j < 8; ++j) v += lseg[slot][j][t];
      int g = g0 + slot;
      if (g < NG && v != 0.f) atomicAdd(&initavg[g * DIM + t], v);
    }
  }
}

__global__ void k_avg_div(const int* __restrict__ starts, float* __restrict__ outp) {
  int g = blockIdx.x, d = threadIdx.x;
  float cnt = fmaxf((float)(starts[g + 1] - starts[g]), 1.0f);
  outp[g * DIM + d] /= cnt;
}

// ---------------------------------------------------------------- layer-2 col sums from conv1 partials
__global__ void k_colred(const float* __restrict__ psum, const float* __restrict__ psq,
                         float* __restrict__ sums) {
  int c = blockIdx.x, t = threadIdx.x;
  __shared__ float r1[256], r2[256];
  float a = 0.f, b = 0.f;
  for (int j = t; j < NBLK_CONV; j += 256) {
    a += psum[(size_t)c * NBLK_CONV + j];
    b += psq[(size_t)c * NBLK_CONV + j];
  }
  r1[t] = a; r2[t] = b; __syncthreads();
  for (int w = 128; w; w >>= 1) { if (t < w) { r1[t] += r1[t + w]; r2[t] += r2[t + w]; } __syncthreads(); }
  if (t == 0) { sums[c] = r1[0]; sums[DIM + c] = r2[0]; }
}

// ---------------------------------------------------------------- xb = bf16(BN(x) * rsqrt(outdeg))
__launch_bounds__(256)
__global__ void k_bnx(const float* __restrict__ x, const float* __restrict__ sums,
                      const float* __restrict__ gamma, const float* __restrict__ beta,
                      const int* __restrict__ cntO, unsigned short* __restrict__ xb) {
  int idx = blockIdx.x * 256 + threadIdx.x;
  int row = idx >> 5, c4 = (idx & 31) * 4;
  float4 sm = *(const float4*)&sums[c4];
  float4 sq = *(const float4*)&sums[DIM + c4];
  float4 ga = *(const float4*)&gamma[c4];
  float4 be = *(const float4*)&beta[c4];
  const float inv = 1.0f / N_NODES;
  float4 sc, sh;
  {
    float m = sm.x * inv, va = sq.x * inv - m * m;
    sc.x = rsqrtf(fmaxf(va, 0.f) + BN_EPS) * ga.x; sh.x = be.x - m * sc.x;
    m = sm.y * inv; va = sq.y * inv - m * m;
    sc.y = rsqrtf(fmaxf(va, 0.f) + BN_EPS) * ga.y; sh.y = be.y - m * sc.y;
    m = sm.z * inv; va = sq.z * inv - m * m;
    sc.z = rsqrtf(fmaxf(va, 0.f) + BN_EPS) * ga.z; sh.z = be.z - m * sc.z;
    m = sm.w * inv; va = sq.w * inv - m * m;
    sc.w = rsqrtf(fmaxf(va, 0.f) + BN_EPS) * ga.w; sh.w = be.w - m * sc.w;
  }
  float4 v = *(const float4*)&x[(size_t)row * DIM + c4];
  float f = rsqrtf(fmaxf((float)cntO[row], 1.0f));
  ushort4 o;
  o.x = f2bf((v.x * sc.x + sh.x) * f);
  o.y = f2bf((v.y * sc.y + sh.y) * f);
  o.z = f2bf((v.z * sc.z + sh.z) * f);
  o.w = f2bf((v.w * sc.w + sh.w) * f);
  *(ushort4*)&xb[(size_t)row * DIM + c4] = o;
}

// ---------------------------------------------------------------- W -> bf16 transposed
__global__ void k_prepW(const float* __restrict__ W1, const float* __restrict__ W2,
                        unsigned short* __restrict__ WbT1, unsigned short* __restrict__ WbT2) {
  int idx = blockIdx.x * 256 + threadIdx.x;
  int which = idx >> 14;
  int i = idx & 16383;
  int k = i >> 7, c = i & 127;
  const float* W = which ? W2 : W1;
  unsigned short* O = which ? WbT2 : WbT1;
  O[c * DIM + k] = f2bf(W[k * DIM + c]);
}

// ---------------------------------------------------------------- pull-mode SpMM -> bf16 agg
__launch_bounds__(256, 8)
__global__ void k_spmm_pull(const unsigned short* __restrict__ xb, const int* __restrict__ csr,
                            const int* __restrict__ rowstart, unsigned short* __restrict__ aggb) {
  int row = blockIdx.x * 4 + threadIdx.y;
  int l = threadIdx.x;
  int half = l >> 5, l32 = l & 31;
  int s = rowstart[row], e = rowstart[row + 1];
  float4 acc = {0.f, 0.f, 0.f, 0.f};
  const size_t coff = (size_t)l32 * 4;
  int i = s + half;
  for (; i + 14 < e; i += 16) {        // 8 neighbors per half per iter
    int s0 = csr[i],      s1 = csr[i + 2],  s2 = csr[i + 4],  s3 = csr[i + 6];
    int s4 = csr[i + 8],  s5 = csr[i + 10], s6 = csr[i + 12], s7 = csr[i + 14];
    uint2 w0 = *(const uint2*)&xb[(size_t)s0 * DIM + coff];
    uint2 w1 = *(const uint2*)&xb[(size_t)s1 * DIM + coff];
    uint2 w2 = *(const uint2*)&xb[(size_t)s2 * DIM + coff];
    uint2 w3 = *(const uint2*)&xb[(size_t)s3 * DIM + coff];
    uint2 w4 = *(const uint2*)&xb[(size_t)s4 * DIM + coff];
    uint2 w5 = *(const uint2*)&xb[(size_t)s5 * DIM + coff];
    uint2 w6 = *(const uint2*)&xb[(size_t)s6 * DIM + coff];
    uint2 w7 = *(const uint2*)&xb[(size_t)s7 * DIM + coff];
    acc.x += (__uint_as_float(w0.x << 16) + __uint_as_float(w1.x << 16))
           + (__uint_as_float(w2.x << 16) + __uint_as_float(w3.x << 16))
           + (__uint_as_float(w4.x << 16) + __uint_as_float(w5.x << 16))
           + (__uint_as_float(w6.x << 16) + __uint_as_float(w7.x << 16));
    acc.y += (__uint_as_float(w0.x & 0xFFFF0000u) + __uint_as_float(w1.x & 0xFFFF0000u))
           + (__uint_as_float(w2.x & 0xFFFF0000u) + __uint_as_float(w3.x & 0xFFFF0000u))
           + (__uint_as_float(w4.x & 0xFFFF0000u) + __uint_as_float(w5.x & 0xFFFF0000u))
           + (__uint_as_float(w6.x & 0xFFFF0000u) + __uint_as_float(w7.x & 0xFFFF0000u));
    acc.z += (__uint_as_float(w0.y << 16) + __uint_as_float(w1.y << 16))
           + (__uint_as_float(w2.y << 16) + __uint_as_float(w3.y << 16))
           + (__uint_as_float(w4.y << 16) + __uint_as_float(w5.y << 16))
           + (__uint_as_float(w6.y << 16) + __uint_as_float(w7.y << 16));
    acc.w += (__uint_as_float(w0.y & 0xFFFF0000u) + __uint_as_float(w1.y & 0xFFFF0000u))
           + (__uint_as_float(w2.y & 0xFFFF0000u) + __uint_as_float(w3.y & 0xFFFF0000u))
           + (__uint_as_float(w4.y & 0xFFFF0000u) + __uint_as_float(w5.y & 0xFFFF0000u))
           + (__uint_as_float(w6.y & 0xFFFF0000u) + __uint_as_float(w7.y & 0xFFFF0000u));
  }
  for (; i + 6 < e; i += 8) {
    int s0 = csr[i], s1 = csr[i + 2], s2 = csr[i + 4], s3 = csr[i + 6];
    uint2 w0 = *(const uint2*)&xb[(size_t)s0 * DIM + coff];
    uint2 w1 = *(const uint2*)&xb[(size_t)s1 * DIM + coff];
    uint2 w2 = *(const uint2*)&xb[(size_t)s2 * DIM + coff];
    uint2 w3 = *(const uint2*)&xb[(size_t)s3 * DIM + coff];
    acc.x += __uint_as_float(w0.x << 16) + __uint_as_float(w1.x << 16)
           + __uint_as_float(w2.x << 16) + __uint_as_float(w3.x << 16);
    acc.y += __uint_as_float(w0.x & 0xFFFF0000u) + __uint_as_float(w1.x & 0xFFFF0000u)
           + __uint_as_float(w2.x & 0xFFFF0000u) + __uint_as_float(w3.x & 0xFFFF0000u);
    acc.z += __uint_as_float(w0.y << 16) + __uint_as_float(w1.y << 16)
           + __uint_as_float(w2.y << 16) + __uint_as_float(w3.y << 16);
    acc.w += __uint_as_float(w0.y & 0xFFFF0000u) + __uint_as_float(w1.y & 0xFFFF0000u)
           + __uint_as_float(w2.y & 0xFFFF0000u) + __uint_as_float(w3.y & 0xFFFF0000u);
  }
  for (; i < e; i += 2) {
    int s0 = csr[i];
    uint2 w0 = *(const uint2*)&xb[(size_t)s0 * DIM + coff];
    acc.x += __uint_as_float(w0.x << 16);
    acc.y += __uint_as_float(w0.x & 0xFFFF0000u);
    acc.z += __uint_as_float(w0.y << 16);
    acc.w += __uint_as_float(w0.y & 0xFFFF0000u);
  }
  acc.x += __shfl_xor(acc.x, 32);
  acc.y += __shfl_xor(acc.y, 32);
  acc.z += __shfl_xor(acc.z, 32);
  acc.w += __shfl_xor(acc.w, 32);
  if (half == 0) {
    float isi = rsqrtf(fmaxf((float)(e - s), 1.0f));
    ushort4 o;
    o.x = f2bf(acc.x * isi);
    o.y = f2bf(acc.y * isi);
    o.z = f2bf(acc.z * isi);
    o.w = f2bf(acc.w * isi);
    *(ushort4*)&aggb[(size_t)row * DIM + l32 * 4] = o;
  }
}

// ---------------------------------------------------------------- MFMA conv (+ optional gate, + optional column-stat partials)
__launch_bounds__(256)
__global__ void k_conv(const unsigned short* __restrict__ aggb,
                       const unsigned short* __restrict__ WbT,
                       const float* __restrict__ bias, const float* __restrict__ hres,
                       float* __restrict__ outp,
                       const float* __restrict__ gWp, const float* __restrict__ gbp,
                       float* __restrict__ gatep,
                       float* __restrict__ psum, float* __restrict__ psq) {
  __shared__ unsigned short As[64 * 136];
  __shared__ unsigned short Ws[128 * 136];
  __shared__ float gsh[64];
  float* Of = (float*)Ws;
  int t = threadIdx.x;
  int row0 = blockIdx.x * 64;

  if (gatep && t < 64) gsh[t] = 0.f;

  for (int i = t; i < 1024; i += 256) {
    int r = i >> 4, q = i & 15;
    int row = row0 + r;
    int4 v = {0, 0, 0, 0};
    if (row < N_NODES) v = *(const int4*)&aggb[(size_t)row * DIM + q * 8];
    *(int4*)&As[r * 136 + q * 8] = v;
  }
  for (int i = t; i < 2048; i += 256) {
    int c = i >> 4, q = i & 15;
    *(int4*)&Ws[c * 136 + q * 8] = *(const int4*)&WbT[(size_t)c * DIM + q * 8];
  }
  __syncthreads();

  int wid = t >> 6, l = t & 63;
  int wr = wid >> 1, wc = wid & 1;
  int lr = l & 15, lq = l >> 4;
  f32x4 acc[2][4] = {};
  const unsigned short* Ab = &As[(wr * 32 + lr) * 136 + lq * 8];
  const unsigned short* Bb = &Ws[(wc * 64 + lr) * 136 + lq * 8];
#pragma unroll
  for (int kk = 0; kk < 4; ++kk) {
    bf16x8 a0 = *(const bf16x8*)(Ab + kk * 32);
    bf16x8 a1 = *(const bf16x8*)(Ab + 16 * 136 + kk * 32);
    bf16x8 b0 = *(const bf16x8*)(Bb + kk * 32);
    bf16x8 b1 = *(const bf16x8*)(Bb + 16 * 136 + kk * 32);
    bf16x8 b2 = *(const bf16x8*)(Bb + 32 * 136 + kk * 32);
    bf16x8 b3 = *(const bf16x8*)(Bb + 48 * 136 + kk * 32);
    acc[0][0] = __builtin_amdgcn_mfma_f32_16x16x32_bf16(a0, b0, acc[0][0], 0, 0, 0);
    acc[0][1] = __builtin_amdgcn_mfma_f32_16x16x32_bf16(a0, b1, acc[0][1], 0, 0, 0);
    acc[0][2] = __builtin_amdgcn_mfma_f32_16x16x32_bf16(a0, b2, acc[0][2], 0, 0, 0);
    acc[0][3] = __builtin_amdgcn_mfma_f32_16x16x32_bf16(a0, b3, acc[0][3], 0, 0, 0);
    acc[1][0] = __builtin_amdgcn_mfma_f32_16x16x32_bf16(a1, b0, acc[1][0], 0, 0, 0);
    acc[1][1] = __builtin_amdgcn_mfma_f32_16x16x32_bf16(a1, b1, acc[1][1], 0, 0, 0);
    acc[1][2] = __builtin_amdgcn_mfma_f32_16x16x32_bf16(a1, b2, acc[1][2], 0, 0, 0);
    acc[1][3] = __builtin_amdgcn_mfma_f32_16x16x32_bf16(a1, b3, acc[1][3], 0, 0, 0);
  }
  __syncthreads();

#pragma unroll
  for (int rt = 0; rt < 2; ++rt) {
#pragma unroll
    for (int ct = 0; ct < 4; ++ct) {
      int rr = wr * 32 + rt * 16 + lq * 4;
      int cc = wc * 64 + ct * 16 + lr;
#pragma unroll
      for (int i = 0; i < 4; ++i)
        Of[(rr + i) * 132 + cc] = acc[rt][ct][i];
    }
  }
  __syncthreads();

  float st[4] = {0.f, 0.f, 0.f, 0.f}, st2[4] = {0.f, 0.f, 0.f, 0.f};
#pragma unroll
  for (int i = 0; i < 8; ++i) {
    int fi = t + i * 256;
    int r = fi >> 5, c4 = (fi & 31) * 4;
    int row = row0 + r;
    if (row < N_NODES) {
      float4 o  = *(float4*)&Of[r * 132 + c4];
      float4 bv = *(const float4*)&bias[c4];
      float4 hv = *(const float4*)&hres[(size_t)row * DIM + c4];
      float4 y = {hv.x + fmaxf(o.x + bv.x, 0.f), hv.y + fmaxf(o.y + bv.y, 0.f),
                  hv.z + fmaxf(o.z + bv.z, 0.f), hv.w + fmaxf(o.w + bv.w, 0.f)};
      *(float4*)&outp[(size_t)row * DIM + c4] = y;
      if (gatep) {
        float4 gw = *(const float4*)&gWp[c4];
        atomicAdd(&gsh[r], y.x * gw.x + y.y * gw.y + y.z * gw.z + y.w * gw.w);
      }
      if (psum) {
        st[0] += y.x; st[1] += y.y; st[2] += y.z; st[3] += y.w;
        st2[0] += y.x*y.x; st2[1] += y.y*y.y; st2[2] += y.z*y.z; st2[3] += y.w*y.w;
      }
    }
  }
  if (gatep) {
    __syncthreads();
    int row = row0 + t;
    if (t < 64 && row < N_NODES) gatep[row] = gsh[t] + gbp[0];
  }
  if (psum) {
    float* sls  = (float*)As;
    float* sls2 = sls + 8 * DIM;
    int rg = t >> 5, c4 = (t & 31) * 4;
    __syncthreads();
#pragma unroll
    for (int i = 0; i < 4; ++i) {
      sls[rg * DIM + c4 + i]  = st[i];
      sls2[rg * DIM + c4 + i] = st2[i];
    }
    __syncthreads();
    if (t < DIM) {
      float a = 0.f, b = 0.f;
#pragma unroll
      for (int j = 0; j < 8; ++j) { a += sls[j * DIM + t]; b += sls2[j * DIM + t]; }
      psum[(size_t)t * NBLK_CONV + blockIdx.x] = a;
      psq[(size_t)t * NBLK_CONV + blockIdx.x]  = b;
    }
  }
}

// ---------------------------------------------------------------- per-graph softmax stats
__global__ void k_gstats(const float* __restrict__ gate, const int* __restrict__ starts,
                         float* __restrict__ gmax, float* __restrict__ gden) {
  int g = blockIdx.x;
  int s = starts[g], e = starts[g + 1];
  int t = threadIdx.x;
  __shared__ float red[256];
  float m = -INFINITY;
  for (int i = s + t; i < e; i += 256) m = fmaxf(m, gate[i]);
  red[t] = m; __syncthreads();
  for (int w = 128; w; w >>= 1) { if (t < w) red[t] = fmaxf(red[t], red[t + w]); __syncthreads(); }
  float mg = red[0]; __syncthreads();
  float ssum = 0.f;
  for (int i = s + t; i < e; i += 256) ssum += expf(gate[i] - mg);
  red[t] = ssum; __syncthreads();
  for (int w = 128; w; w >>= 1) { if (t < w) red[t] += red[t + w]; __syncthreads(); }
  if (t == 0) { gmax[g] = mg; gden[g] = red[0]; }
}

// ---------------------------------------------------------------- weighted pooling (2048 blocks, float4, LDS reduce)
__launch_bounds__(256)
__global__ void k_pool(const float* __restrict__ h2, const float* __restrict__ gate,
                       const int* __restrict__ starts, const float* __restrict__ gmax,
                       const float* __restrict__ gden, float* __restrict__ outp) {
  __shared__ float ls[8][DIM];
  int g = blockIdx.x >> 5, part = blockIdx.x & 31;
  int s = starts[g], e = starts[g + 1];
  int t = threadIdx.x;
  int col4 = (t & 31) * 4, rg = t >> 5;
  float mg = gmax[g];
  float dn = gden[g];
  float invden = dn > 0.f ? 1.0f / dn : 0.f;
  float4 acc = {0.f, 0.f, 0.f, 0.f};
  for (int i = s + part + rg * 32; i < e; i += 256) {   // 32 parts x 8 row-groups
    float w = expf(gate[i] - mg) * invden;
    float4 v = *(const float4*)&h2[(size_t)i * DIM + col4];
    acc.x += w * v.x; acc.y += w * v.y; acc.z += w * v.z; acc.w += w * v.w;
  }
  *(float4*)&ls[rg][col4] = acc;
  __syncthreads();
  if (t < DIM) {
    float a = 0.f;
#pragma unroll
    for (int j = 0; j < 8; ++j) a += ls[j][t];
    if (a != 0.f) atomicAdd(&outp[g * DIM + t], a);
  }
}

// ---------------------------------------------------------------- launch
extern "C" void kernel_launch(void* const* d_in, const int* in_sizes, int n_in,
                              void* d_out, int out_size, void* d_ws, size_t ws_size,
                              hipStream_t stream) {
  const float* h    = (const float*)d_in[0];
  const int*   src  = (const int*)d_in[1];
  const int*   dst  = (const int*)d_in[2];
  const int*   gid  = (const int*)d_in[3];
  const float* W1   = (const float*)d_in[5];
  const float* b1   = (const float*)d_in[6];
  const float* W2   = (const float*)d_in[7];
  const float* b2   = (const float*)d_in[8];
  const float* gW   = (const float*)d_in[9];
  const float* gb   = (const float*)d_in[10];
  const float* gamma= (const float*)d_in[11];
  const float* beta = (const float*)d_in[12];
  float* out = (float*)d_out;

  char* ws = (char*)d_ws;
  float* h12     = (float*)ws; ws += (size_t)N_NODES * DIM * 4;
  unsigned short* xb   = (unsigned short*)ws; ws += (size_t)N_NODES * DIM * 2;
  unsigned short* aggb = (unsigned short*)ws; ws += (size_t)N_NODES * DIM * 2;
  int*   csr     = (int*)ws;   ws += (size_t)N_EDGES * 4;
  int*   cnt_slice = (int*)ws; ws += (size_t)NSLICE * N_NODES * 4;
  float* psum    = (float*)ws; ws += (size_t)DIM * NBLK_CONV * 4;
  float* psq     = (float*)ws; ws += (size_t)DIM * NBLK_CONV * 4;
  unsigned short* WbT1 = (unsigned short*)ws; ws += DIM * DIM * 2;
  unsigned short* WbT2 = (unsigned short*)ws; ws += DIM * DIM * 2;
  int*   rowstart= (int*)ws;   ws += (N_NODES + 1) * 4;
  int*   cnt     = (int*)ws;   ws += N_NODES * 4;
  int*   cntO    = (int*)ws;   ws += N_NODES * 4;
  float* gate    = (float*)ws; ws += N_NODES * 4;
  float* sums    = (float*)ws; ws += 2 * DIM * 4;
  float* gmax    = (float*)ws; ws += NG * 4;
  float* gden    = (float*)ws; ws += NG * 4;
  int*   starts  = (int*)ws;   ws += (NG + 1) * 4;
  int*   bsum    = (int*)ws;   ws += NB * 4;
  int*   boff    = (int*)ws;   ws += NB * 4;

  hipMemsetAsync(cntO,  0, N_NODES * 4, stream);
  hipMemsetAsync(sums,  0, 2 * DIM * 4, stream);
  hipMemsetAsync(d_out, 0, (size_t)out_size * 4, stream);

  // graph structure
  k_histO<<<256, 1024, 0, stream>>>(src, cntO);
  k_histD<<<256, 1024, 0, stream>>>(dst, cnt_slice);
  k_scan_part<<<NB, 256, 0, stream>>>(cnt_slice, cnt, bsum);
  k_scan_mid<<<1, 128, 0, stream>>>(bsum, boff, rowstart);
  k_scan_fin<<<NB, 256, 0, stream>>>(cnt, boff, rowstart);
  k_scatter_slice<<<256, 1024, 0, stream>>>(src, dst, rowstart, cnt_slice, csr);
  k_starts_fill<<<(N_NODES + 255) / 256, 256, 0, stream>>>(gid, starts);
  k_prepW<<<128, 256, 0, stream>>>(W1, W2, WbT1, WbT2);

  // layer 1 (stats fused with init_avg accumulation)
  k_stats1<<<NSB, 256, 0, stream>>>(h, gid, sums, out + NG * DIM);
  k_avg_div<<<NG, DIM, 0, stream>>>(starts, out + NG * DIM);
  k_bnx<<<N_NODES * 32 / 256, 256, 0, stream>>>(h, sums, gamma, beta, cntO, xb);
  k_spmm_pull<<<N_NODES / 4, dim3(64, 4), 0, stream>>>(xb, csr, rowstart, aggb);
  k_conv<<<NBLK_CONV, 256, 0, stream>>>(aggb, WbT1, b1, h, h12,
                                        nullptr, nullptr, nullptr, psum, psq);

  // layer 2 (stats from conv1 partials)
  k_colred<<<DIM, 256, 0, stream>>>(psum, psq, sums);
  k_bnx<<<N_NODES * 32 / 256, 256, 0, stream>>>(h12, sums, gamma, beta, cntO, xb);
  k_spmm_pull<<<N_NODES / 4, dim3(64, 4), 0, stream>>>(xb, csr, rowstart, aggb);
  k_conv<<<NBLK_CONV, 256, 0, stream>>>(aggb, WbT2, b2, h12, h12,
                                        gW, gb, gate, nullptr, nullptr);

  // pooling
  k_gstats<<<NG, 256, 0, stream>>>(gate, starts, gmax, gden);
  k_pool<<<NG * 32, 256, 0, stream>>>(h12, gate, starts, gmax, gden, out);
}